// Round 1
// baseline (1025.510 us; speedup 1.0000x reference)
//
#include <hip/hip_runtime.h>

typedef __attribute__((ext_vector_type(8))) short bf8_t;   // 8 x bf16 (4 VGPRs)
typedef __attribute__((ext_vector_type(4))) short bf4_t;   // 4 x bf16 (2 VGPRs)
typedef __attribute__((ext_vector_type(4))) float f4_t;    // 4 x fp32 acc
typedef unsigned short u16;

#define MFMA16 __builtin_amdgcn_mfma_f32_16x16x32_bf16

#define RSQRT8    0.35355339059327373f
#define RSQRT128  0.08838834764831845f
#define RSQRT192  0.07216878364870323f
#define RSQRT64   0.125f
#define INV_SQRT3 0.57735026918962576f
#define SEG_NORM  0.25f       /* 1/sqrt(16) */
#define C_HALF    0.70710678118654752f
#define SQ23      0.81649658092772603f
#define SQ13      0.57735026918962576f

__device__ __forceinline__ float bf2f(u16 b) {
    return __uint_as_float(((unsigned int)b) << 16);
}
__device__ __forceinline__ u16 f2bf(float f) {
    unsigned int u = __float_as_uint(f);
    u += 0x7FFFu + ((u >> 16) & 1u);           // round-to-nearest-even
    return (u16)(u >> 16);
}
__device__ __forceinline__ float silu_f(float x) { return x / (1.0f + __expf(-x)); }

// One wave computes a 16-row strip x NTILES*16-col block of C = A @ (Whi+Wlo).
template<int KSTEPS, int NTILES>
__device__ __forceinline__ void gemm_strip(
    const u16* A, int as,
    const u16* __restrict__ Wh, const u16* __restrict__ Wl,
    int Kp, int lane, f4_t* acc)
{
    const int r = lane & 15, q = lane >> 4;
    const u16* arow = A + r * as + q * 8;
    const u16* wh = Wh + (size_t)r * Kp + q * 8;
    const u16* wl = Wl + (size_t)r * Kp + q * 8;
#pragma unroll 2
    for (int ks = 0; ks < KSTEPS; ++ks) {
        bf8_t a = *(const bf8_t*)(arow + ks * 32);
#pragma unroll
        for (int n = 0; n < NTILES; ++n) {
            bf8_t bh = *(const bf8_t*)(wh + n * 16 * Kp + ks * 32);
            bf8_t bl = *(const bf8_t*)(wl + n * 16 * Kp + ks * 32);
            acc[n] = MFMA16(a, bl, acc[n], 0, 0, 0);
            acc[n] = MFMA16(a, bh, acc[n], 0, 0, 0);
        }
    }
}

// env_weight epilogue store: weight col w (0..63 within half) -> channels.
__device__ __forceinline__ void env_store(u16* dst, int w, float val, float4 av)
{
    int m = w >> 1;
    if ((w & 1) == 0) {
        dst[4 * m] = f2bf(val * av.x);
    } else {
        dst[4 * m + 1] = f2bf(val * av.y);
        dst[4 * m + 2] = f2bf(val * av.z);
        dst[4 * m + 3] = f2bf(val * av.w);
    }
}

// ---------------------------------------------------------------------------
// Weight prep (single kernel, 10 regions): fp32 [K][N] -> bf16 hi/lo [N][Kp].
// ---------------------------------------------------------------------------
struct PD { const float* src; u16* hi; u16* lo; int K, N, Kp, perm, off, cnt; };
struct PDs { PD d[10]; };

__global__ __launch_bounds__(256) void prep_all(PDs P, int total)
{
    int i = blockIdx.x * 256 + threadIdx.x;
    if (i >= total) return;
#pragma unroll
    for (int rg = 0; rg < 10; ++rg) {
        if (i >= P.d[rg].off && i < P.d[rg].off + P.d[rg].cnt) {
            int li = i - P.d[rg].off;
            int n = li / P.d[rg].Kp, k = li - n * P.d[rg].Kp;
            int ks = k;
            if (P.d[rg].perm && k >= 128)
                ks = (k < 160) ? (128 + 2 * (k - 128)) : (129 + 2 * (k - 160));
            float wv = (ks < P.d[rg].K) ? P.d[rg].src[(size_t)ks * P.d[rg].N + n] : 0.f;
            u16 h = f2bf(wv);
            P.d[rg].hi[li] = h;
            P.d[rg].lo[li] = f2bf(wv - bf2f(h));
        }
    }
}

// ---------------------------------------------------------------------------
// Counting sort of edges by center node (replaces all fp32 atomics).
// ---------------------------------------------------------------------------
__global__ __launch_bounds__(256) void hist_k(const int* __restrict__ eidx,
                                              int* __restrict__ cnt, int E)
{
    int i = blockIdx.x * 256 + threadIdx.x;
    if (i < E) atomicAdd(&cnt[eidx[i]], 1);
}

__global__ __launch_bounds__(1024) void scan_k(const int* __restrict__ cnt,
                                               int* __restrict__ base,
                                               int* __restrict__ cursor, int NN)
{
    __shared__ int part[1024];
    const int t = threadIdx.x;
    const int CHK = (NN + 1023) >> 10;
    int s = 0;
    for (int k = 0; k < CHK; ++k) { int idx = t * CHK + k; if (idx < NN) s += cnt[idx]; }
    part[t] = s;
    __syncthreads();
    for (int off = 1; off < 1024; off <<= 1) {
        int v = (t >= off) ? part[t - off] : 0;
        __syncthreads();
        part[t] += v;
        __syncthreads();
    }
    if (t == 0) base[NN] = part[1023];
    int run = (t == 0) ? 0 : part[t - 1];
    for (int k = 0; k < CHK; ++k) {
        int idx = t * CHK + k;
        if (idx < NN) { base[idx] = run; cursor[idx] = run; run += cnt[idx]; }
    }
}

__global__ __launch_bounds__(256) void scatter_k(const int* __restrict__ eidx,
                                                 int* __restrict__ cursor,
                                                 int* __restrict__ sorted, int E)
{
    int i = blockIdx.x * 256 + threadIdx.x;
    if (i < E) {
        int p = atomicAdd(&cursor[eidx[i]], 1);
        sorted[p] = i;
    }
}

// ---------------------------------------------------------------------------
// Segment reduction: env[node] = (sum over node's edges of env_e) * SEG_NORM.
// 2 nodes per 256-thr block; fp32 register accumulate; bf16 out (pre-normed).
// ---------------------------------------------------------------------------
__global__ __launch_bounds__(256) void reduce_env(
    const int* __restrict__ base, const int* __restrict__ sorted,
    const u16* __restrict__ enve, u16* __restrict__ env, int NN)
{
    const int half = __builtin_amdgcn_readfirstlane(threadIdx.x >> 7);
    const int node = blockIdx.x * 2 + half;
    const int ch = threadIdx.x & 127;
    if (node >= NN) return;
    const int b = base[node], en = base[node + 1];
    float acc = 0.f;
    int i = b;
    for (; i + 3 < en; i += 4) {
        int s0 = sorted[i], s1 = sorted[i + 1], s2 = sorted[i + 2], s3 = sorted[i + 3];
        float v0 = bf2f(enve[(size_t)s0 * 128 + ch]);
        float v1 = bf2f(enve[(size_t)s1 * 128 + ch]);
        float v2 = bf2f(enve[(size_t)s2 * 128 + ch]);
        float v3 = bf2f(enve[(size_t)s3 * 128 + ch]);
        acc += (v0 + v1) + (v2 + v3);
    }
    for (; i < en; ++i) acc += bf2f(enve[(size_t)sorted[i] * 128 + ch]);
    env[(size_t)node * 128 + ch] = f2bf(acc * SEG_NORM);
}

// ---------------------------------------------------------------------------
// Phase A: lat = mlp2(inv); w0 = lat@Wenv0; env_weight -> featbuf + env_e rows.
// 512 thr = 8 waves: strip s4 = w&3 (16 rows), col-half ch = w>>2 (64 cols).
// ---------------------------------------------------------------------------
__global__ __launch_bounds__(512, 4) void phaseA(
    const float* __restrict__ attr, const float* __restrict__ inv,
    const u16* __restrict__ Wh2b0, const u16* __restrict__ Wl2b0,
    const u16* __restrict__ Wh2b1, const u16* __restrict__ Wl2b1,
    const u16* __restrict__ Whenv0, const u16* __restrict__ Wlenv0,
    u16* __restrict__ latbuf, u16* __restrict__ featbuf,
    u16* __restrict__ enve, int E)
{
    __shared__ __align__(16) char sm[39936];
    u16 (*Xi)[32]  = (u16 (*)[32])sm;                     // 4096
    u16 (*Hs)[136] = (u16 (*)[136])(sm + 4096);           // 17408
    u16 (*Ls)[136] = (u16 (*)[136])(sm + 21504);          // 17408
    float (*sattr)[4] = (float (*)[4])(sm + 38912);       // 1024

    const int tid = threadIdx.x;
    const int lane = tid & 63;
    const int w = tid >> 6;
    const int s4 = w & 3, ch = w >> 2;
    const int e0 = blockIdx.x * 64;
    const int E1 = E - 1;
    const int r = lane & 15, q = lane >> 4;

    for (int i = tid; i < 64 * 32; i += 512) {
        int t = i >> 5, c = i & 31;
        u16 v = 0;
        if (c < 8) v = f2bf(inv[(size_t)min(e0 + t, E1) * 8 + c]);
        Xi[t][c] = v;
    }
    if (tid < 256) { int t = tid >> 2, c = tid & 3; sattr[t][c] = attr[(size_t)min(e0 + t, E1) * 4 + c]; }
    __syncthreads();

    const f4_t z = {0.f, 0.f, 0.f, 0.f};
    f4_t acc[4];

    // GEMM1: inv(8->32) @ W2b0 -> silu -> Hs
#pragma unroll
    for (int n = 0; n < 4; ++n) acc[n] = z;
    gemm_strip<1, 4>(&Xi[s4 * 16][0], 32, Wh2b0 + ch * 64 * 32, Wl2b0 + ch * 64 * 32, 32, lane, acc);
#pragma unroll
    for (int n = 0; n < 4; ++n)
#pragma unroll
        for (int jj = 0; jj < 4; ++jj)
            Hs[s4 * 16 + q * 4 + jj][ch * 64 + n * 16 + r] = f2bf(silu_f(acc[n][jj] * RSQRT8));
    __syncthreads();

    // GEMM2: h(128) @ W2b1 -> lat -> Ls + latbuf
#pragma unroll
    for (int n = 0; n < 4; ++n) acc[n] = z;
    gemm_strip<4, 4>(&Hs[s4 * 16][0], 136, Wh2b1 + ch * 64 * 128, Wl2b1 + ch * 64 * 128, 128, lane, acc);
#pragma unroll
    for (int n = 0; n < 4; ++n)
#pragma unroll
        for (int jj = 0; jj < 4; ++jj) {
            int row = s4 * 16 + q * 4 + jj, cc = ch * 64 + n * 16 + r;
            u16 b = f2bf(acc[n][jj] * RSQRT128);
            Ls[row][cc] = b;
            int e = e0 + row;
            if (e < E) latbuf[(size_t)e * 128 + cc] = b;
        }
    __syncthreads();

    // GEMM3: lat(128) @ Wenv0 -> w0; direct env_weight stores from accumulators.
    // ch==0 waves hold cols 0..63 (features); ch==1 waves cols 64..127 (env_e).
#pragma unroll
    for (int n = 0; n < 4; ++n) acc[n] = z;
    gemm_strip<4, 4>(&Ls[s4 * 16][0], 136, Whenv0 + ch * 64 * 128, Wlenv0 + ch * 64 * 128, 128, lane, acc);
#pragma unroll
    for (int jj = 0; jj < 4; ++jj) {
        int row = s4 * 16 + q * 4 + jj;
        int e = e0 + row;
        if (e >= E) continue;
        float4 av = *(const float4*)&sattr[row][0];
        u16* dst = ((ch == 0) ? featbuf : enve) + (size_t)e * 128;
#pragma unroll
        for (int n = 0; n < 4; ++n)
            env_store(dst, n * 16 + r, acc[n][jj] * RSQRT128, av);
    }
}

// ---------------------------------------------------------------------------
// Phase B: tensor products + mix -> feat2; new_lat MLP; lat2; w1 -> env_e rows.
// LDS diet: feat/env0 are consumed ONLY element-wise -> stream them from
// global (env0b is L2-resident, 3.2 MB) in a register pass that writes the
// ss|vv scalars into X4[128..191] and the sv|vs MFMA A-operands into P
// (k-ordered). 52.5 KB LDS -> 3 blocks/CU (was 2); barriers 7 -> 4.
// ---------------------------------------------------------------------------
__global__ __launch_bounds__(512, 6) void phaseB(
    const int* __restrict__ eidx, const float* __restrict__ attr,
    const u16* __restrict__ env0b,
    const u16* __restrict__ Whs0, const u16* __restrict__ Wls0,
    const u16* __restrict__ Whv0, const u16* __restrict__ Wlv0,
    const u16* __restrict__ Whl10, const u16* __restrict__ Wll10,
    const u16* __restrict__ Whl11, const u16* __restrict__ Wll11,
    const u16* __restrict__ Whe1, const u16* __restrict__ Wle1,
    u16* __restrict__ latbuf, u16* __restrict__ featbuf,
    u16* __restrict__ enve, int E)
{
    __shared__ __align__(16) char sm[52480];
    u16 (*X4)[200] = (u16 (*)[200])sm;                    // 25600: lat|ss|vv -> lat2
    u16 (*P)[200]  = (u16 (*)[200])(sm + 25600);          // 25600: sv|vs per dim (192 used)
    u16 (*Hs)[136] = (u16 (*)[136])(sm + 25600);          // overlay P (dead post-mix)
    float (*sattr)[4] = (float (*)[4])(sm + 51200);       // 1024

    const int tid = threadIdx.x;
    const int lane = tid & 63;
    const int w = tid >> 6;
    const int s4 = w & 3, ch = w >> 2;
    const int e0 = blockIdx.x * 64;
    const int E1 = E - 1;
    const int r = lane & 15, q = lane >> 4;

    if (tid < 256) { int t = tid >> 2, c = tid & 3; sattr[t][c] = attr[(size_t)min(e0 + t, E1) * 4 + c]; }

    // lat -> X4[:, 0:128] (vectorized: 2 x 16B per thread)
    for (int i = tid; i < 64 * 16; i += 512) {
        int t = i >> 4, dc = i & 15;
        *(bf8_t*)&X4[t][dc * 8] = ((const bf8_t*)(latbuf + (size_t)min(e0 + t, E1) * 128))[dc];
    }

    // tensor-product pass: 1 thread = (row t, 4 muls). Reads 32B feat + 32B env0
    // straight from global; writes ss->X4[128+m], vv->X4[160+m],
    // sv_d->P[d*64+m], vs_d->P[d*64+32+m]  (exactly the V-GEMM k-order).
    {
        const int t = tid >> 3, cg = tid & 7;
        const int e = min(e0 + t, E1);
        const int nd = eidx[e];
        const u16* fp = featbuf + (size_t)e * 128 + cg * 16;
        const u16* gp = env0b + (size_t)nd * 128 + cg * 16;
        bf8_t fA = *(const bf8_t*)fp;
        bf8_t fB = *(const bf8_t*)(fp + 8);
        bf8_t gA = *(const bf8_t*)gp;
        bf8_t gB = *(const bf8_t*)(gp + 8);
        bf4_t ssv, vvv, svv[3], vsv[3];
#pragma unroll
        for (int c = 0; c < 4; ++c) {
            float f0, f1, f2, f3, g0, g1, g2, g3;
            if (c < 2) {
                f0 = bf2f((u16)fA[4 * c]);     g0 = bf2f((u16)gA[4 * c]);
                f1 = bf2f((u16)fA[4 * c + 1]); g1 = bf2f((u16)gA[4 * c + 1]);
                f2 = bf2f((u16)fA[4 * c + 2]); g2 = bf2f((u16)gA[4 * c + 2]);
                f3 = bf2f((u16)fA[4 * c + 3]); g3 = bf2f((u16)gA[4 * c + 3]);
            } else {
                int cc = c - 2;
                f0 = bf2f((u16)fB[4 * cc]);     g0 = bf2f((u16)gB[4 * cc]);
                f1 = bf2f((u16)fB[4 * cc + 1]); g1 = bf2f((u16)gB[4 * cc + 1]);
                f2 = bf2f((u16)fB[4 * cc + 2]); g2 = bf2f((u16)gB[4 * cc + 2]);
                f3 = bf2f((u16)fB[4 * cc + 3]); g3 = bf2f((u16)gB[4 * cc + 3]);
            }
            ssv[c] = (short)f2bf(f0 * g0);
            vvv[c] = (short)f2bf((f1 * g1 + f2 * g2 + f3 * g3) * INV_SQRT3);
            svv[0][c] = (short)f2bf(f0 * g1);
            svv[1][c] = (short)f2bf(f0 * g2);
            svv[2][c] = (short)f2bf(f0 * g3);
            vsv[0][c] = (short)f2bf(f1 * g0);
            vsv[1][c] = (short)f2bf(f2 * g0);
            vsv[2][c] = (short)f2bf(f3 * g0);
        }
        *(bf4_t*)&X4[t][128 + 4 * cg] = ssv;
        *(bf4_t*)&X4[t][160 + 4 * cg] = vvv;
#pragma unroll
        for (int d = 0; d < 3; ++d) {
            *(bf4_t*)&P[t][d * 64 + 4 * cg]      = svv[d];
            *(bf4_t*)&P[t][d * 64 + 32 + 4 * cg] = vsv[d];
        }
    }
    __syncthreads();

    const f4_t z = {0.f, 0.f, 0.f, 0.f};

    // ---- mix: S-path GEMM + 3 v-dim GEMMs, all A-operands pre-built in LDS ----
    f4_t aS = z, aV[3] = {z, z, z};
    gemm_strip<2, 1>(&X4[s4 * 16][128], 200, Whs0 + ch * 16 * 64, Wls0 + ch * 16 * 64, 64, lane, &aS);
#pragma unroll
    for (int d = 0; d < 3; ++d)
        gemm_strip<2, 1>(&P[s4 * 16][d * 64], 200, Whv0 + ch * 16 * 64, Wlv0 + ch * 16 * 64, 64, lane, &aV[d]);

    // feat2 direct to global
    {
        const int m = ch * 16 + r;
#pragma unroll
        for (int reg = 0; reg < 4; ++reg) {
            int e = e0 + s4 * 16 + q * 4 + reg;
            if (e < E) {
                u16* dst = featbuf + (size_t)e * 128 + 4 * m;
                dst[0] = f2bf(aS[reg] * RSQRT64);
                dst[1] = f2bf(aV[0][reg] * (RSQRT64 * INV_SQRT3));
                dst[2] = f2bf(aV[1][reg] * (RSQRT64 * INV_SQRT3));
                dst[3] = f2bf(aV[2][reg] * (RSQRT64 * INV_SQRT3));
            }
        }
    }

    // GEMM4: [lat|sscal](192) @ Wlat1_0 (k-loop reads X4 only)
    f4_t acc[4];
#pragma unroll
    for (int n = 0; n < 4; ++n) acc[n] = z;
    gemm_strip<6, 4>(&X4[s4 * 16][0], 200, Whl10 + ch * 64 * 192, Wll10 + ch * 64 * 192, 192, lane, acc);
    __syncthreads();   // all P reads (mix) done -> Hs may overwrite P
#pragma unroll
    for (int n = 0; n < 4; ++n)
#pragma unroll
        for (int jj = 0; jj < 4; ++jj)
            Hs[s4 * 16 + q * 4 + jj][ch * 64 + n * 16 + r] = f2bf(silu_f(acc[n][jj] * RSQRT192));
    __syncthreads();

    // GEMM5: h @ Wlat1_1 -> new_lat; lat2 = C*(lat+new_lat) in place in X4
#pragma unroll
    for (int n = 0; n < 4; ++n) acc[n] = z;
    gemm_strip<4, 4>(&Hs[s4 * 16][0], 136, Whl11 + ch * 64 * 128, Wll11 + ch * 64 * 128, 128, lane, acc);
#pragma unroll
    for (int n = 0; n < 4; ++n)
#pragma unroll
        for (int jj = 0; jj < 4; ++jj) {
            int row = s4 * 16 + q * 4 + jj, cc = ch * 64 + n * 16 + r;
            float l2 = C_HALF * (bf2f(X4[row][cc]) + acc[n][jj] * RSQRT128);
            X4[row][cc] = f2bf(l2);      // cell owned by this lane-reg only
        }
    __syncthreads();

    // lat2 -> latbuf ; GEMM6: lat2 @ Wenv1(128x64) -> w1 -> env_e rows (direct)
    for (int i = tid; i < 64 * 16; i += 512) {
        int t = i >> 4, dc = i & 15;
        int e = e0 + t;
        if (e < E) ((bf8_t*)(latbuf + (size_t)e * 128))[dc] = *(const bf8_t*)&X4[t][dc * 8];
    }
    f4_t a6[2] = {z, z};
    gemm_strip<4, 2>(&X4[s4 * 16][0], 200, Whe1 + ch * 32 * 128, Wle1 + ch * 32 * 128, 128, lane, a6);
#pragma unroll
    for (int jj = 0; jj < 4; ++jj) {
        int row = s4 * 16 + q * 4 + jj;
        int e = e0 + row;
        if (e >= E) continue;
        float4 av = *(const float4*)&sattr[row][0];
        u16* dst = enve + (size_t)e * 128;
#pragma unroll
        for (int n = 0; n < 2; ++n)
            env_store(dst, ch * 32 + n * 16 + r, a6[n][jj] * RSQRT128, av);
    }
}

// ---------------------------------------------------------------------------
// Phase C: scalars1 streamed from global (no Ft/Gt LDS), final MLP, out mix.
// 43.0 KB LDS -> 3 blocks/CU; barriers 5 -> 3.
// ---------------------------------------------------------------------------
__global__ __launch_bounds__(512, 6) void phaseC(
    const int* __restrict__ eidx, const u16* __restrict__ env1b,
    const u16* __restrict__ Whf0, const u16* __restrict__ Wlf0,
    const u16* __restrict__ Whf1, const u16* __restrict__ Wlf1,
    const u16* __restrict__ latbuf, const u16* __restrict__ featbuf,
    float* __restrict__ outp, int E)
{
    __shared__ __align__(16) char sm[43008];
    u16 (*X7)[200] = (u16 (*)[200])sm;                    // 25600: lat2|scal1
    u16 (*Hs)[136] = (u16 (*)[136])(sm + 25600);          // 17408

    const int tid = threadIdx.x;
    const int lane = tid & 63;
    const int w = tid >> 6;
    const int s4 = w & 3, ch = w >> 2;
    const int e0 = blockIdx.x * 64;
    const int E1 = E - 1;
    const int r = lane & 15, q = lane >> 4;

    // lat2 -> X7[:, 0:128]
    for (int i = tid; i < 64 * 16; i += 512) {
        int t = i >> 4, dc = i & 15;
        *(bf8_t*)&X7[t][dc * 8] = ((const bf8_t*)(latbuf + (size_t)min(e0 + t, E1) * 128))[dc];
    }

    // scalars1 pass: ss/vv from feat2 x env1, streamed from global
    {
        const int t = tid >> 3, cg = tid & 7;
        const int e = min(e0 + t, E1);
        const int nd = eidx[e];
        const u16* fp = featbuf + (size_t)e * 128 + cg * 16;
        const u16* gp = env1b + (size_t)nd * 128 + cg * 16;
        bf8_t fA = *(const bf8_t*)fp;
        bf8_t fB = *(const bf8_t*)(fp + 8);
        bf8_t gA = *(const bf8_t*)gp;
        bf8_t gB = *(const bf8_t*)(gp + 8);
        bf4_t ssv, vvv;
#pragma unroll
        for (int c = 0; c < 4; ++c) {
            float f0, f1, f2, f3, g0, g1, g2, g3;
            if (c < 2) {
                f0 = bf2f((u16)fA[4 * c]);     g0 = bf2f((u16)gA[4 * c]);
                f1 = bf2f((u16)fA[4 * c + 1]); g1 = bf2f((u16)gA[4 * c + 1]);
                f2 = bf2f((u16)fA[4 * c + 2]); g2 = bf2f((u16)gA[4 * c + 2]);
                f3 = bf2f((u16)fA[4 * c + 3]); g3 = bf2f((u16)gA[4 * c + 3]);
            } else {
                int cc = c - 2;
                f0 = bf2f((u16)fB[4 * cc]);     g0 = bf2f((u16)gB[4 * cc]);
                f1 = bf2f((u16)fB[4 * cc + 1]); g1 = bf2f((u16)gB[4 * cc + 1]);
                f2 = bf2f((u16)fB[4 * cc + 2]); g2 = bf2f((u16)gB[4 * cc + 2]);
                f3 = bf2f((u16)fB[4 * cc + 3]); g3 = bf2f((u16)gB[4 * cc + 3]);
            }
            ssv[c] = (short)f2bf(f0 * g0);
            vvv[c] = (short)f2bf((f1 * g1 + f2 * g2 + f3 * g3) * INV_SQRT3);
        }
        *(bf4_t*)&X7[t][128 + 4 * cg] = ssv;
        *(bf4_t*)&X7[t][160 + 4 * cg] = vvv;
    }
    __syncthreads();

    const f4_t z = {0.f, 0.f, 0.f, 0.f};
    f4_t acc[4];
#pragma unroll
    for (int n = 0; n < 4; ++n) acc[n] = z;
    gemm_strip<6, 4>(&X7[s4 * 16][0], 200, Whf0 + ch * 64 * 192, Wlf0 + ch * 64 * 192, 192, lane, acc);
    // Hs is a fresh region (no overlay) -> no barrier needed before the writes
#pragma unroll
    for (int n = 0; n < 4; ++n)
#pragma unroll
        for (int jj = 0; jj < 4; ++jj)
            Hs[s4 * 16 + q * 4 + jj][ch * 64 + n * 16 + r] = f2bf(silu_f(acc[n][jj] * RSQRT192));
    __syncthreads();

#pragma unroll
    for (int n = 0; n < 4; ++n) acc[n] = z;
    gemm_strip<4, 4>(&Hs[s4 * 16][0], 136, Whf1 + ch * 64 * 128, Wlf1 + ch * 64 * 128, 128, lane, acc);
#pragma unroll
    for (int n = 0; n < 4; ++n)
#pragma unroll
        for (int jj = 0; jj < 4; ++jj) {
            int row = s4 * 16 + q * 4 + jj, cc = ch * 64 + n * 16 + r;
            int e = e0 + row;
            if (e < E)
                outp[(size_t)e * 128 + cc] =
                    SQ23 * bf2f(X7[row][cc]) + SQ13 * (acc[n][jj] * RSQRT128);
        }
}

extern "C" void kernel_launch(void* const* d_in, const int* in_sizes, int n_in,
                              void* d_out, int out_size, void* d_ws, size_t ws_size,
                              hipStream_t stream)
{
    const int E  = in_sizes[0] / 2;
    const int NN = 12500;

    const int*   eidx    = (const int*)d_in[0];
    const float* attr    = (const float*)d_in[1];
    const float* inv     = (const float*)d_in[2];
    float* outp = (float*)d_out;

    // ws: lat bf16 | feat bf16 | env0b, env1b bf16 | weights | sort ints
    u16* latbuf  = (u16*)d_ws;
    u16* featbuf = latbuf + (size_t)E * 128;
    u16* env0b   = featbuf + (size_t)E * 128;
    u16* env1b   = env0b + (size_t)NN * 128;
    u16* p = env1b + (size_t)NN * 128;
    auto carve = [&](int elems) { u16* q0 = p; p += elems; return q0; };
    u16 *Wh2b0 = carve(128 * 32),  *Wl2b0 = carve(128 * 32);
    u16 *Wh2b1 = carve(128 * 128), *Wl2b1 = carve(128 * 128);
    u16 *Whe0  = carve(128 * 128), *Wle0  = carve(128 * 128);
    u16 *Whl10 = carve(128 * 192), *Wll10 = carve(128 * 192);
    u16 *Whl11 = carve(128 * 128), *Wll11 = carve(128 * 128);
    u16 *Whe1  = carve(64 * 128),  *Wle1  = carve(64 * 128);
    u16 *Whs0  = carve(32 * 64),   *Wls0  = carve(32 * 64);
    u16 *Whv0  = carve(32 * 64),   *Wlv0  = carve(32 * 64);
    u16 *Whf0  = carve(128 * 192), *Wlf0  = carve(128 * 192);
    u16 *Whf1  = carve(128 * 128), *Wlf1  = carve(128 * 128);
    int* cnt;
    {
        size_t off_bytes = (size_t)((char*)p - (char*)d_ws);
        off_bytes = (off_bytes + 3) & ~(size_t)3;
        cnt = (int*)((char*)d_ws + off_bytes);
    }
    int* base   = cnt + NN;          // NN+1 entries
    int* cursor = base + NN + 1;
    int* sorted = cursor + NN;

    // env_e scratch: reuse d_out (fully overwritten by phaseC afterwards)
    u16* enve = (u16*)d_out;

    hipMemsetAsync(cnt, 0, NN * sizeof(int), stream);

    // ---- weight prep (one kernel) ----
    PDs P;
    auto setpd = [&](int i, const float* s, u16* h, u16* l, int K, int N, int Kp, int pm, int off) {
        P.d[i] = {s, h, l, K, N, Kp, pm, off, N * Kp};
    };
    setpd(0, (const float*)d_in[3],  Wh2b0, Wl2b0,   8, 128,  32, 0, 0);
    setpd(1, (const float*)d_in[4],  Wh2b1, Wl2b1, 128, 128, 128, 0, 4096);
    setpd(2, (const float*)d_in[5],  Whe0,  Wle0,  128, 128, 128, 0, 20480);
    setpd(3, (const float*)d_in[6],  Whl10, Wll10, 192, 128, 192, 1, 36864);
    setpd(4, (const float*)d_in[7],  Whl11, Wll11, 128, 128, 128, 0, 61440);
    setpd(5, (const float*)d_in[8],  Whe1,  Wle1,  128,  64, 128, 0, 77824);
    setpd(6, (const float*)d_in[9],  Whs0,  Wls0,   64,  32,  64, 0, 86016);
    setpd(7, (const float*)d_in[10], Whv0,  Wlv0,   64,  32,  64, 0, 88064);
    setpd(8, (const float*)d_in[11], Whf0,  Wlf0,  192, 128, 192, 1, 90112);
    setpd(9, (const float*)d_in[12], Whf1,  Wlf1,  128, 128, 128, 0, 114688);
    const int total = 131072;
    prep_all<<<(total + 255) / 256, 256, 0, stream>>>(P, total);

    // ---- counting sort of edges by center node ----
    hist_k<<<(E + 255) / 256, 256, 0, stream>>>(eidx, cnt, E);
    scan_k<<<1, 1024, 0, stream>>>(cnt, base, cursor, NN);
    scatter_k<<<(E + 255) / 256, 256, 0, stream>>>(eidx, cursor, sorted, E);

    const int nb = (E + 63) / 64;
    phaseA<<<nb, 512, 0, stream>>>(attr, inv, Wh2b0, Wl2b0, Wh2b1, Wl2b1,
                                   Whe0, Wle0, latbuf, featbuf, enve, E);
    reduce_env<<<(NN + 1) / 2, 256, 0, stream>>>(base, sorted, enve, env0b, NN);
    phaseB<<<nb, 512, 0, stream>>>(eidx, attr, env0b, Whs0, Wls0, Whv0, Wlv0,
                                   Whl10, Wll10, Whl11, Wll11, Whe1, Wle1,
                                   latbuf, featbuf, enve, E);
    reduce_env<<<(NN + 1) / 2, 256, 0, stream>>>(base, sorted, enve, env1b, NN);
    phaseC<<<nb, 512, 0, stream>>>(eidx, env1b, Whf0, Wlf0, Whf1, Wlf1,
                                   latbuf, featbuf, outp, E);
}

// Round 2
// 430.340 us; speedup vs baseline: 2.3830x; 2.3830x over previous
//
#include <hip/hip_runtime.h>

typedef __attribute__((ext_vector_type(8))) short bf8_t;   // 8 x bf16 (4 VGPRs)
typedef __attribute__((ext_vector_type(4))) short bf4_t;   // 4 x bf16 (2 VGPRs)
typedef __attribute__((ext_vector_type(4))) float f4_t;    // 4 x fp32 acc
typedef unsigned short u16;

#define MFMA16 __builtin_amdgcn_mfma_f32_16x16x32_bf16

#define RSQRT8    0.35355339059327373f
#define RSQRT128  0.08838834764831845f
#define RSQRT192  0.07216878364870323f
#define RSQRT64   0.125f
#define INV_SQRT3 0.57735026918962576f
#define SEG_NORM  0.25f       /* 1/sqrt(16) */
#define C_HALF    0.70710678118654752f
#define SQ23      0.81649658092772603f
#define SQ13      0.57735026918962576f

__device__ __forceinline__ float bf2f(u16 b) {
    return __uint_as_float(((unsigned int)b) << 16);
}
__device__ __forceinline__ u16 f2bf(float f) {
    unsigned int u = __float_as_uint(f);
    u += 0x7FFFu + ((u >> 16) & 1u);           // round-to-nearest-even
    return (u16)(u >> 16);
}
__device__ __forceinline__ float silu_f(float x) { return x / (1.0f + __expf(-x)); }

// ---------------------------------------------------------------------------
// gemm_rows: one wave owns ONE 16-col tile (weights pre-offset by caller) and
// sweeps NSTR row-strips of 16. B-fragment loaded ONCE per k-step (wave-
// contiguous 1KB in fragment-linear layout = 8 fully-used lines), then reused
// for NSTR independent MFMA chains. This is the line-miss-count fix.
// FP order per output: ks ascending, lo-then-hi — identical to previous.
// ---------------------------------------------------------------------------
template<int KS, int NSTR>
__device__ __forceinline__ void gemm_rows(
    const u16* A, int as,
    const u16* __restrict__ Wh, const u16* __restrict__ Wl,
    int lane, f4_t* acc)
{
    const int r = lane & 15;
    const int q = lane >> 4;
    const u16* ab = A + r * as + q * 8;
#pragma unroll
    for (int ks = 0; ks < KS; ++ks) {
        bf8_t bh = *(const bf8_t*)(Wh + (ks * 64 + lane) * 8);
        bf8_t bl = *(const bf8_t*)(Wl + (ks * 64 + lane) * 8);
#pragma unroll
        for (int s = 0; s < NSTR; ++s) {
            bf8_t a = *(const bf8_t*)(ab + s * 16 * as + ks * 32);
            acc[s] = MFMA16(a, bl, acc[s], 0, 0, 0);
            acc[s] = MFMA16(a, bh, acc[s], 0, 0, 0);
        }
    }
}

// env_weight epilogue store: weight col w (0..63 within half) -> channels.
__device__ __forceinline__ void env_store(u16* dst, int w, float val, float4 av)
{
    int m = w >> 1;
    if ((w & 1) == 0) {
        dst[4 * m] = f2bf(val * av.x);
    } else {
        dst[4 * m + 1] = f2bf(val * av.y);
        dst[4 * m + 2] = f2bf(val * av.z);
        dst[4 * m + 3] = f2bf(val * av.w);
    }
}

// ---------------------------------------------------------------------------
// Weight prep: fp32 [K][N] -> bf16 hi/lo in FRAGMENT-LINEAR layout:
// element index = ((tile*KS + ks)*64 + lane)*8 + j  holds
// W^T[col = tile*16 + (lane&15)][k = ks*32 + (lane>>4)*8 + j].
// A wave's B-load for (tile,ks) is then 64 lanes x 16B contiguous (1KB).
// ---------------------------------------------------------------------------
struct PD { const float* src; u16* hi; u16* lo; int K, N, Kp, perm, off, cnt; };
struct PDs { PD d[10]; };

__global__ __launch_bounds__(256) void prep_all(PDs P, int total)
{
    int i = blockIdx.x * 256 + threadIdx.x;
    if (i >= total) return;
#pragma unroll
    for (int rg = 0; rg < 10; ++rg) {
        if (i >= P.d[rg].off && i < P.d[rg].off + P.d[rg].cnt) {
            int li = i - P.d[rg].off;
            int KS = P.d[rg].Kp >> 5;
            int tile = li / (KS * 512);
            int rem  = li - tile * KS * 512;
            int ks   = rem >> 9;
            int lane = (rem >> 3) & 63;
            int j    = rem & 7;
            int n = tile * 16 + (lane & 15);
            int k = ks * 32 + (lane >> 4) * 8 + j;
            int ksrc = k;
            if (P.d[rg].perm && k >= 128)
                ksrc = (k < 160) ? (128 + 2 * (k - 128)) : (129 + 2 * (k - 160));
            float wv = (ksrc < P.d[rg].K) ? P.d[rg].src[(size_t)ksrc * P.d[rg].N + n] : 0.f;
            u16 h = f2bf(wv);
            P.d[rg].hi[li] = h;
            P.d[rg].lo[li] = f2bf(wv - bf2f(h));
        }
    }
}

// ---------------------------------------------------------------------------
// Counting sort of edges by center node.
// ---------------------------------------------------------------------------
__global__ __launch_bounds__(256) void hist_k(const int* __restrict__ eidx,
                                              int* __restrict__ cnt, int E)
{
    int i = blockIdx.x * 256 + threadIdx.x;
    if (i < E) atomicAdd(&cnt[eidx[i]], 1);
}

__global__ __launch_bounds__(1024) void scan_k(const int* __restrict__ cnt,
                                               int* __restrict__ base,
                                               int* __restrict__ cursor, int NN)
{
    __shared__ int part[1024];
    const int t = threadIdx.x;
    const int CHK = (NN + 1023) >> 10;
    int s = 0;
    for (int k = 0; k < CHK; ++k) { int idx = t * CHK + k; if (idx < NN) s += cnt[idx]; }
    part[t] = s;
    __syncthreads();
    for (int off = 1; off < 1024; off <<= 1) {
        int v = (t >= off) ? part[t - off] : 0;
        __syncthreads();
        part[t] += v;
        __syncthreads();
    }
    if (t == 0) base[NN] = part[1023];
    int run = (t == 0) ? 0 : part[t - 1];
    for (int k = 0; k < CHK; ++k) {
        int idx = t * CHK + k;
        if (idx < NN) { base[idx] = run; cursor[idx] = run; run += cnt[idx]; }
    }
}

__global__ __launch_bounds__(256) void scatter_k(const int* __restrict__ eidx,
                                                 int* __restrict__ cursor,
                                                 int* __restrict__ sorted, int E)
{
    int i = blockIdx.x * 256 + threadIdx.x;
    if (i < E) {
        int p = atomicAdd(&cursor[eidx[i]], 1);
        sorted[p] = i;
    }
}

// ---------------------------------------------------------------------------
// Segment reduction: env[node] = (sum over node's edges of env_e) * SEG_NORM.
// ---------------------------------------------------------------------------
__global__ __launch_bounds__(256) void reduce_env(
    const int* __restrict__ base, const int* __restrict__ sorted,
    const u16* __restrict__ enve, u16* __restrict__ env, int NN)
{
    const int half = __builtin_amdgcn_readfirstlane(threadIdx.x >> 7);
    const int node = blockIdx.x * 2 + half;
    const int ch = threadIdx.x & 127;
    if (node >= NN) return;
    const int b = base[node], en = base[node + 1];
    float acc = 0.f;
    int i = b;
    for (; i + 3 < en; i += 4) {
        int s0 = sorted[i], s1 = sorted[i + 1], s2 = sorted[i + 2], s3 = sorted[i + 3];
        float v0 = bf2f(enve[(size_t)s0 * 128 + ch]);
        float v1 = bf2f(enve[(size_t)s1 * 128 + ch]);
        float v2 = bf2f(enve[(size_t)s2 * 128 + ch]);
        float v3 = bf2f(enve[(size_t)s3 * 128 + ch]);
        acc += (v0 + v1) + (v2 + v3);
    }
    for (; i < en; ++i) acc += bf2f(enve[(size_t)sorted[i] * 128 + ch]);
    env[(size_t)node * 128 + ch] = f2bf(acc * SEG_NORM);
}

// ---------------------------------------------------------------------------
// Phase A. 8 waves; wave w owns col tile w (16 cols), sweeps all 64 rows.
// ---------------------------------------------------------------------------
__global__ __launch_bounds__(512, 4) void phaseA(
    const float* __restrict__ attr, const float* __restrict__ inv,
    const u16* __restrict__ Wh2b0, const u16* __restrict__ Wl2b0,
    const u16* __restrict__ Wh2b1, const u16* __restrict__ Wl2b1,
    const u16* __restrict__ Whenv0, const u16* __restrict__ Wlenv0,
    u16* __restrict__ latbuf, u16* __restrict__ featbuf,
    u16* __restrict__ enve, int E)
{
    __shared__ __align__(16) char sm[39936];
    u16 (*Xi)[32]  = (u16 (*)[32])sm;                     // 4096
    u16 (*Hs)[136] = (u16 (*)[136])(sm + 4096);           // 17408
    u16 (*Ls)[136] = (u16 (*)[136])(sm + 21504);          // 17408
    float (*sattr)[4] = (float (*)[4])(sm + 38912);       // 1024

    const int tid = threadIdx.x;
    const int lane = tid & 63;
    const int w = tid >> 6;
    const int e0 = blockIdx.x * 64;
    const int E1 = E - 1;
    const int r = lane & 15, q = lane >> 4;

    for (int i = tid; i < 64 * 32; i += 512) {
        int t = i >> 5, c = i & 31;
        u16 v = 0;
        if (c < 8) v = f2bf(inv[(size_t)min(e0 + t, E1) * 8 + c]);
        Xi[t][c] = v;
    }
    if (tid < 256) { int t = tid >> 2, c = tid & 3; sattr[t][c] = attr[(size_t)min(e0 + t, E1) * 4 + c]; }
    __syncthreads();

    const f4_t z = {0.f, 0.f, 0.f, 0.f};
    f4_t acc[4];

    // GEMM1: inv(8->32) @ W2b0 -> silu -> Hs
#pragma unroll
    for (int s = 0; s < 4; ++s) acc[s] = z;
    gemm_rows<1, 4>(&Xi[0][0], 32, Wh2b0 + w * 512, Wl2b0 + w * 512, lane, acc);
#pragma unroll
    for (int s = 0; s < 4; ++s)
#pragma unroll
        for (int jj = 0; jj < 4; ++jj)
            Hs[s * 16 + q * 4 + jj][w * 16 + r] = f2bf(silu_f(acc[s][jj] * RSQRT8));
    __syncthreads();

    // GEMM2: h(128) @ W2b1 -> lat -> Ls + latbuf
#pragma unroll
    for (int s = 0; s < 4; ++s) acc[s] = z;
    gemm_rows<4, 4>(&Hs[0][0], 136, Wh2b1 + w * 4 * 512, Wl2b1 + w * 4 * 512, lane, acc);
#pragma unroll
    for (int s = 0; s < 4; ++s)
#pragma unroll
        for (int jj = 0; jj < 4; ++jj) {
            int row = s * 16 + q * 4 + jj, cc = w * 16 + r;
            u16 b = f2bf(acc[s][jj] * RSQRT128);
            Ls[row][cc] = b;
            int e = e0 + row;
            if (e < E) latbuf[(size_t)e * 128 + cc] = b;
        }
    __syncthreads();

    // GEMM3: lat(128) @ Wenv0 -> w0; env_weight stores from accumulators.
#pragma unroll
    for (int s = 0; s < 4; ++s) acc[s] = z;
    gemm_rows<4, 4>(&Ls[0][0], 136, Whenv0 + w * 4 * 512, Wlenv0 + w * 4 * 512, lane, acc);
    {
        const int col = w * 16 + r;
        u16* dstbase = (col < 64) ? featbuf : enve;
        const int wcol = col & 63;
#pragma unroll
        for (int s = 0; s < 4; ++s)
#pragma unroll
            for (int jj = 0; jj < 4; ++jj) {
                int row = s * 16 + q * 4 + jj;
                int e = e0 + row;
                if (e >= E) continue;
                float4 av = *(const float4*)&sattr[row][0];
                env_store(dstbase + (size_t)e * 128, wcol, acc[s][jj] * RSQRT128, av);
            }
    }
}

// ---------------------------------------------------------------------------
// Phase B: tensor products (streamed from global) + mix; new_lat MLP; lat2;
// w1 -> env_e rows. Col-tile-per-wave GEMMs.
// ---------------------------------------------------------------------------
__global__ __launch_bounds__(512, 6) void phaseB(
    const int* __restrict__ eidx, const float* __restrict__ attr,
    const u16* __restrict__ env0b,
    const u16* __restrict__ Whs0, const u16* __restrict__ Wls0,
    const u16* __restrict__ Whv0, const u16* __restrict__ Wlv0,
    const u16* __restrict__ Whl10, const u16* __restrict__ Wll10,
    const u16* __restrict__ Whl11, const u16* __restrict__ Wll11,
    const u16* __restrict__ Whe1, const u16* __restrict__ Wle1,
    u16* __restrict__ latbuf, u16* __restrict__ featbuf,
    u16* __restrict__ enve, int E)
{
    __shared__ __align__(16) char sm[52480];
    u16 (*X4)[200] = (u16 (*)[200])sm;                    // 25600: lat|ss|vv -> lat2
    u16 (*P)[200]  = (u16 (*)[200])(sm + 25600);          // 25600: sv|vs per dim (192 used)
    u16 (*Hs)[136] = (u16 (*)[136])(sm + 25600);          // overlay P (dead post-mix)
    float (*sattr)[4] = (float (*)[4])(sm + 51200);       // 1024

    const int tid = threadIdx.x;
    const int lane = tid & 63;
    const int w = tid >> 6;
    const int e0 = blockIdx.x * 64;
    const int E1 = E - 1;
    const int r = lane & 15, q = lane >> 4;

    if (tid < 256) { int t = tid >> 2, c = tid & 3; sattr[t][c] = attr[(size_t)min(e0 + t, E1) * 4 + c]; }

    // lat -> X4[:, 0:128]
    for (int i = tid; i < 64 * 16; i += 512) {
        int t = i >> 4, dc = i & 15;
        *(bf8_t*)&X4[t][dc * 8] = ((const bf8_t*)(latbuf + (size_t)min(e0 + t, E1) * 128))[dc];
    }

    // tensor-product pass: ss->X4[128+m], vv->X4[160+m], sv_d/vs_d -> P.
    {
        const int t = tid >> 3, cg = tid & 7;
        const int e = min(e0 + t, E1);
        const int nd = eidx[e];
        const u16* fp = featbuf + (size_t)e * 128 + cg * 16;
        const u16* gp = env0b + (size_t)nd * 128 + cg * 16;
        bf8_t fA = *(const bf8_t*)fp;
        bf8_t fB = *(const bf8_t*)(fp + 8);
        bf8_t gA = *(const bf8_t*)gp;
        bf8_t gB = *(const bf8_t*)(gp + 8);
        bf4_t ssv, vvv, svv[3], vsv[3];
#pragma unroll
        for (int c = 0; c < 4; ++c) {
            float f0, f1, f2, f3, g0, g1, g2, g3;
            if (c < 2) {
                f0 = bf2f((u16)fA[4 * c]);     g0 = bf2f((u16)gA[4 * c]);
                f1 = bf2f((u16)fA[4 * c + 1]); g1 = bf2f((u16)gA[4 * c + 1]);
                f2 = bf2f((u16)fA[4 * c + 2]); g2 = bf2f((u16)gA[4 * c + 2]);
                f3 = bf2f((u16)fA[4 * c + 3]); g3 = bf2f((u16)gA[4 * c + 3]);
            } else {
                int cc = c - 2;
                f0 = bf2f((u16)fB[4 * cc]);     g0 = bf2f((u16)gB[4 * cc]);
                f1 = bf2f((u16)fB[4 * cc + 1]); g1 = bf2f((u16)gB[4 * cc + 1]);
                f2 = bf2f((u16)fB[4 * cc + 2]); g2 = bf2f((u16)gB[4 * cc + 2]);
                f3 = bf2f((u16)fB[4 * cc + 3]); g3 = bf2f((u16)gB[4 * cc + 3]);
            }
            ssv[c] = (short)f2bf(f0 * g0);
            vvv[c] = (short)f2bf((f1 * g1 + f2 * g2 + f3 * g3) * INV_SQRT3);
            svv[0][c] = (short)f2bf(f0 * g1);
            svv[1][c] = (short)f2bf(f0 * g2);
            svv[2][c] = (short)f2bf(f0 * g3);
            vsv[0][c] = (short)f2bf(f1 * g0);
            vsv[1][c] = (short)f2bf(f2 * g0);
            vsv[2][c] = (short)f2bf(f3 * g0);
        }
        *(bf4_t*)&X4[t][128 + 4 * cg] = ssv;
        *(bf4_t*)&X4[t][160 + 4 * cg] = vvv;
#pragma unroll
        for (int d = 0; d < 3; ++d) {
            *(bf4_t*)&P[t][d * 64 + 4 * cg]      = svv[d];
            *(bf4_t*)&P[t][d * 64 + 32 + 4 * cg] = vsv[d];
        }
    }
    __syncthreads();

    const f4_t z = {0.f, 0.f, 0.f, 0.f};

    // ---- mix: wave = (strip sw, col-half cw); B-frags loaded once, shared
    // across S and all 3 V dims.
    {
        const int sw = w >> 1, cw = w & 1;
        f4_t aS = z, aV[3] = {z, z, z};
        const u16* bsh = Whs0 + cw * 2 * 512;
        const u16* bsl = Wls0 + cw * 2 * 512;
        const u16* bvh = Whv0 + cw * 2 * 512;
        const u16* bvl = Wlv0 + cw * 2 * 512;
        bf8_t s0h = *(const bf8_t*)(bsh + lane * 8);
        bf8_t s0l = *(const bf8_t*)(bsl + lane * 8);
        bf8_t s1h = *(const bf8_t*)(bsh + 512 + lane * 8);
        bf8_t s1l = *(const bf8_t*)(bsl + 512 + lane * 8);
        bf8_t v0h = *(const bf8_t*)(bvh + lane * 8);
        bf8_t v0l = *(const bf8_t*)(bvl + lane * 8);
        bf8_t v1h = *(const bf8_t*)(bvh + 512 + lane * 8);
        bf8_t v1l = *(const bf8_t*)(bvl + 512 + lane * 8);
        const u16* arow = &X4[sw * 16 + r][0];
        bf8_t a0 = *(const bf8_t*)(arow + 128 + q * 8);
        bf8_t a1 = *(const bf8_t*)(arow + 160 + q * 8);
        aS = MFMA16(a0, s0l, aS, 0, 0, 0);
        aS = MFMA16(a0, s0h, aS, 0, 0, 0);
        aS = MFMA16(a1, s1l, aS, 0, 0, 0);
        aS = MFMA16(a1, s1h, aS, 0, 0, 0);
        const u16* prow = &P[sw * 16 + r][0];
#pragma unroll
        for (int d = 0; d < 3; ++d) {
            bf8_t p0 = *(const bf8_t*)(prow + d * 64 + q * 8);
            bf8_t p1 = *(const bf8_t*)(prow + d * 64 + 32 + q * 8);
            aV[d] = MFMA16(p0, v0l, aV[d], 0, 0, 0);
            aV[d] = MFMA16(p0, v0h, aV[d], 0, 0, 0);
            aV[d] = MFMA16(p1, v1l, aV[d], 0, 0, 0);
            aV[d] = MFMA16(p1, v1h, aV[d], 0, 0, 0);
        }
        // feat2 direct to global
        const int m = cw * 16 + r;
#pragma unroll
        for (int reg = 0; reg < 4; ++reg) {
            int e = e0 + sw * 16 + q * 4 + reg;
            if (e < E) {
                u16* dst = featbuf + (size_t)e * 128 + 4 * m;
                dst[0] = f2bf(aS[reg] * RSQRT64);
                dst[1] = f2bf(aV[0][reg] * (RSQRT64 * INV_SQRT3));
                dst[2] = f2bf(aV[1][reg] * (RSQRT64 * INV_SQRT3));
                dst[3] = f2bf(aV[2][reg] * (RSQRT64 * INV_SQRT3));
            }
        }
    }

    // GEMM4: [lat|sscal](192) @ Wlat1_0
    f4_t acc[4];
#pragma unroll
    for (int s = 0; s < 4; ++s) acc[s] = z;
    gemm_rows<6, 4>(&X4[0][0], 200, Whl10 + w * 6 * 512, Wll10 + w * 6 * 512, lane, acc);
    __syncthreads();   // all P reads (mix) done -> Hs may overwrite P
#pragma unroll
    for (int s = 0; s < 4; ++s)
#pragma unroll
        for (int jj = 0; jj < 4; ++jj)
            Hs[s * 16 + q * 4 + jj][w * 16 + r] = f2bf(silu_f(acc[s][jj] * RSQRT192));
    __syncthreads();

    // GEMM5: h @ Wlat1_1 -> new_lat; lat2 = C*(lat+new_lat) in place in X4
#pragma unroll
    for (int s = 0; s < 4; ++s) acc[s] = z;
    gemm_rows<4, 4>(&Hs[0][0], 136, Whl11 + w * 4 * 512, Wll11 + w * 4 * 512, lane, acc);
#pragma unroll
    for (int s = 0; s < 4; ++s)
#pragma unroll
        for (int jj = 0; jj < 4; ++jj) {
            int row = s * 16 + q * 4 + jj, cc = w * 16 + r;
            float l2 = C_HALF * (bf2f(X4[row][cc]) + acc[s][jj] * RSQRT128);
            X4[row][cc] = f2bf(l2);      // cell owned by this lane-reg only
        }
    __syncthreads();

    // lat2 -> latbuf ; GEMM6: lat2 @ Wenv1(128x64) -> w1 -> env_e rows
    for (int i = tid; i < 64 * 16; i += 512) {
        int t = i >> 4, dc = i & 15;
        int e = e0 + t;
        if (e < E) ((bf8_t*)(latbuf + (size_t)e * 128))[dc] = *(const bf8_t*)&X4[t][dc * 8];
    }
    {
        const int ct = w & 3, rh = w >> 2;   // col tile 0..3, row half 0..1
        f4_t a6[2] = {z, z};
        gemm_rows<4, 2>(&X4[rh * 32][0], 200, Whe1 + ct * 4 * 512, Wle1 + ct * 4 * 512, lane, a6);
        const int col = ct * 16 + r;         // 0..63
#pragma unroll
        for (int s = 0; s < 2; ++s)
#pragma unroll
            for (int jj = 0; jj < 4; ++jj) {
                int row = rh * 32 + s * 16 + q * 4 + jj;
                int e = e0 + row;
                if (e >= E) continue;
                float4 av = *(const float4*)&sattr[row][0];
                env_store(enve + (size_t)e * 128, col, a6[s][jj] * RSQRT128, av);
            }
    }
}

// ---------------------------------------------------------------------------
// Phase C: scalars1 streamed from global, final MLP, out mix.
// ---------------------------------------------------------------------------
__global__ __launch_bounds__(512, 6) void phaseC(
    const int* __restrict__ eidx, const u16* __restrict__ env1b,
    const u16* __restrict__ Whf0, const u16* __restrict__ Wlf0,
    const u16* __restrict__ Whf1, const u16* __restrict__ Wlf1,
    const u16* __restrict__ latbuf, const u16* __restrict__ featbuf,
    float* __restrict__ outp, int E)
{
    __shared__ __align__(16) char sm[43008];
    u16 (*X7)[200] = (u16 (*)[200])sm;                    // 25600: lat2|scal1
    u16 (*Hs)[136] = (u16 (*)[136])(sm + 25600);          // 17408

    const int tid = threadIdx.x;
    const int lane = tid & 63;
    const int w = tid >> 6;
    const int e0 = blockIdx.x * 64;
    const int E1 = E - 1;
    const int r = lane & 15, q = lane >> 4;

    // lat2 -> X7[:, 0:128]
    for (int i = tid; i < 64 * 16; i += 512) {
        int t = i >> 4, dc = i & 15;
        *(bf8_t*)&X7[t][dc * 8] = ((const bf8_t*)(latbuf + (size_t)min(e0 + t, E1) * 128))[dc];
    }

    // scalars1 pass: ss/vv from feat2 x env1, streamed from global
    {
        const int t = tid >> 3, cg = tid & 7;
        const int e = min(e0 + t, E1);
        const int nd = eidx[e];
        const u16* fp = featbuf + (size_t)e * 128 + cg * 16;
        const u16* gp = env1b + (size_t)nd * 128 + cg * 16;
        bf8_t fA = *(const bf8_t*)fp;
        bf8_t fB = *(const bf8_t*)(fp + 8);
        bf8_t gA = *(const bf8_t*)gp;
        bf8_t gB = *(const bf8_t*)(gp + 8);
        bf4_t ssv, vvv;
#pragma unroll
        for (int c = 0; c < 4; ++c) {
            float f0, f1, f2, f3, g0, g1, g2, g3;
            if (c < 2) {
                f0 = bf2f((u16)fA[4 * c]);     g0 = bf2f((u16)gA[4 * c]);
                f1 = bf2f((u16)fA[4 * c + 1]); g1 = bf2f((u16)gA[4 * c + 1]);
                f2 = bf2f((u16)fA[4 * c + 2]); g2 = bf2f((u16)gA[4 * c + 2]);
                f3 = bf2f((u16)fA[4 * c + 3]); g3 = bf2f((u16)gA[4 * c + 3]);
            } else {
                int cc = c - 2;
                f0 = bf2f((u16)fB[4 * cc]);     g0 = bf2f((u16)gB[4 * cc]);
                f1 = bf2f((u16)fB[4 * cc + 1]); g1 = bf2f((u16)gB[4 * cc + 1]);
                f2 = bf2f((u16)fB[4 * cc + 2]); g2 = bf2f((u16)gB[4 * cc + 2]);
                f3 = bf2f((u16)fB[4 * cc + 3]); g3 = bf2f((u16)gB[4 * cc + 3]);
            }
            ssv[c] = (short)f2bf(f0 * g0);
            vvv[c] = (short)f2bf((f1 * g1 + f2 * g2 + f3 * g3) * INV_SQRT3);
        }
        *(bf4_t*)&X7[t][128 + 4 * cg] = ssv;
        *(bf4_t*)&X7[t][160 + 4 * cg] = vvv;
    }
    __syncthreads();

    const f4_t z = {0.f, 0.f, 0.f, 0.f};
    f4_t acc[4];
#pragma unroll
    for (int s = 0; s < 4; ++s) acc[s] = z;
    gemm_rows<6, 4>(&X7[0][0], 200, Whf0 + w * 6 * 512, Wlf0 + w * 6 * 512, lane, acc);
    // Hs is a fresh region (disjoint from X7) -> no barrier needed before writes
#pragma unroll
    for (int s = 0; s < 4; ++s)
#pragma unroll
        for (int jj = 0; jj < 4; ++jj)
            Hs[s * 16 + q * 4 + jj][w * 16 + r] = f2bf(silu_f(acc[s][jj] * RSQRT192));
    __syncthreads();

#pragma unroll
    for (int s = 0; s < 4; ++s) acc[s] = z;
    gemm_rows<4, 4>(&Hs[0][0], 136, Whf1 + w * 4 * 512, Wlf1 + w * 4 * 512, lane, acc);
#pragma unroll
    for (int s = 0; s < 4; ++s)
#pragma unroll
        for (int jj = 0; jj < 4; ++jj) {
            int row = s * 16 + q * 4 + jj, cc = w * 16 + r;
            int e = e0 + row;
            if (e < E)
                outp[(size_t)e * 128 + cc] =
                    SQ23 * bf2f(X7[row][cc]) + SQ13 * (acc[s][jj] * RSQRT128);
        }
}

extern "C" void kernel_launch(void* const* d_in, const int* in_sizes, int n_in,
                              void* d_out, int out_size, void* d_ws, size_t ws_size,
                              hipStream_t stream)
{
    const int E  = in_sizes[0] / 2;
    const int NN = 12500;

    const int*   eidx    = (const int*)d_in[0];
    const float* attr    = (const float*)d_in[1];
    const float* inv     = (const float*)d_in[2];
    float* outp = (float*)d_out;

    // ws: lat bf16 | feat bf16 | env0b, env1b bf16 | weights | sort ints
    u16* latbuf  = (u16*)d_ws;
    u16* featbuf = latbuf + (size_t)E * 128;
    u16* env0b   = featbuf + (size_t)E * 128;
    u16* env1b   = env0b + (size_t)NN * 128;
    u16* p = env1b + (size_t)NN * 128;
    auto carve = [&](int elems) { u16* q0 = p; p += elems; return q0; };
    u16 *Wh2b0 = carve(128 * 32),  *Wl2b0 = carve(128 * 32);
    u16 *Wh2b1 = carve(128 * 128), *Wl2b1 = carve(128 * 128);
    u16 *Whe0  = carve(128 * 128), *Wle0  = carve(128 * 128);
    u16 *Whl10 = carve(128 * 192), *Wll10 = carve(128 * 192);
    u16 *Whl11 = carve(128 * 128), *Wll11 = carve(128 * 128);
    u16 *Whe1  = carve(64 * 128),  *Wle1  = carve(64 * 128);
    u16 *Whs0  = carve(32 * 64),   *Wls0  = carve(32 * 64);
    u16 *Whv0  = carve(32 * 64),   *Wlv0  = carve(32 * 64);
    u16 *Whf0  = carve(128 * 192), *Wlf0  = carve(128 * 192);
    u16 *Whf1  = carve(128 * 128), *Wlf1  = carve(128 * 128);
    int* cnt;
    {
        size_t off_bytes = (size_t)((char*)p - (char*)d_ws);
        off_bytes = (off_bytes + 3) & ~(size_t)3;
        cnt = (int*)((char*)d_ws + off_bytes);
    }
    int* base   = cnt + NN;          // NN+1 entries
    int* cursor = base + NN + 1;
    int* sorted = cursor + NN;

    // env_e scratch: reuse d_out (fully overwritten by phaseC afterwards)
    u16* enve = (u16*)d_out;

    hipMemsetAsync(cnt, 0, NN * sizeof(int), stream);

    // ---- weight prep (one kernel) ----
    PDs P;
    auto setpd = [&](int i, const float* s, u16* h, u16* l, int K, int N, int Kp, int pm, int off) {
        P.d[i] = {s, h, l, K, N, Kp, pm, off, N * Kp};
    };
    setpd(0, (const float*)d_in[3],  Wh2b0, Wl2b0,   8, 128,  32, 0, 0);
    setpd(1, (const float*)d_in[4],  Wh2b1, Wl2b1, 128, 128, 128, 0, 4096);
    setpd(2, (const float*)d_in[5],  Whe0,  Wle0,  128, 128, 128, 0, 20480);
    setpd(3, (const float*)d_in[6],  Whl10, Wll10, 192, 128, 192, 1, 36864);
    setpd(4, (const float*)d_in[7],  Whl11, Wll11, 128, 128, 128, 0, 61440);
    setpd(5, (const float*)d_in[8],  Whe1,  Wle1,  128,  64, 128, 0, 77824);
    setpd(6, (const float*)d_in[9],  Whs0,  Wls0,   64,  32,  64, 0, 86016);
    setpd(7, (const float*)d_in[10], Whv0,  Wlv0,   64,  32,  64, 0, 88064);
    setpd(8, (const float*)d_in[11], Whf0,  Wlf0,  192, 128, 192, 1, 90112);
    setpd(9, (const float*)d_in[12], Whf1,  Wlf1,  128, 128, 128, 0, 114688);
    const int total = 131072;
    prep_all<<<(total + 255) / 256, 256, 0, stream>>>(P, total);

    // ---- counting sort of edges by center node ----
    hist_k<<<(E + 255) / 256, 256, 0, stream>>>(eidx, cnt, E);
    scan_k<<<1, 1024, 0, stream>>>(cnt, base, cursor, NN);
    scatter_k<<<(E + 255) / 256, 256, 0, stream>>>(eidx, cursor, sorted, E);

    const int nb = (E + 63) / 64;
    phaseA<<<nb, 512, 0, stream>>>(attr, inv, Wh2b0, Wl2b0, Wh2b1, Wl2b1,
                                   Whe0, Wle0, latbuf, featbuf, enve, E);
    reduce_env<<<(NN + 1) / 2, 256, 0, stream>>>(base, sorted, enve, env0b, NN);
    phaseB<<<nb, 512, 0, stream>>>(eidx, attr, env0b, Whs0, Wls0, Whv0, Wlv0,
                                   Whl10, Wll10, Whl11, Wll11, Whe1, Wle1,
                                   latbuf, featbuf, enve, E);
    reduce_env<<<(NN + 1) / 2, 256, 0, stream>>>(base, sorted, enve, env1b, NN);
    phaseC<<<nb, 512, 0, stream>>>(eidx, env1b, Whf0, Wlf0, Whf1, Wlf1,
                                   latbuf, featbuf, outp, E);
}

// Round 3
// 416.293 us; speedup vs baseline: 2.4634x; 1.0337x over previous
//
#include <hip/hip_runtime.h>

typedef __attribute__((ext_vector_type(8))) short bf8_t;   // 8 x bf16 (4 VGPRs)
typedef __attribute__((ext_vector_type(4))) short bf4_t;   // 4 x bf16 (2 VGPRs)
typedef __attribute__((ext_vector_type(4))) float f4_t;    // 4 x fp32 acc
typedef unsigned short u16;

#define MFMA16 __builtin_amdgcn_mfma_f32_16x16x32_bf16

#define RSQRT8    0.35355339059327373f
#define RSQRT128  0.08838834764831845f
#define RSQRT192  0.07216878364870323f
#define RSQRT64   0.125f
#define INV_SQRT3 0.57735026918962576f
#define SEG_NORM  0.25f       /* 1/sqrt(16) */
#define C_HALF    0.70710678118654752f
#define SQ23      0.81649658092772603f
#define SQ13      0.57735026918962576f

__device__ __forceinline__ float bf2f(u16 b) {
    return __uint_as_float(((unsigned int)b) << 16);
}
__device__ __forceinline__ u16 f2bf(float f) {
    unsigned int u = __float_as_uint(f);
    u += 0x7FFFu + ((u >> 16) & 1u);           // round-to-nearest-even
    return (u16)(u >> 16);
}
__device__ __forceinline__ float silu_f(float x) { return x / (1.0f + __expf(-x)); }

// ---------------------------------------------------------------------------
// gemm_rows: one wave owns ONE 16-col tile (weights pre-offset by caller) and
// sweeps NSTR row-strips of 16. B-fragments are PRELOADED into registers in
// chunks of <=4 k-steps (explicit batching -> L2 latency paid ~once per chunk
// instead of per load; VGPR cost 16-32), then the MFMA loop runs pure
// ds_read+MFMA. AS is a compile-time LDS row stride so A addresses fold into
// ds_read offset immediates. FP order per output: ks ascending, lo-then-hi.
// ---------------------------------------------------------------------------
template<int KS, int NSTR, int AS>
__device__ __forceinline__ void gemm_rows(
    const u16* A,
    const u16* __restrict__ Wh, const u16* __restrict__ Wl,
    int lane, f4_t* acc)
{
    const int r = lane & 15;
    const int q = lane >> 4;
    const u16* ab = A + r * AS + q * 8;
    constexpr int CH = (KS > 4) ? 3 : KS;     // 6 -> 2 chunks of 3; else 1 chunk
#pragma unroll
    for (int c0 = 0; c0 < KS; c0 += CH) {
        bf8_t bh[CH], bl[CH];
#pragma unroll
        for (int j = 0; j < CH; ++j) {
            bh[j] = *(const bf8_t*)(Wh + ((c0 + j) * 64 + lane) * 8);
            bl[j] = *(const bf8_t*)(Wl + ((c0 + j) * 64 + lane) * 8);
        }
#pragma unroll
        for (int j = 0; j < CH; ++j) {
#pragma unroll
            for (int s = 0; s < NSTR; ++s) {
                bf8_t a = *(const bf8_t*)(ab + s * 16 * AS + (c0 + j) * 32);
                acc[s] = MFMA16(a, bl[j], acc[s], 0, 0, 0);
                acc[s] = MFMA16(a, bh[j], acc[s], 0, 0, 0);
            }
        }
    }
}

// env_weight epilogue store: weight col w (0..63 within half) -> channels.
__device__ __forceinline__ void env_store(u16* dst, int w, float val, float4 av)
{
    int m = w >> 1;
    if ((w & 1) == 0) {
        dst[4 * m] = f2bf(val * av.x);
    } else {
        dst[4 * m + 1] = f2bf(val * av.y);
        dst[4 * m + 2] = f2bf(val * av.z);
        dst[4 * m + 3] = f2bf(val * av.w);
    }
}

// ---------------------------------------------------------------------------
// Weight prep: fp32 [K][N] -> bf16 hi/lo in FRAGMENT-LINEAR layout:
// element index = ((tile*KS + ks)*64 + lane)*8 + j  holds
// W^T[col = tile*16 + (lane&15)][k = ks*32 + (lane>>4)*8 + j].
// ---------------------------------------------------------------------------
struct PD { const float* src; u16* hi; u16* lo; int K, N, Kp, perm, off, cnt; };
struct PDs { PD d[10]; };

__global__ __launch_bounds__(256) void prep_all(PDs P, int total)
{
    int i = blockIdx.x * 256 + threadIdx.x;
    if (i >= total) return;
#pragma unroll
    for (int rg = 0; rg < 10; ++rg) {
        if (i >= P.d[rg].off && i < P.d[rg].off + P.d[rg].cnt) {
            int li = i - P.d[rg].off;
            int KS = P.d[rg].Kp >> 5;
            int tile = li / (KS * 512);
            int rem  = li - tile * KS * 512;
            int ks   = rem >> 9;
            int lane = (rem >> 3) & 63;
            int j    = rem & 7;
            int n = tile * 16 + (lane & 15);
            int k = ks * 32 + (lane >> 4) * 8 + j;
            int ksrc = k;
            if (P.d[rg].perm && k >= 128)
                ksrc = (k < 160) ? (128 + 2 * (k - 128)) : (129 + 2 * (k - 160));
            float wv = (ksrc < P.d[rg].K) ? P.d[rg].src[(size_t)ksrc * P.d[rg].N + n] : 0.f;
            u16 h = f2bf(wv);
            P.d[rg].hi[li] = h;
            P.d[rg].lo[li] = f2bf(wv - bf2f(h));
        }
    }
}

// ---------------------------------------------------------------------------
// Counting sort of edges by center node.
// ---------------------------------------------------------------------------
__global__ __launch_bounds__(256) void hist_k(const int* __restrict__ eidx,
                                              int* __restrict__ cnt, int E)
{
    int i = blockIdx.x * 256 + threadIdx.x;
    if (i < E) atomicAdd(&cnt[eidx[i]], 1);
}

__global__ __launch_bounds__(1024) void scan_k(const int* __restrict__ cnt,
                                               int* __restrict__ base,
                                               int* __restrict__ cursor, int NN)
{
    __shared__ int part[1024];
    const int t = threadIdx.x;
    const int CHK = (NN + 1023) >> 10;
    int s = 0;
    for (int k = 0; k < CHK; ++k) { int idx = t * CHK + k; if (idx < NN) s += cnt[idx]; }
    part[t] = s;
    __syncthreads();
    for (int off = 1; off < 1024; off <<= 1) {
        int v = (t >= off) ? part[t - off] : 0;
        __syncthreads();
        part[t] += v;
        __syncthreads();
    }
    if (t == 0) base[NN] = part[1023];
    int run = (t == 0) ? 0 : part[t - 1];
    for (int k = 0; k < CHK; ++k) {
        int idx = t * CHK + k;
        if (idx < NN) { base[idx] = run; cursor[idx] = run; run += cnt[idx]; }
    }
}

__global__ __launch_bounds__(256) void scatter_k(const int* __restrict__ eidx,
                                                 int* __restrict__ cursor,
                                                 int* __restrict__ sorted, int E)
{
    int i = blockIdx.x * 256 + threadIdx.x;
    if (i < E) {
        int p = atomicAdd(&cursor[eidx[i]], 1);
        sorted[p] = i;
    }
}

// ---------------------------------------------------------------------------
// Segment reduction: env[node] = (sum over node's edges of env_e) * SEG_NORM.
// ---------------------------------------------------------------------------
__global__ __launch_bounds__(256) void reduce_env(
    const int* __restrict__ base, const int* __restrict__ sorted,
    const u16* __restrict__ enve, u16* __restrict__ env, int NN)
{
    const int half = __builtin_amdgcn_readfirstlane(threadIdx.x >> 7);
    const int node = blockIdx.x * 2 + half;
    const int ch = threadIdx.x & 127;
    if (node >= NN) return;
    const int b = base[node], en = base[node + 1];
    float acc = 0.f;
    int i = b;
    for (; i + 3 < en; i += 4) {
        int s0 = sorted[i], s1 = sorted[i + 1], s2 = sorted[i + 2], s3 = sorted[i + 3];
        float v0 = bf2f(enve[(size_t)s0 * 128 + ch]);
        float v1 = bf2f(enve[(size_t)s1 * 128 + ch]);
        float v2 = bf2f(enve[(size_t)s2 * 128 + ch]);
        float v3 = bf2f(enve[(size_t)s3 * 128 + ch]);
        acc += (v0 + v1) + (v2 + v3);
    }
    for (; i < en; ++i) acc += bf2f(enve[(size_t)sorted[i] * 128 + ch]);
    env[(size_t)node * 128 + ch] = f2bf(acc * SEG_NORM);
}

// ---------------------------------------------------------------------------
// Phase A. 8 waves; wave w owns col tile w (16 cols), sweeps all 64 rows.
// ---------------------------------------------------------------------------
__global__ __launch_bounds__(512, 6) void phaseA(
    const float* __restrict__ attr, const float* __restrict__ inv,
    const u16* __restrict__ Wh2b0, const u16* __restrict__ Wl2b0,
    const u16* __restrict__ Wh2b1, const u16* __restrict__ Wl2b1,
    const u16* __restrict__ Whenv0, const u16* __restrict__ Wlenv0,
    u16* __restrict__ latbuf, u16* __restrict__ featbuf,
    u16* __restrict__ enve, int E)
{
    __shared__ __align__(16) char sm[39936];
    u16 (*Xi)[32]  = (u16 (*)[32])sm;                     // 4096
    u16 (*Hs)[136] = (u16 (*)[136])(sm + 4096);           // 17408
    u16 (*Ls)[136] = (u16 (*)[136])(sm + 21504);          // 17408
    float (*sattr)[4] = (float (*)[4])(sm + 38912);       // 1024

    const int tid = threadIdx.x;
    const int lane = tid & 63;
    const int w = tid >> 6;
    const int e0 = blockIdx.x * 64;
    const int E1 = E - 1;
    const int r = lane & 15, q = lane >> 4;
    const bool full = (e0 + 64 <= E);

    for (int i = tid; i < 64 * 32; i += 512) {
        int t = i >> 5, c = i & 31;
        u16 v = 0;
        if (c < 8) v = f2bf(inv[(size_t)min(e0 + t, E1) * 8 + c]);
        Xi[t][c] = v;
    }
    if (tid < 256) { int t = tid >> 2, c = tid & 3; sattr[t][c] = attr[(size_t)min(e0 + t, E1) * 4 + c]; }
    __syncthreads();

    const f4_t z = {0.f, 0.f, 0.f, 0.f};
    f4_t acc[4];

    // GEMM1: inv(8->32) @ W2b0 -> silu -> Hs
#pragma unroll
    for (int s = 0; s < 4; ++s) acc[s] = z;
    gemm_rows<1, 4, 32>(&Xi[0][0], Wh2b0 + w * 512, Wl2b0 + w * 512, lane, acc);
#pragma unroll
    for (int s = 0; s < 4; ++s)
#pragma unroll
        for (int jj = 0; jj < 4; ++jj)
            Hs[s * 16 + q * 4 + jj][w * 16 + r] = f2bf(silu_f(acc[s][jj] * RSQRT8));
    __syncthreads();

    // GEMM2: h(128) @ W2b1 -> lat -> Ls + latbuf
#pragma unroll
    for (int s = 0; s < 4; ++s) acc[s] = z;
    gemm_rows<4, 4, 136>(&Hs[0][0], Wh2b1 + w * 4 * 512, Wl2b1 + w * 4 * 512, lane, acc);
    if (full) {
#pragma unroll
        for (int s = 0; s < 4; ++s)
#pragma unroll
            for (int jj = 0; jj < 4; ++jj) {
                int row = s * 16 + q * 4 + jj, cc = w * 16 + r;
                u16 b = f2bf(acc[s][jj] * RSQRT128);
                Ls[row][cc] = b;
                latbuf[(size_t)(e0 + row) * 128 + cc] = b;
            }
    } else {
#pragma unroll
        for (int s = 0; s < 4; ++s)
#pragma unroll
            for (int jj = 0; jj < 4; ++jj) {
                int row = s * 16 + q * 4 + jj, cc = w * 16 + r;
                u16 b = f2bf(acc[s][jj] * RSQRT128);
                Ls[row][cc] = b;
                int e = e0 + row;
                if (e < E) latbuf[(size_t)e * 128 + cc] = b;
            }
    }
    __syncthreads();

    // GEMM3: lat(128) @ Wenv0 -> w0; env_weight stores from accumulators.
#pragma unroll
    for (int s = 0; s < 4; ++s) acc[s] = z;
    gemm_rows<4, 4, 136>(&Ls[0][0], Whenv0 + w * 4 * 512, Wlenv0 + w * 4 * 512, lane, acc);
    {
        const int col = w * 16 + r;
        u16* dstbase = (col < 64) ? featbuf : enve;
        const int wcol = col & 63;
        if (full) {
#pragma unroll
            for (int s = 0; s < 4; ++s)
#pragma unroll
                for (int jj = 0; jj < 4; ++jj) {
                    int row = s * 16 + q * 4 + jj;
                    float4 av = *(const float4*)&sattr[row][0];
                    env_store(dstbase + (size_t)(e0 + row) * 128, wcol, acc[s][jj] * RSQRT128, av);
                }
        } else {
#pragma unroll
            for (int s = 0; s < 4; ++s)
#pragma unroll
                for (int jj = 0; jj < 4; ++jj) {
                    int row = s * 16 + q * 4 + jj;
                    int e = e0 + row;
                    if (e >= E) continue;
                    float4 av = *(const float4*)&sattr[row][0];
                    env_store(dstbase + (size_t)e * 128, wcol, acc[s][jj] * RSQRT128, av);
                }
        }
    }
}

// ---------------------------------------------------------------------------
// Phase B: tensor products (streamed from global) + mix; new_lat MLP; lat2;
// w1 -> env_e rows. Col-tile-per-wave GEMMs with B-register preload.
// ---------------------------------------------------------------------------
__global__ __launch_bounds__(512, 6) void phaseB(
    const int* __restrict__ eidx, const float* __restrict__ attr,
    const u16* __restrict__ env0b,
    const u16* __restrict__ Whs0, const u16* __restrict__ Wls0,
    const u16* __restrict__ Whv0, const u16* __restrict__ Wlv0,
    const u16* __restrict__ Whl10, const u16* __restrict__ Wll10,
    const u16* __restrict__ Whl11, const u16* __restrict__ Wll11,
    const u16* __restrict__ Whe1, const u16* __restrict__ Wle1,
    u16* __restrict__ latbuf, u16* __restrict__ featbuf,
    u16* __restrict__ enve, int E)
{
    __shared__ __align__(16) char sm[52480];
    u16 (*X4)[200] = (u16 (*)[200])sm;                    // 25600: lat|ss|vv -> lat2
    u16 (*P)[200]  = (u16 (*)[200])(sm + 25600);          // 25600: sv|vs per dim (192 used)
    u16 (*Hs)[136] = (u16 (*)[136])(sm + 25600);          // overlay P (dead post-mix)
    float (*sattr)[4] = (float (*)[4])(sm + 51200);       // 1024

    const int tid = threadIdx.x;
    const int lane = tid & 63;
    const int w = tid >> 6;
    const int e0 = blockIdx.x * 64;
    const int E1 = E - 1;
    const int r = lane & 15, q = lane >> 4;
    const bool full = (e0 + 64 <= E);

    if (tid < 256) { int t = tid >> 2, c = tid & 3; sattr[t][c] = attr[(size_t)min(e0 + t, E1) * 4 + c]; }

    // lat -> X4[:, 0:128]
    for (int i = tid; i < 64 * 16; i += 512) {
        int t = i >> 4, dc = i & 15;
        *(bf8_t*)&X4[t][dc * 8] = ((const bf8_t*)(latbuf + (size_t)min(e0 + t, E1) * 128))[dc];
    }

    // tensor-product pass: ss->X4[128+m], vv->X4[160+m], sv_d/vs_d -> P.
    {
        const int t = tid >> 3, cg = tid & 7;
        const int e = min(e0 + t, E1);
        const int nd = eidx[e];
        const u16* fp = featbuf + (size_t)e * 128 + cg * 16;
        const u16* gp = env0b + (size_t)nd * 128 + cg * 16;
        bf8_t fA = *(const bf8_t*)fp;
        bf8_t fB = *(const bf8_t*)(fp + 8);
        bf8_t gA = *(const bf8_t*)gp;
        bf8_t gB = *(const bf8_t*)(gp + 8);
        bf4_t ssv, vvv, svv[3], vsv[3];
#pragma unroll
        for (int c = 0; c < 4; ++c) {
            float f0, f1, f2, f3, g0, g1, g2, g3;
            if (c < 2) {
                f0 = bf2f((u16)fA[4 * c]);     g0 = bf2f((u16)gA[4 * c]);
                f1 = bf2f((u16)fA[4 * c + 1]); g1 = bf2f((u16)gA[4 * c + 1]);
                f2 = bf2f((u16)fA[4 * c + 2]); g2 = bf2f((u16)gA[4 * c + 2]);
                f3 = bf2f((u16)fA[4 * c + 3]); g3 = bf2f((u16)gA[4 * c + 3]);
            } else {
                int cc = c - 2;
                f0 = bf2f((u16)fB[4 * cc]);     g0 = bf2f((u16)gB[4 * cc]);
                f1 = bf2f((u16)fB[4 * cc + 1]); g1 = bf2f((u16)gB[4 * cc + 1]);
                f2 = bf2f((u16)fB[4 * cc + 2]); g2 = bf2f((u16)gB[4 * cc + 2]);
                f3 = bf2f((u16)fB[4 * cc + 3]); g3 = bf2f((u16)gB[4 * cc + 3]);
            }
            ssv[c] = (short)f2bf(f0 * g0);
            vvv[c] = (short)f2bf((f1 * g1 + f2 * g2 + f3 * g3) * INV_SQRT3);
            svv[0][c] = (short)f2bf(f0 * g1);
            svv[1][c] = (short)f2bf(f0 * g2);
            svv[2][c] = (short)f2bf(f0 * g3);
            vsv[0][c] = (short)f2bf(f1 * g0);
            vsv[1][c] = (short)f2bf(f2 * g0);
            vsv[2][c] = (short)f2bf(f3 * g0);
        }
        *(bf4_t*)&X4[t][128 + 4 * cg] = ssv;
        *(bf4_t*)&X4[t][160 + 4 * cg] = vvv;
#pragma unroll
        for (int d = 0; d < 3; ++d) {
            *(bf4_t*)&P[t][d * 64 + 4 * cg]      = svv[d];
            *(bf4_t*)&P[t][d * 64 + 32 + 4 * cg] = vsv[d];
        }
    }
    __syncthreads();

    const f4_t z = {0.f, 0.f, 0.f, 0.f};

    // ---- mix: wave = (strip sw, col-half cw); B-frags loaded once, shared
    // across S and all 3 V dims.
    {
        const int sw = w >> 1, cw = w & 1;
        f4_t aS = z, aV[3] = {z, z, z};
        const u16* bsh = Whs0 + cw * 2 * 512;
        const u16* bsl = Wls0 + cw * 2 * 512;
        const u16* bvh = Whv0 + cw * 2 * 512;
        const u16* bvl = Wlv0 + cw * 2 * 512;
        bf8_t s0h = *(const bf8_t*)(bsh + lane * 8);
        bf8_t s0l = *(const bf8_t*)(bsl + lane * 8);
        bf8_t s1h = *(const bf8_t*)(bsh + 512 + lane * 8);
        bf8_t s1l = *(const bf8_t*)(bsl + 512 + lane * 8);
        bf8_t v0h = *(const bf8_t*)(bvh + lane * 8);
        bf8_t v0l = *(const bf8_t*)(bvl + lane * 8);
        bf8_t v1h = *(const bf8_t*)(bvh + 512 + lane * 8);
        bf8_t v1l = *(const bf8_t*)(bvl + 512 + lane * 8);
        const u16* arow = &X4[sw * 16 + r][0];
        bf8_t a0 = *(const bf8_t*)(arow + 128 + q * 8);
        bf8_t a1 = *(const bf8_t*)(arow + 160 + q * 8);
        aS = MFMA16(a0, s0l, aS, 0, 0, 0);
        aS = MFMA16(a0, s0h, aS, 0, 0, 0);
        aS = MFMA16(a1, s1l, aS, 0, 0, 0);
        aS = MFMA16(a1, s1h, aS, 0, 0, 0);
        const u16* prow = &P[sw * 16 + r][0];
#pragma unroll
        for (int d = 0; d < 3; ++d) {
            bf8_t p0 = *(const bf8_t*)(prow + d * 64 + q * 8);
            bf8_t p1 = *(const bf8_t*)(prow + d * 64 + 32 + q * 8);
            aV[d] = MFMA16(p0, v0l, aV[d], 0, 0, 0);
            aV[d] = MFMA16(p0, v0h, aV[d], 0, 0, 0);
            aV[d] = MFMA16(p1, v1l, aV[d], 0, 0, 0);
            aV[d] = MFMA16(p1, v1h, aV[d], 0, 0, 0);
        }
        // feat2 direct to global
        const int m = cw * 16 + r;
        if (full) {
#pragma unroll
            for (int reg = 0; reg < 4; ++reg) {
                int e = e0 + sw * 16 + q * 4 + reg;
                u16* dst = featbuf + (size_t)e * 128 + 4 * m;
                dst[0] = f2bf(aS[reg] * RSQRT64);
                dst[1] = f2bf(aV[0][reg] * (RSQRT64 * INV_SQRT3));
                dst[2] = f2bf(aV[1][reg] * (RSQRT64 * INV_SQRT3));
                dst[3] = f2bf(aV[2][reg] * (RSQRT64 * INV_SQRT3));
            }
        } else {
#pragma unroll
            for (int reg = 0; reg < 4; ++reg) {
                int e = e0 + sw * 16 + q * 4 + reg;
                if (e < E) {
                    u16* dst = featbuf + (size_t)e * 128 + 4 * m;
                    dst[0] = f2bf(aS[reg] * RSQRT64);
                    dst[1] = f2bf(aV[0][reg] * (RSQRT64 * INV_SQRT3));
                    dst[2] = f2bf(aV[1][reg] * (RSQRT64 * INV_SQRT3));
                    dst[3] = f2bf(aV[2][reg] * (RSQRT64 * INV_SQRT3));
                }
            }
        }
    }

    // GEMM4: [lat|sscal](192) @ Wlat1_0
    f4_t acc[4];
#pragma unroll
    for (int s = 0; s < 4; ++s) acc[s] = z;
    gemm_rows<6, 4, 200>(&X4[0][0], Whl10 + w * 6 * 512, Wll10 + w * 6 * 512, lane, acc);
    __syncthreads();   // all P reads (mix) done -> Hs may overwrite P
#pragma unroll
    for (int s = 0; s < 4; ++s)
#pragma unroll
        for (int jj = 0; jj < 4; ++jj)
            Hs[s * 16 + q * 4 + jj][w * 16 + r] = f2bf(silu_f(acc[s][jj] * RSQRT192));
    __syncthreads();

    // GEMM5: h @ Wlat1_1 -> new_lat; lat2 = C*(lat+new_lat) in place in X4
#pragma unroll
    for (int s = 0; s < 4; ++s) acc[s] = z;
    gemm_rows<4, 4, 136>(&Hs[0][0], Whl11 + w * 4 * 512, Wll11 + w * 4 * 512, lane, acc);
#pragma unroll
    for (int s = 0; s < 4; ++s)
#pragma unroll
        for (int jj = 0; jj < 4; ++jj) {
            int row = s * 16 + q * 4 + jj, cc = w * 16 + r;
            float l2 = C_HALF * (bf2f(X4[row][cc]) + acc[s][jj] * RSQRT128);
            X4[row][cc] = f2bf(l2);      // cell owned by this lane-reg only
        }
    __syncthreads();

    // lat2 -> latbuf ; GEMM6: lat2 @ Wenv1(128x64) -> w1 -> env_e rows
    if (full) {
        for (int i = tid; i < 64 * 16; i += 512) {
            int t = i >> 4, dc = i & 15;
            ((bf8_t*)(latbuf + (size_t)(e0 + t) * 128))[dc] = *(const bf8_t*)&X4[t][dc * 8];
        }
    } else {
        for (int i = tid; i < 64 * 16; i += 512) {
            int t = i >> 4, dc = i & 15;
            int e = e0 + t;
            if (e < E) ((bf8_t*)(latbuf + (size_t)e * 128))[dc] = *(const bf8_t*)&X4[t][dc * 8];
        }
    }
    {
        const int ct = w & 3, rh = w >> 2;   // col tile 0..3, row half 0..1
        f4_t a6[2] = {z, z};
        gemm_rows<4, 2, 200>(&X4[rh * 32][0], Whe1 + ct * 4 * 512, Wle1 + ct * 4 * 512, lane, a6);
        const int col = ct * 16 + r;         // 0..63
        if (full) {
#pragma unroll
            for (int s = 0; s < 2; ++s)
#pragma unroll
                for (int jj = 0; jj < 4; ++jj) {
                    int row = rh * 32 + s * 16 + q * 4 + jj;
                    float4 av = *(const float4*)&sattr[row][0];
                    env_store(enve + (size_t)(e0 + row) * 128, col, a6[s][jj] * RSQRT128, av);
                }
        } else {
#pragma unroll
            for (int s = 0; s < 2; ++s)
#pragma unroll
                for (int jj = 0; jj < 4; ++jj) {
                    int row = rh * 32 + s * 16 + q * 4 + jj;
                    int e = e0 + row;
                    if (e >= E) continue;
                    float4 av = *(const float4*)&sattr[row][0];
                    env_store(enve + (size_t)e * 128, col, a6[s][jj] * RSQRT128, av);
                }
        }
    }
}

// ---------------------------------------------------------------------------
// Phase C: scalars1 streamed from global, final MLP, out mix.
// ---------------------------------------------------------------------------
__global__ __launch_bounds__(512, 6) void phaseC(
    const int* __restrict__ eidx, const u16* __restrict__ env1b,
    const u16* __restrict__ Whf0, const u16* __restrict__ Wlf0,
    const u16* __restrict__ Whf1, const u16* __restrict__ Wlf1,
    const u16* __restrict__ latbuf, const u16* __restrict__ featbuf,
    float* __restrict__ outp, int E)
{
    __shared__ __align__(16) char sm[43008];
    u16 (*X7)[200] = (u16 (*)[200])sm;                    // 25600: lat2|scal1
    u16 (*Hs)[136] = (u16 (*)[136])(sm + 25600);          // 17408

    const int tid = threadIdx.x;
    const int lane = tid & 63;
    const int w = tid >> 6;
    const int e0 = blockIdx.x * 64;
    const int E1 = E - 1;
    const int r = lane & 15, q = lane >> 4;
    const bool full = (e0 + 64 <= E);

    // lat2 -> X7[:, 0:128]
    for (int i = tid; i < 64 * 16; i += 512) {
        int t = i >> 4, dc = i & 15;
        *(bf8_t*)&X7[t][dc * 8] = ((const bf8_t*)(latbuf + (size_t)min(e0 + t, E1) * 128))[dc];
    }

    // scalars1 pass: ss/vv from feat2 x env1, streamed from global
    {
        const int t = tid >> 3, cg = tid & 7;
        const int e = min(e0 + t, E1);
        const int nd = eidx[e];
        const u16* fp = featbuf + (size_t)e * 128 + cg * 16;
        const u16* gp = env1b + (size_t)nd * 128 + cg * 16;
        bf8_t fA = *(const bf8_t*)fp;
        bf8_t fB = *(const bf8_t*)(fp + 8);
        bf8_t gA = *(const bf8_t*)gp;
        bf8_t gB = *(const bf8_t*)(gp + 8);
        bf4_t ssv, vvv;
#pragma unroll
        for (int c = 0; c < 4; ++c) {
            float f0, f1, f2, f3, g0, g1, g2, g3;
            if (c < 2) {
                f0 = bf2f((u16)fA[4 * c]);     g0 = bf2f((u16)gA[4 * c]);
                f1 = bf2f((u16)fA[4 * c + 1]); g1 = bf2f((u16)gA[4 * c + 1]);
                f2 = bf2f((u16)fA[4 * c + 2]); g2 = bf2f((u16)gA[4 * c + 2]);
                f3 = bf2f((u16)fA[4 * c + 3]); g3 = bf2f((u16)gA[4 * c + 3]);
            } else {
                int cc = c - 2;
                f0 = bf2f((u16)fB[4 * cc]);     g0 = bf2f((u16)gB[4 * cc]);
                f1 = bf2f((u16)fB[4 * cc + 1]); g1 = bf2f((u16)gB[4 * cc + 1]);
                f2 = bf2f((u16)fB[4 * cc + 2]); g2 = bf2f((u16)gB[4 * cc + 2]);
                f3 = bf2f((u16)fB[4 * cc + 3]); g3 = bf2f((u16)gB[4 * cc + 3]);
            }
            ssv[c] = (short)f2bf(f0 * g0);
            vvv[c] = (short)f2bf((f1 * g1 + f2 * g2 + f3 * g3) * INV_SQRT3);
        }
        *(bf4_t*)&X7[t][128 + 4 * cg] = ssv;
        *(bf4_t*)&X7[t][160 + 4 * cg] = vvv;
    }
    __syncthreads();

    const f4_t z = {0.f, 0.f, 0.f, 0.f};
    f4_t acc[4];
#pragma unroll
    for (int s = 0; s < 4; ++s) acc[s] = z;
    gemm_rows<6, 4, 200>(&X7[0][0], Whf0 + w * 6 * 512, Wlf0 + w * 6 * 512, lane, acc);
    // Hs is a fresh region (disjoint from X7) -> no barrier needed before writes
#pragma unroll
    for (int s = 0; s < 4; ++s)
#pragma unroll
        for (int jj = 0; jj < 4; ++jj)
            Hs[s * 16 + q * 4 + jj][w * 16 + r] = f2bf(silu_f(acc[s][jj] * RSQRT192));
    __syncthreads();

#pragma unroll
    for (int s = 0; s < 4; ++s) acc[s] = z;
    gemm_rows<4, 4, 136>(&Hs[0][0], Whf1 + w * 4 * 512, Wlf1 + w * 4 * 512, lane, acc);
    if (full) {
#pragma unroll
        for (int s = 0; s < 4; ++s)
#pragma unroll
            for (int jj = 0; jj < 4; ++jj) {
                int row = s * 16 + q * 4 + jj, cc = w * 16 + r;
                outp[(size_t)(e0 + row) * 128 + cc] =
                    SQ23 * bf2f(X7[row][cc]) + SQ13 * (acc[s][jj] * RSQRT128);
            }
    } else {
#pragma unroll
        for (int s = 0; s < 4; ++s)
#pragma unroll
            for (int jj = 0; jj < 4; ++jj) {
                int row = s * 16 + q * 4 + jj, cc = w * 16 + r;
                int e = e0 + row;
                if (e < E)
                    outp[(size_t)e * 128 + cc] =
                        SQ23 * bf2f(X7[row][cc]) + SQ13 * (acc[s][jj] * RSQRT128);
            }
    }
}

extern "C" void kernel_launch(void* const* d_in, const int* in_sizes, int n_in,
                              void* d_out, int out_size, void* d_ws, size_t ws_size,
                              hipStream_t stream)
{
    const int E  = in_sizes[0] / 2;
    const int NN = 12500;

    const int*   eidx    = (const int*)d_in[0];
    const float* attr    = (const float*)d_in[1];
    const float* inv     = (const float*)d_in[2];
    float* outp = (float*)d_out;

    // ws: lat bf16 | feat bf16 | env0b, env1b bf16 | weights | sort ints
    u16* latbuf  = (u16*)d_ws;
    u16* featbuf = latbuf + (size_t)E * 128;
    u16* env0b   = featbuf + (size_t)E * 128;
    u16* env1b   = env0b + (size_t)NN * 128;
    u16* p = env1b + (size_t)NN * 128;
    auto carve = [&](int elems) { u16* q0 = p; p += elems; return q0; };
    u16 *Wh2b0 = carve(128 * 32),  *Wl2b0 = carve(128 * 32);
    u16 *Wh2b1 = carve(128 * 128), *Wl2b1 = carve(128 * 128);
    u16 *Whe0  = carve(128 * 128), *Wle0  = carve(128 * 128);
    u16 *Whl10 = carve(128 * 192), *Wll10 = carve(128 * 192);
    u16 *Whl11 = carve(128 * 128), *Wll11 = carve(128 * 128);
    u16 *Whe1  = carve(64 * 128),  *Wle1  = carve(64 * 128);
    u16 *Whs0  = carve(32 * 64),   *Wls0  = carve(32 * 64);
    u16 *Whv0  = carve(32 * 64),   *Wlv0  = carve(32 * 64);
    u16 *Whf0  = carve(128 * 192), *Wlf0  = carve(128 * 192);
    u16 *Whf1  = carve(128 * 128), *Wlf1  = carve(128 * 128);
    int* cnt;
    {
        size_t off_bytes = (size_t)((char*)p - (char*)d_ws);
        off_bytes = (off_bytes + 3) & ~(size_t)3;
        cnt = (int*)((char*)d_ws + off_bytes);
    }
    int* base   = cnt + NN;          // NN+1 entries
    int* cursor = base + NN + 1;
    int* sorted = cursor + NN;

    // env_e scratch: reuse d_out (fully overwritten by phaseC afterwards)
    u16* enve = (u16*)d_out;

    hipMemsetAsync(cnt, 0, NN * sizeof(int), stream);

    // ---- weight prep (one kernel) ----
    PDs P;
    auto setpd = [&](int i, const float* s, u16* h, u16* l, int K, int N, int Kp, int pm, int off) {
        P.d[i] = {s, h, l, K, N, Kp, pm, off, N * Kp};
    };
    setpd(0, (const float*)d_in[3],  Wh2b0, Wl2b0,   8, 128,  32, 0, 0);
    setpd(1, (const float*)d_in[4],  Wh2b1, Wl2b1, 128, 128, 128, 0, 4096);
    setpd(2, (const float*)d_in[5],  Whe0,  Wle0,  128, 128, 128, 0, 20480);
    setpd(3, (const float*)d_in[6],  Whl10, Wll10, 192, 128, 192, 1, 36864);
    setpd(4, (const float*)d_in[7],  Whl11, Wll11, 128, 128, 128, 0, 61440);
    setpd(5, (const float*)d_in[8],  Whe1,  Wle1,  128,  64, 128, 0, 77824);
    setpd(6, (const float*)d_in[9],  Whs0,  Wls0,   64,  32,  64, 0, 86016);
    setpd(7, (const float*)d_in[10], Whv0,  Wlv0,   64,  32,  64, 0, 88064);
    setpd(8, (const float*)d_in[11], Whf0,  Wlf0,  192, 128, 192, 1, 90112);
    setpd(9, (const float*)d_in[12], Whf1,  Wlf1,  128, 128, 128, 0, 114688);
    const int total = 131072;
    prep_all<<<(total + 255) / 256, 256, 0, stream>>>(P, total);

    // ---- counting sort of edges by center node ----
    hist_k<<<(E + 255) / 256, 256, 0, stream>>>(eidx, cnt, E);
    scan_k<<<1, 1024, 0, stream>>>(cnt, base, cursor, NN);
    scatter_k<<<(E + 255) / 256, 256, 0, stream>>>(eidx, cursor, sorted, E);

    const int nb = (E + 63) / 64;
    phaseA<<<nb, 512, 0, stream>>>(attr, inv, Wh2b0, Wl2b0, Wh2b1, Wl2b1,
                                   Whe0, Wle0, latbuf, featbuf, enve, E);
    reduce_env<<<(NN + 1) / 2, 256, 0, stream>>>(base, sorted, enve, env0b, NN);
    phaseB<<<nb, 512, 0, stream>>>(eidx, attr, env0b, Whs0, Wls0, Whv0, Wlv0,
                                   Whl10, Wll10, Whl11, Wll11, Whe1, Wle1,
                                   latbuf, featbuf, enve, E);
    reduce_env<<<(NN + 1) / 2, 256, 0, stream>>>(base, sorted, enve, env1b, NN);
    phaseC<<<nb, 512, 0, stream>>>(eidx, env1b, Whf0, Wlf0, Whf1, Wlf1,
                                   latbuf, featbuf, outp, E);
}

// Round 4
// 409.756 us; speedup vs baseline: 2.5027x; 1.0160x over previous
//
#include <hip/hip_runtime.h>

typedef __attribute__((ext_vector_type(8))) short bf8_t;   // 8 x bf16 (4 VGPRs)
typedef __attribute__((ext_vector_type(4))) short bf4_t;   // 4 x bf16 (2 VGPRs)
typedef __attribute__((ext_vector_type(4))) float f4_t;    // 4 x fp32 acc
typedef unsigned short u16;
typedef unsigned int u32;

#define MFMA16 __builtin_amdgcn_mfma_f32_16x16x32_bf16

#define RSQRT8    0.35355339059327373f
#define RSQRT128  0.08838834764831845f
#define RSQRT192  0.07216878364870323f
#define RSQRT64   0.125f
#define INV_SQRT3 0.57735026918962576f
#define SEG_NORM  0.25f       /* 1/sqrt(16) */
#define C_HALF    0.70710678118654752f
#define SQ23      0.81649658092772603f
#define SQ13      0.57735026918962576f

__device__ __forceinline__ float bf2f(u16 b) {
    return __uint_as_float(((u32)b) << 16);
}
// software RNE (cold paths only; bit-identical to HW cvt)
__device__ __forceinline__ u16 f2bf(float f) {
    u32 u = __float_as_uint(f);
    u += 0x7FFFu + ((u >> 16) & 1u);
    return (u16)(u >> 16);
}
// hardware RNE pack: lo -> bits[15:0], hi -> bits[31:16]; 1 VALU inst
__device__ __forceinline__ u32 cvtpk(float lo, float hi) {
    u32 r;
    asm("v_cvt_pk_bf16_f32 %0, %1, %2" : "=v"(r) : "v"(lo), "v"(hi));
    return r;
}
__device__ __forceinline__ u16 f2bf_hw(float f) { return (u16)cvtpk(f, f); }
__device__ __forceinline__ float silu_f(float x) {
    return x * __builtin_amdgcn_rcpf(1.0f + __expf(-x));
}

// ---------------------------------------------------------------------------
// gemm_rows: one wave owns ONE 16-col tile (weights pre-offset by caller) and
// sweeps NSTR row-strips of 16. B-fragments batched in chunks; AS is a
// compile-time LDS row stride. FP order: ks ascending, lo-then-hi.
// ---------------------------------------------------------------------------
template<int KS, int NSTR, int AS>
__device__ __forceinline__ void gemm_rows(
    const u16* A,
    const u16* __restrict__ Wh, const u16* __restrict__ Wl,
    int lane, f4_t* acc)
{
    const int r = lane & 15;
    const int q = lane >> 4;
    const u16* ab = A + r * AS + q * 8;
    constexpr int CH = (KS > 4) ? 3 : KS;
#pragma unroll
    for (int c0 = 0; c0 < KS; c0 += CH) {
        bf8_t bh[CH], bl[CH];
#pragma unroll
        for (int j = 0; j < CH; ++j) {
            bh[j] = *(const bf8_t*)(Wh + ((c0 + j) * 64 + lane) * 8);
            bl[j] = *(const bf8_t*)(Wl + ((c0 + j) * 64 + lane) * 8);
        }
#pragma unroll
        for (int j = 0; j < CH; ++j) {
#pragma unroll
            for (int s = 0; s < NSTR; ++s) {
                bf8_t a = *(const bf8_t*)(ab + s * 16 * AS + (c0 + j) * 32);
                acc[s] = MFMA16(a, bl[j], acc[s], 0, 0, 0);
                acc[s] = MFMA16(a, bh[j], acc[s], 0, 0, 0);
            }
        }
    }
}

// env_weight epilogue store: weight col w (0..63 within half) -> channels.
__device__ __forceinline__ void env_store(u16* dst, int w, float val, float4 av)
{
    int m = w >> 1;
    if ((w & 1) == 0) {
        dst[4 * m] = f2bf_hw(val * av.x);
    } else {
        dst[4 * m + 1] = f2bf_hw(val * av.y);
        *(u32*)(dst + 4 * m + 2) = cvtpk(val * av.z, val * av.w);
    }
}

// ---------------------------------------------------------------------------
// Weight prep: fp32 [K][N] -> bf16 hi/lo in FRAGMENT-LINEAR layout:
// element index = ((tile*KS + ks)*64 + lane)*8 + j  holds
// W^T[col = tile*16 + (lane&15)][k = ks*32 + (lane>>4)*8 + j].
// ---------------------------------------------------------------------------
struct PD { const float* src; u16* hi; u16* lo; int K, N, Kp, perm, off, cnt; };
struct PDs { PD d[10]; };

__global__ __launch_bounds__(256) void prep_all(PDs P, int total)
{
    int i = blockIdx.x * 256 + threadIdx.x;
    if (i >= total) return;
#pragma unroll
    for (int rg = 0; rg < 10; ++rg) {
        if (i >= P.d[rg].off && i < P.d[rg].off + P.d[rg].cnt) {
            int li = i - P.d[rg].off;
            int KS = P.d[rg].Kp >> 5;
            int tile = li / (KS * 512);
            int rem  = li - tile * KS * 512;
            int ks   = rem >> 9;
            int lane = (rem >> 3) & 63;
            int j    = rem & 7;
            int n = tile * 16 + (lane & 15);
            int k = ks * 32 + (lane >> 4) * 8 + j;
            int ksrc = k;
            if (P.d[rg].perm && k >= 128)
                ksrc = (k < 160) ? (128 + 2 * (k - 128)) : (129 + 2 * (k - 160));
            float wv = (ksrc < P.d[rg].K) ? P.d[rg].src[(size_t)ksrc * P.d[rg].N + n] : 0.f;
            u16 h = f2bf(wv);
            P.d[rg].hi[li] = h;
            P.d[rg].lo[li] = f2bf(wv - bf2f(h));
        }
    }
}

// ---------------------------------------------------------------------------
// Counting sort of edges by center node.
// ---------------------------------------------------------------------------
__global__ __launch_bounds__(256) void hist_k(const int* __restrict__ eidx,
                                              int* __restrict__ cnt, int E)
{
    int i = blockIdx.x * 256 + threadIdx.x;
    if (i < E) atomicAdd(&cnt[eidx[i]], 1);
}

__global__ __launch_bounds__(1024) void scan_k(const int* __restrict__ cnt,
                                               int* __restrict__ base,
                                               int* __restrict__ cursor, int NN)
{
    __shared__ int part[1024];
    const int t = threadIdx.x;
    const int CHK = (NN + 1023) >> 10;
    int s = 0;
    for (int k = 0; k < CHK; ++k) { int idx = t * CHK + k; if (idx < NN) s += cnt[idx]; }
    part[t] = s;
    __syncthreads();
    for (int off = 1; off < 1024; off <<= 1) {
        int v = (t >= off) ? part[t - off] : 0;
        __syncthreads();
        part[t] += v;
        __syncthreads();
    }
    if (t == 0) base[NN] = part[1023];
    int run = (t == 0) ? 0 : part[t - 1];
    for (int k = 0; k < CHK; ++k) {
        int idx = t * CHK + k;
        if (idx < NN) { base[idx] = run; cursor[idx] = run; run += cnt[idx]; }
    }
}

__global__ __launch_bounds__(256) void scatter_k(const int* __restrict__ eidx,
                                                 int* __restrict__ cursor,
                                                 int* __restrict__ sorted, int E)
{
    int i = blockIdx.x * 256 + threadIdx.x;
    if (i < E) {
        int p = atomicAdd(&cursor[eidx[i]], 1);
        sorted[p] = i;
    }
}

// ---------------------------------------------------------------------------
// Segment reduction: env[node] = (sum over node's edges of env_e) * SEG_NORM.
// 4 nodes per 256-thr block; 64 threads/node, u32 (2-channel) loads.
// FP order per channel identical to scalar version.
// ---------------------------------------------------------------------------
__global__ __launch_bounds__(256) void reduce_env(
    const int* __restrict__ base, const int* __restrict__ sorted,
    const u16* __restrict__ enve, u16* __restrict__ env, int NN)
{
    const int node = blockIdx.x * 4 + (threadIdx.x >> 6);
    const int ch = threadIdx.x & 63;          // channel pair: 2ch, 2ch+1
    if (node >= NN) return;
    const int b = base[node], en = base[node + 1];
    float a0 = 0.f, a1 = 0.f;
    int i = b;
    for (; i + 3 < en; i += 4) {
        int s0 = sorted[i], s1 = sorted[i + 1], s2 = sorted[i + 2], s3 = sorted[i + 3];
        u32 v0 = *(const u32*)(enve + (size_t)s0 * 128 + 2 * ch);
        u32 v1 = *(const u32*)(enve + (size_t)s1 * 128 + 2 * ch);
        u32 v2 = *(const u32*)(enve + (size_t)s2 * 128 + 2 * ch);
        u32 v3 = *(const u32*)(enve + (size_t)s3 * 128 + 2 * ch);
        a0 += (bf2f((u16)v0) + bf2f((u16)v1)) + (bf2f((u16)v2) + bf2f((u16)v3));
        a1 += (bf2f((u16)(v0 >> 16)) + bf2f((u16)(v1 >> 16))) + (bf2f((u16)(v2 >> 16)) + bf2f((u16)(v3 >> 16)));
    }
    for (; i < en; ++i) {
        u32 v = *(const u32*)(enve + (size_t)sorted[i] * 128 + 2 * ch);
        a0 += bf2f((u16)v);
        a1 += bf2f((u16)(v >> 16));
    }
    *(u32*)(env + (size_t)node * 128 + 2 * ch) = cvtpk(a0 * SEG_NORM, a1 * SEG_NORM);
}

// ---------------------------------------------------------------------------
// Phase A. 8 waves; wave w owns col tile w (16 cols), sweeps all 64 rows.
// ---------------------------------------------------------------------------
__global__ __launch_bounds__(512, 6) void phaseA(
    const float* __restrict__ attr, const float* __restrict__ inv,
    const u16* __restrict__ Wh2b0, const u16* __restrict__ Wl2b0,
    const u16* __restrict__ Wh2b1, const u16* __restrict__ Wl2b1,
    const u16* __restrict__ Whenv0, const u16* __restrict__ Wlenv0,
    u16* __restrict__ latbuf, u16* __restrict__ featbuf,
    u16* __restrict__ enve, int E)
{
    __shared__ __align__(16) char sm[39936];
    u16 (*Xi)[32]  = (u16 (*)[32])sm;                     // 4096
    u16 (*Hs)[136] = (u16 (*)[136])(sm + 4096);           // 17408
    u16 (*Ls)[136] = (u16 (*)[136])(sm + 21504);          // 17408
    float (*sattr)[4] = (float (*)[4])(sm + 38912);       // 1024

    const int tid = threadIdx.x;
    const int lane = tid & 63;
    const int w = tid >> 6;
    const int e0 = blockIdx.x * 64;
    const int E1 = E - 1;
    const int r = lane & 15, q = lane >> 4;
    const bool full = (e0 + 64 <= E);

    for (int i = tid; i < 64 * 32; i += 512) {
        int t = i >> 5, c = i & 31;
        u16 v = 0;
        if (c < 8) v = f2bf_hw(inv[(size_t)min(e0 + t, E1) * 8 + c]);
        Xi[t][c] = v;
    }
    if (tid < 256) { int t = tid >> 2, c = tid & 3; sattr[t][c] = attr[(size_t)min(e0 + t, E1) * 4 + c]; }
    __syncthreads();

    const f4_t z = {0.f, 0.f, 0.f, 0.f};
    f4_t acc[4];

    // GEMM1: inv(8->32) @ W2b0 -> silu -> Hs
#pragma unroll
    for (int s = 0; s < 4; ++s) acc[s] = z;
    gemm_rows<1, 4, 32>(&Xi[0][0], Wh2b0 + w * 512, Wl2b0 + w * 512, lane, acc);
#pragma unroll
    for (int s = 0; s < 4; ++s)
#pragma unroll
        for (int jj = 0; jj < 4; jj += 2) {
            u32 pk = cvtpk(silu_f(acc[s][jj] * RSQRT8), silu_f(acc[s][jj + 1] * RSQRT8));
            Hs[s * 16 + q * 4 + jj][w * 16 + r]     = (u16)pk;
            Hs[s * 16 + q * 4 + jj + 1][w * 16 + r] = (u16)(pk >> 16);
        }
    __syncthreads();

    // GEMM2: h(128) @ W2b1 -> lat -> Ls + latbuf
#pragma unroll
    for (int s = 0; s < 4; ++s) acc[s] = z;
    gemm_rows<4, 4, 136>(&Hs[0][0], Wh2b1 + w * 4 * 512, Wl2b1 + w * 4 * 512, lane, acc);
#pragma unroll
    for (int s = 0; s < 4; ++s)
#pragma unroll
        for (int jj = 0; jj < 4; jj += 2) {
            int row0 = s * 16 + q * 4 + jj, cc = w * 16 + r;
            u32 pk = cvtpk(acc[s][jj] * RSQRT128, acc[s][jj + 1] * RSQRT128);
            u16 b0 = (u16)pk, b1 = (u16)(pk >> 16);
            Ls[row0][cc] = b0;
            Ls[row0 + 1][cc] = b1;
            int ea = e0 + row0;
            if (full) {
                latbuf[(size_t)ea * 128 + cc] = b0;
                latbuf[(size_t)(ea + 1) * 128 + cc] = b1;
            } else {
                if (ea < E)     latbuf[(size_t)ea * 128 + cc] = b0;
                if (ea + 1 < E) latbuf[(size_t)(ea + 1) * 128 + cc] = b1;
            }
        }
    __syncthreads();

    // GEMM3: lat(128) @ Wenv0 -> w0; env_weight stores from accumulators.
#pragma unroll
    for (int s = 0; s < 4; ++s) acc[s] = z;
    gemm_rows<4, 4, 136>(&Ls[0][0], Whenv0 + w * 4 * 512, Wlenv0 + w * 4 * 512, lane, acc);
    {
        const int col = w * 16 + r;
        u16* dstbase = (col < 64) ? featbuf : enve;
        const int wcol = col & 63;
        if (full) {
#pragma unroll
            for (int s = 0; s < 4; ++s)
#pragma unroll
                for (int jj = 0; jj < 4; ++jj) {
                    int row = s * 16 + q * 4 + jj;
                    float4 av = *(const float4*)&sattr[row][0];
                    env_store(dstbase + (size_t)(e0 + row) * 128, wcol, acc[s][jj] * RSQRT128, av);
                }
        } else {
#pragma unroll
            for (int s = 0; s < 4; ++s)
#pragma unroll
                for (int jj = 0; jj < 4; ++jj) {
                    int row = s * 16 + q * 4 + jj;
                    int e = e0 + row;
                    if (e >= E) continue;
                    float4 av = *(const float4*)&sattr[row][0];
                    env_store(dstbase + (size_t)e * 128, wcol, acc[s][jj] * RSQRT128, av);
                }
        }
    }
}

// ---------------------------------------------------------------------------
// Phase B: tensor products (streamed from global) + mix; new_lat MLP; lat2;
// w1 -> env_e rows. Col-tile-per-wave GEMMs; HW bf16 converts throughout.
// ---------------------------------------------------------------------------
__global__ __launch_bounds__(512, 6) void phaseB(
    const int* __restrict__ eidx, const float* __restrict__ attr,
    const u16* __restrict__ env0b,
    const u16* __restrict__ Whs0, const u16* __restrict__ Wls0,
    const u16* __restrict__ Whv0, const u16* __restrict__ Wlv0,
    const u16* __restrict__ Whl10, const u16* __restrict__ Wll10,
    const u16* __restrict__ Whl11, const u16* __restrict__ Wll11,
    const u16* __restrict__ Whe1, const u16* __restrict__ Wle1,
    u16* __restrict__ latbuf, u16* __restrict__ featbuf,
    u16* __restrict__ enve, int E)
{
    __shared__ __align__(16) char sm[52480];
    u16 (*X4)[200] = (u16 (*)[200])sm;                    // 25600: lat|ss|vv -> lat2
    u16 (*P)[200]  = (u16 (*)[200])(sm + 25600);          // 25600: sv|vs per dim (192 used)
    u16 (*Hs)[136] = (u16 (*)[136])(sm + 25600);          // overlay P (dead post-mix)
    float (*sattr)[4] = (float (*)[4])(sm + 51200);       // 1024

    const int tid = threadIdx.x;
    const int lane = tid & 63;
    const int w = tid >> 6;
    const int e0 = blockIdx.x * 64;
    const int E1 = E - 1;
    const int r = lane & 15, q = lane >> 4;
    const bool full = (e0 + 64 <= E);

    if (tid < 256) { int t = tid >> 2, c = tid & 3; sattr[t][c] = attr[(size_t)min(e0 + t, E1) * 4 + c]; }

    // lat -> X4[:, 0:128]
    for (int i = tid; i < 64 * 16; i += 512) {
        int t = i >> 4, dc = i & 15;
        *(bf8_t*)&X4[t][dc * 8] = ((const bf8_t*)(latbuf + (size_t)min(e0 + t, E1) * 128))[dc];
    }

    // tensor-product pass: ss->X4[128+m], vv->X4[160+m], sv_d/vs_d -> P.
    {
        const int t = tid >> 3, cg = tid & 7;
        const int e = min(e0 + t, E1);
        const int nd = eidx[e];
        const u16* fp = featbuf + (size_t)e * 128 + cg * 16;
        const u16* gp = env0b + (size_t)nd * 128 + cg * 16;
        bf8_t fA = *(const bf8_t*)fp;
        bf8_t fB = *(const bf8_t*)(fp + 8);
        bf8_t gA = *(const bf8_t*)gp;
        bf8_t gB = *(const bf8_t*)(gp + 8);
        float ssf[4], vvf[4], svf[3][4], vsf[3][4];
#pragma unroll
        for (int c = 0; c < 4; ++c) {
            float f0, f1, f2, f3, g0, g1, g2, g3;
            if (c < 2) {
                f0 = bf2f((u16)fA[4 * c]);     g0 = bf2f((u16)gA[4 * c]);
                f1 = bf2f((u16)fA[4 * c + 1]); g1 = bf2f((u16)gA[4 * c + 1]);
                f2 = bf2f((u16)fA[4 * c + 2]); g2 = bf2f((u16)gA[4 * c + 2]);
                f3 = bf2f((u16)fA[4 * c + 3]); g3 = bf2f((u16)gA[4 * c + 3]);
            } else {
                int cc = c - 2;
                f0 = bf2f((u16)fB[4 * cc]);     g0 = bf2f((u16)gB[4 * cc]);
                f1 = bf2f((u16)fB[4 * cc + 1]); g1 = bf2f((u16)gB[4 * cc + 1]);
                f2 = bf2f((u16)fB[4 * cc + 2]); g2 = bf2f((u16)gB[4 * cc + 2]);
                f3 = bf2f((u16)fB[4 * cc + 3]); g3 = bf2f((u16)gB[4 * cc + 3]);
            }
            ssf[c] = f0 * g0;
            vvf[c] = (f1 * g1 + f2 * g2 + f3 * g3) * INV_SQRT3;
            svf[0][c] = f0 * g1;  svf[1][c] = f0 * g2;  svf[2][c] = f0 * g3;
            vsf[0][c] = f1 * g0;  vsf[1][c] = f2 * g0;  vsf[2][c] = f3 * g0;
        }
        *(uint2*)&X4[t][128 + 4 * cg] = make_uint2(cvtpk(ssf[0], ssf[1]), cvtpk(ssf[2], ssf[3]));
        *(uint2*)&X4[t][160 + 4 * cg] = make_uint2(cvtpk(vvf[0], vvf[1]), cvtpk(vvf[2], vvf[3]));
#pragma unroll
        for (int d = 0; d < 3; ++d) {
            *(uint2*)&P[t][d * 64 + 4 * cg]      = make_uint2(cvtpk(svf[d][0], svf[d][1]), cvtpk(svf[d][2], svf[d][3]));
            *(uint2*)&P[t][d * 64 + 32 + 4 * cg] = make_uint2(cvtpk(vsf[d][0], vsf[d][1]), cvtpk(vsf[d][2], vsf[d][3]));
        }
    }
    __syncthreads();

    const f4_t z = {0.f, 0.f, 0.f, 0.f};

    // ---- mix: wave = (strip sw, col-half cw); B-frags loaded once, shared
    // across S and all 3 V dims.
    {
        const int sw = w >> 1, cw = w & 1;
        f4_t aS = z, aV[3] = {z, z, z};
        const u16* bsh = Whs0 + cw * 2 * 512;
        const u16* bsl = Wls0 + cw * 2 * 512;
        const u16* bvh = Whv0 + cw * 2 * 512;
        const u16* bvl = Wlv0 + cw * 2 * 512;
        bf8_t s0h = *(const bf8_t*)(bsh + lane * 8);
        bf8_t s0l = *(const bf8_t*)(bsl + lane * 8);
        bf8_t s1h = *(const bf8_t*)(bsh + 512 + lane * 8);
        bf8_t s1l = *(const bf8_t*)(bsl + 512 + lane * 8);
        bf8_t v0h = *(const bf8_t*)(bvh + lane * 8);
        bf8_t v0l = *(const bf8_t*)(bvl + lane * 8);
        bf8_t v1h = *(const bf8_t*)(bvh + 512 + lane * 8);
        bf8_t v1l = *(const bf8_t*)(bvl + 512 + lane * 8);
        const u16* arow = &X4[sw * 16 + r][0];
        bf8_t a0 = *(const bf8_t*)(arow + 128 + q * 8);
        bf8_t a1 = *(const bf8_t*)(arow + 160 + q * 8);
        aS = MFMA16(a0, s0l, aS, 0, 0, 0);
        aS = MFMA16(a0, s0h, aS, 0, 0, 0);
        aS = MFMA16(a1, s1l, aS, 0, 0, 0);
        aS = MFMA16(a1, s1h, aS, 0, 0, 0);
        const u16* prow = &P[sw * 16 + r][0];
#pragma unroll
        for (int d = 0; d < 3; ++d) {
            bf8_t p0 = *(const bf8_t*)(prow + d * 64 + q * 8);
            bf8_t p1 = *(const bf8_t*)(prow + d * 64 + 32 + q * 8);
            aV[d] = MFMA16(p0, v0l, aV[d], 0, 0, 0);
            aV[d] = MFMA16(p0, v0h, aV[d], 0, 0, 0);
            aV[d] = MFMA16(p1, v1l, aV[d], 0, 0, 0);
            aV[d] = MFMA16(p1, v1h, aV[d], 0, 0, 0);
        }
        // feat2 direct to global: one 8B store per reg
        const int m = cw * 16 + r;
#pragma unroll
        for (int reg = 0; reg < 4; ++reg) {
            int e = e0 + sw * 16 + q * 4 + reg;
            if (full || e < E) {
                uint2 pv;
                pv.x = cvtpk(aS[reg] * RSQRT64,
                             aV[0][reg] * (RSQRT64 * INV_SQRT3));
                pv.y = cvtpk(aV[1][reg] * (RSQRT64 * INV_SQRT3),
                             aV[2][reg] * (RSQRT64 * INV_SQRT3));
                *(uint2*)(featbuf + (size_t)e * 128 + 4 * m) = pv;
            }
        }
    }

    // GEMM4: [lat|sscal](192) @ Wlat1_0
    f4_t acc[4];
#pragma unroll
    for (int s = 0; s < 4; ++s) acc[s] = z;
    gemm_rows<6, 4, 200>(&X4[0][0], Whl10 + w * 6 * 512, Wll10 + w * 6 * 512, lane, acc);
    __syncthreads();   // all P reads (mix) done -> Hs may overwrite P
#pragma unroll
    for (int s = 0; s < 4; ++s)
#pragma unroll
        for (int jj = 0; jj < 4; jj += 2) {
            u32 pk = cvtpk(silu_f(acc[s][jj] * RSQRT192), silu_f(acc[s][jj + 1] * RSQRT192));
            Hs[s * 16 + q * 4 + jj][w * 16 + r]     = (u16)pk;
            Hs[s * 16 + q * 4 + jj + 1][w * 16 + r] = (u16)(pk >> 16);
        }
    __syncthreads();

    // GEMM5: h @ Wlat1_1 -> new_lat; lat2 = C*(lat+new_lat) in place in X4
#pragma unroll
    for (int s = 0; s < 4; ++s) acc[s] = z;
    gemm_rows<4, 4, 136>(&Hs[0][0], Whl11 + w * 4 * 512, Wll11 + w * 4 * 512, lane, acc);
#pragma unroll
    for (int s = 0; s < 4; ++s)
#pragma unroll
        for (int jj = 0; jj < 4; jj += 2) {
            int row0 = s * 16 + q * 4 + jj, cc = w * 16 + r;
            float l2a = C_HALF * (bf2f(X4[row0][cc]) + acc[s][jj] * RSQRT128);
            float l2b = C_HALF * (bf2f(X4[row0 + 1][cc]) + acc[s][jj + 1] * RSQRT128);
            u32 pk = cvtpk(l2a, l2b);
            X4[row0][cc]     = (u16)pk;       // cells owned by this lane-reg only
            X4[row0 + 1][cc] = (u16)(pk >> 16);
        }
    __syncthreads();

    // lat2 -> latbuf ; GEMM6: lat2 @ Wenv1(128x64) -> w1 -> env_e rows
    if (full) {
        for (int i = tid; i < 64 * 16; i += 512) {
            int t = i >> 4, dc = i & 15;
            ((bf8_t*)(latbuf + (size_t)(e0 + t) * 128))[dc] = *(const bf8_t*)&X4[t][dc * 8];
        }
    } else {
        for (int i = tid; i < 64 * 16; i += 512) {
            int t = i >> 4, dc = i & 15;
            int e = e0 + t;
            if (e < E) ((bf8_t*)(latbuf + (size_t)e * 128))[dc] = *(const bf8_t*)&X4[t][dc * 8];
        }
    }
    {
        const int ct = w & 3, rh = w >> 2;   // col tile 0..3, row half 0..1
        f4_t a6[2] = {z, z};
        gemm_rows<4, 2, 200>(&X4[rh * 32][0], Whe1 + ct * 4 * 512, Wle1 + ct * 4 * 512, lane, a6);
        const int col = ct * 16 + r;         // 0..63
#pragma unroll
        for (int s = 0; s < 2; ++s)
#pragma unroll
            for (int jj = 0; jj < 4; ++jj) {
                int row = rh * 32 + s * 16 + q * 4 + jj;
                int e = e0 + row;
                if (!full && e >= E) continue;
                float4 av = *(const float4*)&sattr[row][0];
                env_store(enve + (size_t)e * 128, col, a6[s][jj] * RSQRT128, av);
            }
    }
}

// ---------------------------------------------------------------------------
// Phase C: scalars1 streamed from global, final MLP, out mix.
// ---------------------------------------------------------------------------
__global__ __launch_bounds__(512, 6) void phaseC(
    const int* __restrict__ eidx, const u16* __restrict__ env1b,
    const u16* __restrict__ Whf0, const u16* __restrict__ Wlf0,
    const u16* __restrict__ Whf1, const u16* __restrict__ Wlf1,
    const u16* __restrict__ latbuf, const u16* __restrict__ featbuf,
    float* __restrict__ outp, int E)
{
    __shared__ __align__(16) char sm[43008];
    u16 (*X7)[200] = (u16 (*)[200])sm;                    // 25600: lat2|scal1
    u16 (*Hs)[136] = (u16 (*)[136])(sm + 25600);          // 17408

    const int tid = threadIdx.x;
    const int lane = tid & 63;
    const int w = tid >> 6;
    const int e0 = blockIdx.x * 64;
    const int E1 = E - 1;
    const int r = lane & 15, q = lane >> 4;
    const bool full = (e0 + 64 <= E);

    // lat2 -> X7[:, 0:128]
    for (int i = tid; i < 64 * 16; i += 512) {
        int t = i >> 4, dc = i & 15;
        *(bf8_t*)&X7[t][dc * 8] = ((const bf8_t*)(latbuf + (size_t)min(e0 + t, E1) * 128))[dc];
    }

    // scalars1 pass: ss/vv from feat2 x env1, streamed from global
    {
        const int t = tid >> 3, cg = tid & 7;
        const int e = min(e0 + t, E1);
        const int nd = eidx[e];
        const u16* fp = featbuf + (size_t)e * 128 + cg * 16;
        const u16* gp = env1b + (size_t)nd * 128 + cg * 16;
        bf8_t fA = *(const bf8_t*)fp;
        bf8_t fB = *(const bf8_t*)(fp + 8);
        bf8_t gA = *(const bf8_t*)gp;
        bf8_t gB = *(const bf8_t*)(gp + 8);
        float ssf[4], vvf[4];
#pragma unroll
        for (int c = 0; c < 4; ++c) {
            float f0, f1, f2, f3, g0, g1, g2, g3;
            if (c < 2) {
                f0 = bf2f((u16)fA[4 * c]);     g0 = bf2f((u16)gA[4 * c]);
                f1 = bf2f((u16)fA[4 * c + 1]); g1 = bf2f((u16)gA[4 * c + 1]);
                f2 = bf2f((u16)fA[4 * c + 2]); g2 = bf2f((u16)gA[4 * c + 2]);
                f3 = bf2f((u16)fA[4 * c + 3]); g3 = bf2f((u16)gA[4 * c + 3]);
            } else {
                int cc = c - 2;
                f0 = bf2f((u16)fB[4 * cc]);     g0 = bf2f((u16)gB[4 * cc]);
                f1 = bf2f((u16)fB[4 * cc + 1]); g1 = bf2f((u16)gB[4 * cc + 1]);
                f2 = bf2f((u16)fB[4 * cc + 2]); g2 = bf2f((u16)gB[4 * cc + 2]);
                f3 = bf2f((u16)fB[4 * cc + 3]); g3 = bf2f((u16)gB[4 * cc + 3]);
            }
            ssf[c] = f0 * g0;
            vvf[c] = (f1 * g1 + f2 * g2 + f3 * g3) * INV_SQRT3;
        }
        *(uint2*)&X7[t][128 + 4 * cg] = make_uint2(cvtpk(ssf[0], ssf[1]), cvtpk(ssf[2], ssf[3]));
        *(uint2*)&X7[t][160 + 4 * cg] = make_uint2(cvtpk(vvf[0], vvf[1]), cvtpk(vvf[2], vvf[3]));
    }
    __syncthreads();

    const f4_t z = {0.f, 0.f, 0.f, 0.f};
    f4_t acc[4];
#pragma unroll
    for (int s = 0; s < 4; ++s) acc[s] = z;
    gemm_rows<6, 4, 200>(&X7[0][0], Whf0 + w * 6 * 512, Wlf0 + w * 6 * 512, lane, acc);
    // Hs is a fresh region (disjoint from X7) -> no barrier needed before writes
#pragma unroll
    for (int s = 0; s < 4; ++s)
#pragma unroll
        for (int jj = 0; jj < 4; jj += 2) {
            u32 pk = cvtpk(silu_f(acc[s][jj] * RSQRT192), silu_f(acc[s][jj + 1] * RSQRT192));
            Hs[s * 16 + q * 4 + jj][w * 16 + r]     = (u16)pk;
            Hs[s * 16 + q * 4 + jj + 1][w * 16 + r] = (u16)(pk >> 16);
        }
    __syncthreads();

#pragma unroll
    for (int s = 0; s < 4; ++s) acc[s] = z;
    gemm_rows<4, 4, 136>(&Hs[0][0], Whf1 + w * 4 * 512, Wlf1 + w * 4 * 512, lane, acc);
    if (full) {
#pragma unroll
        for (int s = 0; s < 4; ++s)
#pragma unroll
            for (int jj = 0; jj < 4; ++jj) {
                int row = s * 16 + q * 4 + jj, cc = w * 16 + r;
                outp[(size_t)(e0 + row) * 128 + cc] =
                    SQ23 * bf2f(X7[row][cc]) + SQ13 * (acc[s][jj] * RSQRT128);
            }
    } else {
#pragma unroll
        for (int s = 0; s < 4; ++s)
#pragma unroll
            for (int jj = 0; jj < 4; ++jj) {
                int row = s * 16 + q * 4 + jj, cc = w * 16 + r;
                int e = e0 + row;
                if (e < E)
                    outp[(size_t)e * 128 + cc] =
                        SQ23 * bf2f(X7[row][cc]) + SQ13 * (acc[s][jj] * RSQRT128);
            }
    }
}

extern "C" void kernel_launch(void* const* d_in, const int* in_sizes, int n_in,
                              void* d_out, int out_size, void* d_ws, size_t ws_size,
                              hipStream_t stream)
{
    const int E  = in_sizes[0] / 2;
    const int NN = 12500;

    const int*   eidx    = (const int*)d_in[0];
    const float* attr    = (const float*)d_in[1];
    const float* inv     = (const float*)d_in[2];
    float* outp = (float*)d_out;

    // ws: lat bf16 | feat bf16 | env0b, env1b bf16 | weights | sort ints
    u16* latbuf  = (u16*)d_ws;
    u16* featbuf = latbuf + (size_t)E * 128;
    u16* env0b   = featbuf + (size_t)E * 128;
    u16* env1b   = env0b + (size_t)NN * 128;
    u16* p = env1b + (size_t)NN * 128;
    auto carve = [&](int elems) { u16* q0 = p; p += elems; return q0; };
    u16 *Wh2b0 = carve(128 * 32),  *Wl2b0 = carve(128 * 32);
    u16 *Wh2b1 = carve(128 * 128), *Wl2b1 = carve(128 * 128);
    u16 *Whe0  = carve(128 * 128), *Wle0  = carve(128 * 128);
    u16 *Whl10 = carve(128 * 192), *Wll10 = carve(128 * 192);
    u16 *Whl11 = carve(128 * 128), *Wll11 = carve(128 * 128);
    u16 *Whe1  = carve(64 * 128),  *Wle1  = carve(64 * 128);
    u16 *Whs0  = carve(32 * 64),   *Wls0  = carve(32 * 64);
    u16 *Whv0  = carve(32 * 64),   *Wlv0  = carve(32 * 64);
    u16 *Whf0  = carve(128 * 192), *Wlf0  = carve(128 * 192);
    u16 *Whf1  = carve(128 * 128), *Wlf1  = carve(128 * 128);
    int* cnt;
    {
        size_t off_bytes = (size_t)((char*)p - (char*)d_ws);
        off_bytes = (off_bytes + 3) & ~(size_t)3;
        cnt = (int*)((char*)d_ws + off_bytes);
    }
    int* base   = cnt + NN;          // NN+1 entries
    int* cursor = base + NN + 1;
    int* sorted = cursor + NN;

    // env_e scratch: reuse d_out (fully overwritten by phaseC afterwards)
    u16* enve = (u16*)d_out;

    hipMemsetAsync(cnt, 0, NN * sizeof(int), stream);

    // ---- weight prep (one kernel) ----
    PDs P;
    auto setpd = [&](int i, const float* s, u16* h, u16* l, int K, int N, int Kp, int pm, int off) {
        P.d[i] = {s, h, l, K, N, Kp, pm, off, N * Kp};
    };
    setpd(0, (const float*)d_in[3],  Wh2b0, Wl2b0,   8, 128,  32, 0, 0);
    setpd(1, (const float*)d_in[4],  Wh2b1, Wl2b1, 128, 128, 128, 0, 4096);
    setpd(2, (const float*)d_in[5],  Whe0,  Wle0,  128, 128, 128, 0, 20480);
    setpd(3, (const float*)d_in[6],  Whl10, Wll10, 192, 128, 192, 1, 36864);
    setpd(4, (const float*)d_in[7],  Whl11, Wll11, 128, 128, 128, 0, 61440);
    setpd(5, (const float*)d_in[8],  Whe1,  Wle1,  128,  64, 128, 0, 77824);
    setpd(6, (const float*)d_in[9],  Whs0,  Wls0,   64,  32,  64, 0, 86016);
    setpd(7, (const float*)d_in[10], Whv0,  Wlv0,   64,  32,  64, 0, 88064);
    setpd(8, (const float*)d_in[11], Whf0,  Wlf0,  192, 128, 192, 1, 90112);
    setpd(9, (const float*)d_in[12], Whf1,  Wlf1,  128, 128, 128, 0, 114688);
    const int total = 131072;
    prep_all<<<(total + 255) / 256, 256, 0, stream>>>(P, total);

    // ---- counting sort of edges by center node ----
    hist_k<<<(E + 255) / 256, 256, 0, stream>>>(eidx, cnt, E);
    scan_k<<<1, 1024, 0, stream>>>(cnt, base, cursor, NN);
    scatter_k<<<(E + 255) / 256, 256, 0, stream>>>(eidx, cursor, sorted, E);

    const int nb = (E + 63) / 64;
    phaseA<<<nb, 512, 0, stream>>>(attr, inv, Wh2b0, Wl2b0, Wh2b1, Wl2b1,
                                   Whe0, Wle0, latbuf, featbuf, enve, E);
    reduce_env<<<(NN + 3) / 4, 256, 0, stream>>>(base, sorted, enve, env0b, NN);
    phaseB<<<nb, 512, 0, stream>>>(eidx, attr, env0b, Whs0, Wls0, Whv0, Wlv0,
                                   Whl10, Wll10, Whl11, Wll11, Whe1, Wle1,
                                   latbuf, featbuf, enve, E);
    reduce_env<<<(NN + 3) / 4, 256, 0, stream>>>(base, sorted, enve, env1b, NN);
    phaseC<<<nb, 512, 0, stream>>>(eidx, env1b, Whf0, Wlf0, Whf1, Wlf1,
                                   latbuf, featbuf, outp, E);
}

// Round 5
// 374.009 us; speedup vs baseline: 2.7419x; 1.0956x over previous
//
#include <hip/hip_runtime.h>

typedef __attribute__((ext_vector_type(8))) short bf8_t;   // 8 x bf16 (4 VGPRs)
typedef __attribute__((ext_vector_type(4))) short bf4_t;   // 4 x bf16 (2 VGPRs)
typedef __attribute__((ext_vector_type(4))) float f4_t;    // 4 x fp32 acc
typedef unsigned short u16;
typedef unsigned int u32;

#define MFMA16 __builtin_amdgcn_mfma_f32_16x16x32_bf16

#define RSQRT8    0.35355339059327373f
#define RSQRT128  0.08838834764831845f
#define RSQRT192  0.07216878364870323f
#define RSQRT64   0.125f
#define INV_SQRT3 0.57735026918962576f
#define SEG_NORM  0.25f       /* 1/sqrt(16) */
#define C_HALF    0.70710678118654752f
#define SQ23      0.81649658092772603f
#define SQ13      0.57735026918962576f

__device__ __forceinline__ float bf2f(u16 b) {
    return __uint_as_float(((u32)b) << 16);
}
// software RNE (cold paths only; bit-identical to HW cvt)
__device__ __forceinline__ u16 f2bf(float f) {
    u32 u = __float_as_uint(f);
    u += 0x7FFFu + ((u >> 16) & 1u);
    return (u16)(u >> 16);
}
// hardware RNE pack: lo -> bits[15:0], hi -> bits[31:16]; 1 VALU inst
__device__ __forceinline__ u32 cvtpk(float lo, float hi) {
    u32 r;
    asm("v_cvt_pk_bf16_f32 %0, %1, %2" : "=v"(r) : "v"(lo), "v"(hi));
    return r;
}
__device__ __forceinline__ u16 f2bf_hw(float f) { return (u16)cvtpk(f, f); }
__device__ __forceinline__ float silu_f(float x) {
    return x * __builtin_amdgcn_rcpf(1.0f + __expf(-x));
}

// ---------------------------------------------------------------------------
// gemm_rows: one wave owns ONE 16-col tile (weights pre-offset by caller) and
// sweeps NSTR row-strips of 16. B-fragments batched in chunks; AS is a
// compile-time LDS row stride. FP order: ks ascending, lo-then-hi.
// ---------------------------------------------------------------------------
template<int KS, int NSTR, int AS>
__device__ __forceinline__ void gemm_rows(
    const u16* A,
    const u16* __restrict__ Wh, const u16* __restrict__ Wl,
    int lane, f4_t* acc)
{
    const int r = lane & 15;
    const int q = lane >> 4;
    const u16* ab = A + r * AS + q * 8;
    constexpr int CH = (KS > 4) ? 3 : KS;
#pragma unroll
    for (int c0 = 0; c0 < KS; c0 += CH) {
        bf8_t bh[CH], bl[CH];
#pragma unroll
        for (int j = 0; j < CH; ++j) {
            bh[j] = *(const bf8_t*)(Wh + ((c0 + j) * 64 + lane) * 8);
            bl[j] = *(const bf8_t*)(Wl + ((c0 + j) * 64 + lane) * 8);
        }
#pragma unroll
        for (int j = 0; j < CH; ++j) {
#pragma unroll
            for (int s = 0; s < NSTR; ++s) {
                bf8_t a = *(const bf8_t*)(ab + s * 16 * AS + (c0 + j) * 32);
                acc[s] = MFMA16(a, bl[j], acc[s], 0, 0, 0);
                acc[s] = MFMA16(a, bh[j], acc[s], 0, 0, 0);
            }
        }
    }
}

// ---------------------------------------------------------------------------
// Weight prep (+ fused edge histogram): fp32 [K][N] -> bf16 hi/lo in
// FRAGMENT-LINEAR layout: element ((tile*KS + ks)*64 + lane)*8 + j  holds
// W^T[col = tile*16 + (lane&15)][k = ks*32 + (lane>>4)*8 + j].
// ---------------------------------------------------------------------------
struct PD { const float* src; u16* hi; u16* lo; int K, N, Kp, perm, off, cnt; };
struct PDs { PD d[10]; };

__global__ __launch_bounds__(256) void prep_all(PDs P, int total,
                                                const int* __restrict__ eidx,
                                                int* __restrict__ cnt, int E)
{
    int i = blockIdx.x * 256 + threadIdx.x;
    if (i < E) atomicAdd(&cnt[eidx[i]], 1);
    if (i >= total) return;
#pragma unroll
    for (int rg = 0; rg < 10; ++rg) {
        if (i >= P.d[rg].off && i < P.d[rg].off + P.d[rg].cnt) {
            int li = i - P.d[rg].off;
            int KS = P.d[rg].Kp >> 5;
            int tile = li / (KS * 512);
            int rem  = li - tile * KS * 512;
            int ks   = rem >> 9;
            int lane = (rem >> 3) & 63;
            int j    = rem & 7;
            int n = tile * 16 + (lane & 15);
            int k = ks * 32 + (lane >> 4) * 8 + j;
            int ksrc = k;
            if (P.d[rg].perm && k >= 128)
                ksrc = (k < 160) ? (128 + 2 * (k - 128)) : (129 + 2 * (k - 160));
            float wv = (ksrc < P.d[rg].K) ? P.d[rg].src[(size_t)ksrc * P.d[rg].N + n] : 0.f;
            u16 h = f2bf(wv);
            P.d[rg].hi[li] = h;
            P.d[rg].lo[li] = f2bf(wv - bf2f(h));
        }
    }
}

__global__ __launch_bounds__(1024) void scan_k(const int* __restrict__ cnt,
                                               int* __restrict__ base,
                                               int* __restrict__ cursor, int NN)
{
    __shared__ int part[1024];
    const int t = threadIdx.x;
    const int CHK = (NN + 1023) >> 10;
    int s = 0;
    for (int k = 0; k < CHK; ++k) { int idx = t * CHK + k; if (idx < NN) s += cnt[idx]; }
    part[t] = s;
    __syncthreads();
    for (int off = 1; off < 1024; off <<= 1) {
        int v = (t >= off) ? part[t - off] : 0;
        __syncthreads();
        part[t] += v;
        __syncthreads();
    }
    if (t == 0) base[NN] = part[1023];
    int run = (t == 0) ? 0 : part[t - 1];
    for (int k = 0; k < CHK; ++k) {
        int idx = t * CHK + k;
        if (idx < NN) { base[idx] = run; cursor[idx] = run; run += cnt[idx]; }
    }
}

__global__ __launch_bounds__(256) void scatter_k(const int* __restrict__ eidx,
                                                 int* __restrict__ cursor,
                                                 int* __restrict__ sorted, int E)
{
    int i = blockIdx.x * 256 + threadIdx.x;
    if (i < E) {
        int p = atomicAdd(&cursor[eidx[i]], 1);
        sorted[p] = i;
    }
}

// ---------------------------------------------------------------------------
// Segment reduction from WEIGHT-SPACE rows: env[node][c] =
//   SEG_NORM * sum_e  w[e][2m+(idx>0)] * attr[e][idx]   (c = 4m+idx).
// 4 nodes per 256-thr block; 64 threads/node, each owns channel pair
// (2ch, 2ch+1): one aligned u32 w-load + one float2 attr-load per edge.
// ---------------------------------------------------------------------------
__global__ __launch_bounds__(256) void reduce_env(
    const int* __restrict__ base, const int* __restrict__ sorted,
    const u16* __restrict__ envw, const float* __restrict__ attr,
    u16* __restrict__ env, int NN)
{
    const int node = blockIdx.x * 4 + (threadIdx.x >> 6);
    const int ch = threadIdx.x & 63;          // channel pair: 2ch, 2ch+1
    if (node >= NN) return;
    const int b = base[node], en = base[node + 1];
    const int wo = ch & ~1;                   // aligned u16 col of the u32 w-load
    const int ao = (ch & 1) * 2;              // attr index base: 0 -> (0,1), 1 -> (2,3)
    const bool odd = (ch & 1) != 0;
    float a0 = 0.f, a1 = 0.f;
    int i = b;
    for (; i + 3 < en; i += 4) {
        int s0 = sorted[i], s1 = sorted[i + 1], s2 = sorted[i + 2], s3 = sorted[i + 3];
        u32 w0 = *(const u32*)(envw + (size_t)s0 * 64 + wo);
        u32 w1 = *(const u32*)(envw + (size_t)s1 * 64 + wo);
        u32 w2 = *(const u32*)(envw + (size_t)s2 * 64 + wo);
        u32 w3 = *(const u32*)(envw + (size_t)s3 * 64 + wo);
        float2 v0 = *(const float2*)(attr + (size_t)s0 * 4 + ao);
        float2 v1 = *(const float2*)(attr + (size_t)s1 * 4 + ao);
        float2 v2 = *(const float2*)(attr + (size_t)s2 * 4 + ao);
        float2 v3 = *(const float2*)(attr + (size_t)s3 * 4 + ao);
        float l0 = bf2f((u16)(odd ? (w0 >> 16) : w0)), h0 = bf2f((u16)(w0 >> 16));
        float l1 = bf2f((u16)(odd ? (w1 >> 16) : w1)), h1 = bf2f((u16)(w1 >> 16));
        float l2 = bf2f((u16)(odd ? (w2 >> 16) : w2)), h2 = bf2f((u16)(w2 >> 16));
        float l3 = bf2f((u16)(odd ? (w3 >> 16) : w3)), h3 = bf2f((u16)(w3 >> 16));
        a0 += (l0 * v0.x + l1 * v1.x) + (l2 * v2.x + l3 * v3.x);
        a1 += (h0 * v0.y + h1 * v1.y) + (h2 * v2.y + h3 * v3.y);
    }
    for (; i < en; ++i) {
        int s0 = sorted[i];
        u32 w0 = *(const u32*)(envw + (size_t)s0 * 64 + wo);
        float2 v0 = *(const float2*)(attr + (size_t)s0 * 4 + ao);
        a0 += bf2f((u16)(odd ? (w0 >> 16) : w0)) * v0.x;
        a1 += bf2f((u16)(w0 >> 16)) * v0.y;
    }
    *(u32*)(env + (size_t)node * 128 + 2 * ch) = cvtpk(a0 * SEG_NORM, a1 * SEG_NORM);
}

// ---------------------------------------------------------------------------
// Phase A. 8 waves; wave w owns col tile w (16 cols), sweeps all 64 rows.
// GEMM3 now stores raw w0 cols: [0,64) -> featw, [64,128) -> envw (64ch rows).
// ---------------------------------------------------------------------------
__global__ __launch_bounds__(512, 6) void phaseA(
    const float* __restrict__ inv,
    const u16* __restrict__ Wh2b0, const u16* __restrict__ Wl2b0,
    const u16* __restrict__ Wh2b1, const u16* __restrict__ Wl2b1,
    const u16* __restrict__ Whenv0, const u16* __restrict__ Wlenv0,
    u16* __restrict__ latbuf, u16* __restrict__ featw,
    u16* __restrict__ envw, int E)
{
    __shared__ __align__(16) char sm[38912];
    u16 (*Xi)[32]  = (u16 (*)[32])sm;                     // 4096
    u16 (*Hs)[136] = (u16 (*)[136])(sm + 4096);           // 17408
    u16 (*Ls)[136] = (u16 (*)[136])(sm + 21504);          // 17408

    const int tid = threadIdx.x;
    const int lane = tid & 63;
    const int w = tid >> 6;
    const int e0 = blockIdx.x * 64;
    const int E1 = E - 1;
    const int r = lane & 15, q = lane >> 4;
    const bool full = (e0 + 64 <= E);

    for (int i = tid; i < 64 * 32; i += 512) {
        int t = i >> 5, c = i & 31;
        u16 v = 0;
        if (c < 8) v = f2bf_hw(inv[(size_t)min(e0 + t, E1) * 8 + c]);
        Xi[t][c] = v;
    }
    __syncthreads();

    const f4_t z = {0.f, 0.f, 0.f, 0.f};
    f4_t acc[4];

    // GEMM1: inv(8->32) @ W2b0 -> silu -> Hs
#pragma unroll
    for (int s = 0; s < 4; ++s) acc[s] = z;
    gemm_rows<1, 4, 32>(&Xi[0][0], Wh2b0 + w * 512, Wl2b0 + w * 512, lane, acc);
#pragma unroll
    for (int s = 0; s < 4; ++s)
#pragma unroll
        for (int jj = 0; jj < 4; jj += 2) {
            u32 pk = cvtpk(silu_f(acc[s][jj] * RSQRT8), silu_f(acc[s][jj + 1] * RSQRT8));
            Hs[s * 16 + q * 4 + jj][w * 16 + r]     = (u16)pk;
            Hs[s * 16 + q * 4 + jj + 1][w * 16 + r] = (u16)(pk >> 16);
        }
    __syncthreads();

    // GEMM2: h(128) @ W2b1 -> lat -> Ls + latbuf
#pragma unroll
    for (int s = 0; s < 4; ++s) acc[s] = z;
    gemm_rows<4, 4, 136>(&Hs[0][0], Wh2b1 + w * 4 * 512, Wl2b1 + w * 4 * 512, lane, acc);
#pragma unroll
    for (int s = 0; s < 4; ++s)
#pragma unroll
        for (int jj = 0; jj < 4; jj += 2) {
            int row0 = s * 16 + q * 4 + jj, cc = w * 16 + r;
            u32 pk = cvtpk(acc[s][jj] * RSQRT128, acc[s][jj + 1] * RSQRT128);
            u16 b0 = (u16)pk, b1 = (u16)(pk >> 16);
            Ls[row0][cc] = b0;
            Ls[row0 + 1][cc] = b1;
            int ea = e0 + row0;
            if (full) {
                latbuf[(size_t)ea * 128 + cc] = b0;
                latbuf[(size_t)(ea + 1) * 128 + cc] = b1;
            } else {
                if (ea < E)     latbuf[(size_t)ea * 128 + cc] = b0;
                if (ea + 1 < E) latbuf[(size_t)(ea + 1) * 128 + cc] = b1;
            }
        }
    __syncthreads();

    // GEMM3: lat(128) @ Wenv0 -> w0; store raw w-cols (64ch rows).
#pragma unroll
    for (int s = 0; s < 4; ++s) acc[s] = z;
    gemm_rows<4, 4, 136>(&Ls[0][0], Whenv0 + w * 4 * 512, Wlenv0 + w * 4 * 512, lane, acc);
    {
        const int col = w * 16 + r;
        u16* dstbase = (col < 64) ? featw : envw;
        const int wcol = col & 63;
#pragma unroll
        for (int s = 0; s < 4; ++s)
#pragma unroll
            for (int jj = 0; jj < 4; jj += 2) {
                int row0 = s * 16 + q * 4 + jj;
                u32 pk = cvtpk(acc[s][jj] * RSQRT128, acc[s][jj + 1] * RSQRT128);
                int ea = e0 + row0;
                if (full) {
                    dstbase[(size_t)ea * 64 + wcol] = (u16)pk;
                    dstbase[(size_t)(ea + 1) * 64 + wcol] = (u16)(pk >> 16);
                } else {
                    if (ea < E)     dstbase[(size_t)ea * 64 + wcol] = (u16)pk;
                    if (ea + 1 < E) dstbase[(size_t)(ea + 1) * 64 + wcol] = (u16)(pk >> 16);
                }
            }
    }
}

// ---------------------------------------------------------------------------
// Phase B: tensor products (w0 x attr x env0 reconstructed in registers) +
// mix; new_lat MLP; lat2; w1 stored raw (64ch rows) for reduce_env.
// ---------------------------------------------------------------------------
__global__ __launch_bounds__(512, 6) void phaseB(
    const int* __restrict__ eidx, const float* __restrict__ attr,
    const u16* __restrict__ env0b,
    const u16* __restrict__ featw, u16* __restrict__ envw,
    const u16* __restrict__ Whs0, const u16* __restrict__ Wls0,
    const u16* __restrict__ Whv0, const u16* __restrict__ Wlv0,
    const u16* __restrict__ Whl10, const u16* __restrict__ Wll10,
    const u16* __restrict__ Whl11, const u16* __restrict__ Wll11,
    const u16* __restrict__ Whe1, const u16* __restrict__ Wle1,
    u16* __restrict__ latbuf, u16* __restrict__ featbuf, int E)
{
    __shared__ __align__(16) char sm[51200];
    u16 (*X4)[200] = (u16 (*)[200])sm;                    // 25600: lat|ss|vv -> lat2
    u16 (*P)[200]  = (u16 (*)[200])(sm + 25600);          // 25600: sv|vs per dim (192 used)
    u16 (*Hs)[136] = (u16 (*)[136])(sm + 25600);          // overlay P (dead post-mix)

    const int tid = threadIdx.x;
    const int lane = tid & 63;
    const int w = tid >> 6;
    const int e0 = blockIdx.x * 64;
    const int E1 = E - 1;
    const int r = lane & 15, q = lane >> 4;
    const bool full = (e0 + 64 <= E);

    // lat -> X4[:, 0:128]
    for (int i = tid; i < 64 * 16; i += 512) {
        int t = i >> 4, dc = i & 15;
        *(bf8_t*)&X4[t][dc * 8] = ((const bf8_t*)(latbuf + (size_t)min(e0 + t, E1) * 128))[dc];
    }

    // tensor-product pass: f-channels reconstructed from w0 row x attr.
    {
        const int t = tid >> 3, cg = tid & 7;
        const int e = min(e0 + t, E1);
        const int nd = eidx[e];
        bf8_t wv = *(const bf8_t*)(featw + (size_t)e * 64 + cg * 8);
        const u16* gp = env0b + (size_t)nd * 128 + cg * 16;
        bf8_t gA = *(const bf8_t*)gp;
        bf8_t gB = *(const bf8_t*)(gp + 8);
        float4 av = *(const float4*)(attr + (size_t)e * 4);
        float ssf[4], vvf[4], svf[3][4], vsf[3][4];
#pragma unroll
        for (int c = 0; c < 4; ++c) {
            float wf0 = bf2f((u16)wv[2 * c]);
            float wf1 = bf2f((u16)wv[2 * c + 1]);
            float f0 = wf0 * av.x, f1 = wf1 * av.y, f2 = wf1 * av.z, f3 = wf1 * av.w;
            float g0, g1, g2, g3;
            if (c < 2) {
                g0 = bf2f((u16)gA[4 * c]);     g1 = bf2f((u16)gA[4 * c + 1]);
                g2 = bf2f((u16)gA[4 * c + 2]); g3 = bf2f((u16)gA[4 * c + 3]);
            } else {
                int cc = c - 2;
                g0 = bf2f((u16)gB[4 * cc]);     g1 = bf2f((u16)gB[4 * cc + 1]);
                g2 = bf2f((u16)gB[4 * cc + 2]); g3 = bf2f((u16)gB[4 * cc + 3]);
            }
            ssf[c] = f0 * g0;
            vvf[c] = (f1 * g1 + f2 * g2 + f3 * g3) * INV_SQRT3;
            svf[0][c] = f0 * g1;  svf[1][c] = f0 * g2;  svf[2][c] = f0 * g3;
            vsf[0][c] = f1 * g0;  vsf[1][c] = f2 * g0;  vsf[2][c] = f3 * g0;
        }
        *(uint2*)&X4[t][128 + 4 * cg] = make_uint2(cvtpk(ssf[0], ssf[1]), cvtpk(ssf[2], ssf[3]));
        *(uint2*)&X4[t][160 + 4 * cg] = make_uint2(cvtpk(vvf[0], vvf[1]), cvtpk(vvf[2], vvf[3]));
#pragma unroll
        for (int d = 0; d < 3; ++d) {
            *(uint2*)&P[t][d * 64 + 4 * cg]      = make_uint2(cvtpk(svf[d][0], svf[d][1]), cvtpk(svf[d][2], svf[d][3]));
            *(uint2*)&P[t][d * 64 + 32 + 4 * cg] = make_uint2(cvtpk(vsf[d][0], vsf[d][1]), cvtpk(vsf[d][2], vsf[d][3]));
        }
    }
    __syncthreads();

    const f4_t z = {0.f, 0.f, 0.f, 0.f};

    // ---- mix: wave = (strip sw, col-half cw); B-frags loaded once, shared
    // across S and all 3 V dims.
    {
        const int sw = w >> 1, cw = w & 1;
        f4_t aS = z, aV[3] = {z, z, z};
        const u16* bsh = Whs0 + cw * 2 * 512;
        const u16* bsl = Wls0 + cw * 2 * 512;
        const u16* bvh = Whv0 + cw * 2 * 512;
        const u16* bvl = Wlv0 + cw * 2 * 512;
        bf8_t s0h = *(const bf8_t*)(bsh + lane * 8);
        bf8_t s0l = *(const bf8_t*)(bsl + lane * 8);
        bf8_t s1h = *(const bf8_t*)(bsh + 512 + lane * 8);
        bf8_t s1l = *(const bf8_t*)(bsl + 512 + lane * 8);
        bf8_t v0h = *(const bf8_t*)(bvh + lane * 8);
        bf8_t v0l = *(const bf8_t*)(bvl + lane * 8);
        bf8_t v1h = *(const bf8_t*)(bvh + 512 + lane * 8);
        bf8_t v1l = *(const bf8_t*)(bvl + 512 + lane * 8);
        const u16* arow = &X4[sw * 16 + r][0];
        bf8_t a0 = *(const bf8_t*)(arow + 128 + q * 8);
        bf8_t a1 = *(const bf8_t*)(arow + 160 + q * 8);
        aS = MFMA16(a0, s0l, aS, 0, 0, 0);
        aS = MFMA16(a0, s0h, aS, 0, 0, 0);
        aS = MFMA16(a1, s1l, aS, 0, 0, 0);
        aS = MFMA16(a1, s1h, aS, 0, 0, 0);
        const u16* prow = &P[sw * 16 + r][0];
#pragma unroll
        for (int d = 0; d < 3; ++d) {
            bf8_t p0 = *(const bf8_t*)(prow + d * 64 + q * 8);
            bf8_t p1 = *(const bf8_t*)(prow + d * 64 + 32 + q * 8);
            aV[d] = MFMA16(p0, v0l, aV[d], 0, 0, 0);
            aV[d] = MFMA16(p0, v0h, aV[d], 0, 0, 0);
            aV[d] = MFMA16(p1, v1l, aV[d], 0, 0, 0);
            aV[d] = MFMA16(p1, v1h, aV[d], 0, 0, 0);
        }
        // feat2 direct to global: one 8B store per reg
        const int m = cw * 16 + r;
#pragma unroll
        for (int reg = 0; reg < 4; ++reg) {
            int e = e0 + sw * 16 + q * 4 + reg;
            if (full || e < E) {
                uint2 pv;
                pv.x = cvtpk(aS[reg] * RSQRT64,
                             aV[0][reg] * (RSQRT64 * INV_SQRT3));
                pv.y = cvtpk(aV[1][reg] * (RSQRT64 * INV_SQRT3),
                             aV[2][reg] * (RSQRT64 * INV_SQRT3));
                *(uint2*)(featbuf + (size_t)e * 128 + 4 * m) = pv;
            }
        }
    }

    // GEMM4: [lat|sscal](192) @ Wlat1_0
    f4_t acc[4];
#pragma unroll
    for (int s = 0; s < 4; ++s) acc[s] = z;
    gemm_rows<6, 4, 200>(&X4[0][0], Whl10 + w * 6 * 512, Wll10 + w * 6 * 512, lane, acc);
    __syncthreads();   // all P reads (mix) done -> Hs may overwrite P
#pragma unroll
    for (int s = 0; s < 4; ++s)
#pragma unroll
        for (int jj = 0; jj < 4; jj += 2) {
            u32 pk = cvtpk(silu_f(acc[s][jj] * RSQRT192), silu_f(acc[s][jj + 1] * RSQRT192));
            Hs[s * 16 + q * 4 + jj][w * 16 + r]     = (u16)pk;
            Hs[s * 16 + q * 4 + jj + 1][w * 16 + r] = (u16)(pk >> 16);
        }
    __syncthreads();

    // GEMM5: h @ Wlat1_1 -> new_lat; lat2 = C*(lat+new_lat) in place in X4
#pragma unroll
    for (int s = 0; s < 4; ++s) acc[s] = z;
    gemm_rows<4, 4, 136>(&Hs[0][0], Whl11 + w * 4 * 512, Wll11 + w * 4 * 512, lane, acc);
#pragma unroll
    for (int s = 0; s < 4; ++s)
#pragma unroll
        for (int jj = 0; jj < 4; jj += 2) {
            int row0 = s * 16 + q * 4 + jj, cc = w * 16 + r;
            float l2a = C_HALF * (bf2f(X4[row0][cc]) + acc[s][jj] * RSQRT128);
            float l2b = C_HALF * (bf2f(X4[row0 + 1][cc]) + acc[s][jj + 1] * RSQRT128);
            u32 pk = cvtpk(l2a, l2b);
            X4[row0][cc]     = (u16)pk;       // cells owned by this lane-reg only
            X4[row0 + 1][cc] = (u16)(pk >> 16);
        }
    __syncthreads();

    // lat2 -> latbuf ; GEMM6: lat2 @ Wenv1(128x64) -> w1 -> raw 64ch rows
    if (full) {
        for (int i = tid; i < 64 * 16; i += 512) {
            int t = i >> 4, dc = i & 15;
            ((bf8_t*)(latbuf + (size_t)(e0 + t) * 128))[dc] = *(const bf8_t*)&X4[t][dc * 8];
        }
    } else {
        for (int i = tid; i < 64 * 16; i += 512) {
            int t = i >> 4, dc = i & 15;
            int e = e0 + t;
            if (e < E) ((bf8_t*)(latbuf + (size_t)e * 128))[dc] = *(const bf8_t*)&X4[t][dc * 8];
        }
    }
    {
        const int ct = w & 3, rh = w >> 2;   // col tile 0..3, row half 0..1
        f4_t a6[2] = {z, z};
        gemm_rows<4, 2, 200>(&X4[rh * 32][0], Whe1 + ct * 4 * 512, Wle1 + ct * 4 * 512, lane, a6);
        const int col = ct * 16 + r;         // 0..63
#pragma unroll
        for (int s = 0; s < 2; ++s)
#pragma unroll
            for (int jj = 0; jj < 4; jj += 2) {
                int row0 = rh * 32 + s * 16 + q * 4 + jj;
                u32 pk = cvtpk(a6[s][jj] * RSQRT128, a6[s][jj + 1] * RSQRT128);
                int ea = e0 + row0;
                if (full) {
                    envw[(size_t)ea * 64 + col] = (u16)pk;
                    envw[(size_t)(ea + 1) * 64 + col] = (u16)(pk >> 16);
                } else {
                    if (ea < E)     envw[(size_t)ea * 64 + col] = (u16)pk;
                    if (ea + 1 < E) envw[(size_t)(ea + 1) * 64 + col] = (u16)(pk >> 16);
                }
            }
    }
}

// ---------------------------------------------------------------------------
// Phase C: scalars1 streamed from global, final MLP, out mix.
// ---------------------------------------------------------------------------
__global__ __launch_bounds__(512, 6) void phaseC(
    const int* __restrict__ eidx, const u16* __restrict__ env1b,
    const u16* __restrict__ Whf0, const u16* __restrict__ Wlf0,
    const u16* __restrict__ Whf1, const u16* __restrict__ Wlf1,
    const u16* __restrict__ latbuf, const u16* __restrict__ featbuf,
    float* __restrict__ outp, int E)
{
    __shared__ __align__(16) char sm[43008];
    u16 (*X7)[200] = (u16 (*)[200])sm;                    // 25600: lat2|scal1
    u16 (*Hs)[136] = (u16 (*)[136])(sm + 25600);          // 17408

    const int tid = threadIdx.x;
    const int lane = tid & 63;
    const int w = tid >> 6;
    const int e0 = blockIdx.x * 64;
    const int E1 = E - 1;
    const int r = lane & 15, q = lane >> 4;
    const bool full = (e0 + 64 <= E);

    // lat2 -> X7[:, 0:128]
    for (int i = tid; i < 64 * 16; i += 512) {
        int t = i >> 4, dc = i & 15;
        *(bf8_t*)&X7[t][dc * 8] = ((const bf8_t*)(latbuf + (size_t)min(e0 + t, E1) * 128))[dc];
    }

    // scalars1 pass: ss/vv from feat2 x env1, streamed from global
    {
        const int t = tid >> 3, cg = tid & 7;
        const int e = min(e0 + t, E1);
        const int nd = eidx[e];
        const u16* fp = featbuf + (size_t)e * 128 + cg * 16;
        const u16* gp = env1b + (size_t)nd * 128 + cg * 16;
        bf8_t fA = *(const bf8_t*)fp;
        bf8_t fB = *(const bf8_t*)(fp + 8);
        bf8_t gA = *(const bf8_t*)gp;
        bf8_t gB = *(const bf8_t*)(gp + 8);
        float ssf[4], vvf[4];
#pragma unroll
        for (int c = 0; c < 4; ++c) {
            float f0, f1, f2, f3, g0, g1, g2, g3;
            if (c < 2) {
                f0 = bf2f((u16)fA[4 * c]);     g0 = bf2f((u16)gA[4 * c]);
                f1 = bf2f((u16)fA[4 * c + 1]); g1 = bf2f((u16)gA[4 * c + 1]);
                f2 = bf2f((u16)fA[4 * c + 2]); g2 = bf2f((u16)gA[4 * c + 2]);
                f3 = bf2f((u16)fA[4 * c + 3]); g3 = bf2f((u16)gA[4 * c + 3]);
            } else {
                int cc = c - 2;
                f0 = bf2f((u16)fB[4 * cc]);     g0 = bf2f((u16)gB[4 * cc]);
                f1 = bf2f((u16)fB[4 * cc + 1]); g1 = bf2f((u16)gB[4 * cc + 1]);
                f2 = bf2f((u16)fB[4 * cc + 2]); g2 = bf2f((u16)gB[4 * cc + 2]);
                f3 = bf2f((u16)fB[4 * cc + 3]); g3 = bf2f((u16)gB[4 * cc + 3]);
            }
            ssf[c] = f0 * g0;
            vvf[c] = (f1 * g1 + f2 * g2 + f3 * g3) * INV_SQRT3;
        }
        *(uint2*)&X7[t][128 + 4 * cg] = make_uint2(cvtpk(ssf[0], ssf[1]), cvtpk(ssf[2], ssf[3]));
        *(uint2*)&X7[t][160 + 4 * cg] = make_uint2(cvtpk(vvf[0], vvf[1]), cvtpk(vvf[2], vvf[3]));
    }
    __syncthreads();

    const f4_t z = {0.f, 0.f, 0.f, 0.f};
    f4_t acc[4];
#pragma unroll
    for (int s = 0; s < 4; ++s) acc[s] = z;
    gemm_rows<6, 4, 200>(&X7[0][0], Whf0 + w * 6 * 512, Wlf0 + w * 6 * 512, lane, acc);
    // Hs is a fresh region (disjoint from X7) -> no barrier needed before writes
#pragma unroll
    for (int s = 0; s < 4; ++s)
#pragma unroll
        for (int jj = 0; jj < 4; jj += 2) {
            u32 pk = cvtpk(silu_f(acc[s][jj] * RSQRT192), silu_f(acc[s][jj + 1] * RSQRT192));
            Hs[s * 16 + q * 4 + jj][w * 16 + r]     = (u16)pk;
            Hs[s * 16 + q * 4 + jj + 1][w * 16 + r] = (u16)(pk >> 16);
        }
    __syncthreads();

#pragma unroll
    for (int s = 0; s < 4; ++s) acc[s] = z;
    gemm_rows<4, 4, 136>(&Hs[0][0], Whf1 + w * 4 * 512, Wlf1 + w * 4 * 512, lane, acc);
    if (full) {
#pragma unroll
        for (int s = 0; s < 4; ++s)
#pragma unroll
            for (int jj = 0; jj < 4; ++jj) {
                int row = s * 16 + q * 4 + jj, cc = w * 16 + r;
                outp[(size_t)(e0 + row) * 128 + cc] =
                    SQ23 * bf2f(X7[row][cc]) + SQ13 * (acc[s][jj] * RSQRT128);
            }
    } else {
#pragma unroll
        for (int s = 0; s < 4; ++s)
#pragma unroll
            for (int jj = 0; jj < 4; ++jj) {
                int row = s * 16 + q * 4 + jj, cc = w * 16 + r;
                int e = e0 + row;
                if (e < E)
                    outp[(size_t)e * 128 + cc] =
                        SQ23 * bf2f(X7[row][cc]) + SQ13 * (acc[s][jj] * RSQRT128);
            }
    }
}

extern "C" void kernel_launch(void* const* d_in, const int* in_sizes, int n_in,
                              void* d_out, int out_size, void* d_ws, size_t ws_size,
                              hipStream_t stream)
{
    const int E  = in_sizes[0] / 2;
    const int NN = 12500;

    const int*   eidx    = (const int*)d_in[0];
    const float* attr    = (const float*)d_in[1];
    const float* inv     = (const float*)d_in[2];
    float* outp = (float*)d_out;

    // ws: lat bf16 | feat2 bf16 | env0b, env1b bf16 | weights | sort ints
    u16* latbuf  = (u16*)d_ws;
    u16* featbuf = latbuf + (size_t)E * 128;
    u16* env0b   = featbuf + (size_t)E * 128;
    u16* env1b   = env0b + (size_t)NN * 128;
    u16* p = env1b + (size_t)NN * 128;
    auto carve = [&](int elems) { u16* q0 = p; p += elems; return q0; };
    u16 *Wh2b0 = carve(128 * 32),  *Wl2b0 = carve(128 * 32);
    u16 *Wh2b1 = carve(128 * 128), *Wl2b1 = carve(128 * 128);
    u16 *Whe0  = carve(128 * 128), *Wle0  = carve(128 * 128);
    u16 *Whl10 = carve(128 * 192), *Wll10 = carve(128 * 192);
    u16 *Whl11 = carve(128 * 128), *Wll11 = carve(128 * 128);
    u16 *Whe1  = carve(64 * 128),  *Wle1  = carve(64 * 128);
    u16 *Whs0  = carve(32 * 64),   *Wls0  = carve(32 * 64);
    u16 *Whv0  = carve(32 * 64),   *Wlv0  = carve(32 * 64);
    u16 *Whf0  = carve(128 * 192), *Wlf0  = carve(128 * 192);
    u16 *Whf1  = carve(128 * 128), *Wlf1  = carve(128 * 128);
    int* cnt;
    {
        size_t off_bytes = (size_t)((char*)p - (char*)d_ws);
        off_bytes = (off_bytes + 3) & ~(size_t)3;
        cnt = (int*)((char*)d_ws + off_bytes);
    }
    int* base   = cnt + NN;          // NN+1 entries
    int* cursor = base + NN + 1;
    int* sorted = cursor + NN;

    // w-space scratch lives in d_out (fully overwritten by phaseC afterwards):
    // featw = w0[:, :64] rows, envw = w0[:,64:] rows then w1 rows.
    u16* featw = (u16*)d_out;
    u16* envw  = featw + (size_t)E * 64;

    hipMemsetAsync(cnt, 0, NN * sizeof(int), stream);

    // ---- weight prep + edge histogram (one kernel) ----
    PDs P;
    auto setpd = [&](int i, const float* s, u16* h, u16* l, int K, int N, int Kp, int pm, int off) {
        P.d[i] = {s, h, l, K, N, Kp, pm, off, N * Kp};
    };
    setpd(0, (const float*)d_in[3],  Wh2b0, Wl2b0,   8, 128,  32, 0, 0);
    setpd(1, (const float*)d_in[4],  Wh2b1, Wl2b1, 128, 128, 128, 0, 4096);
    setpd(2, (const float*)d_in[5],  Whe0,  Wle0,  128, 128, 128, 0, 20480);
    setpd(3, (const float*)d_in[6],  Whl10, Wll10, 192, 128, 192, 1, 36864);
    setpd(4, (const float*)d_in[7],  Whl11, Wll11, 128, 128, 128, 0, 61440);
    setpd(5, (const float*)d_in[8],  Whe1,  Wle1,  128,  64, 128, 0, 77824);
    setpd(6, (const float*)d_in[9],  Whs0,  Wls0,   64,  32,  64, 0, 86016);
    setpd(7, (const float*)d_in[10], Whv0,  Wlv0,   64,  32,  64, 0, 88064);
    setpd(8, (const float*)d_in[11], Whf0,  Wlf0,  192, 128, 192, 1, 90112);
    setpd(9, (const float*)d_in[12], Whf1,  Wlf1,  128, 128, 128, 0, 114688);
    const int total = 131072;
    const int span = (E > total) ? E : total;
    prep_all<<<(span + 255) / 256, 256, 0, stream>>>(P, total, eidx, cnt, E);

    // ---- counting sort of edges by center node ----
    scan_k<<<1, 1024, 0, stream>>>(cnt, base, cursor, NN);
    scatter_k<<<(E + 255) / 256, 256, 0, stream>>>(eidx, cursor, sorted, E);

    const int nb = (E + 63) / 64;
    phaseA<<<nb, 512, 0, stream>>>(inv, Wh2b0, Wl2b0, Wh2b1, Wl2b1,
                                   Whe0, Wle0, latbuf, featw, envw, E);
    reduce_env<<<(NN + 3) / 4, 256, 0, stream>>>(base, sorted, envw, attr, env0b, NN);
    phaseB<<<nb, 512, 0, stream>>>(eidx, attr, env0b, featw, envw,
                                   Whs0, Wls0, Whv0, Wlv0,
                                   Whl10, Wll10, Whl11, Wll11, Whe1, Wle1,
                                   latbuf, featbuf, E);
    reduce_env<<<(NN + 3) / 4, 256, 0, stream>>>(base, sorted, envw, attr, env1b, NN);
    phaseC<<<nb, 512, 0, stream>>>(eidx, env1b, Whf0, Wlf0, Whf1, Wlf1,
                                   latbuf, featbuf, outp, E);
}

// Round 6
// 348.592 us; speedup vs baseline: 2.9419x; 1.0729x over previous
//
#include <hip/hip_runtime.h>

typedef __attribute__((ext_vector_type(8))) short bf8_t;   // 8 x bf16 (4 VGPRs)
typedef __attribute__((ext_vector_type(4))) short bf4_t;   // 4 x bf16 (2 VGPRs)
typedef __attribute__((ext_vector_type(4))) float f4_t;    // 4 x fp32 acc
typedef unsigned short u16;
typedef unsigned int u32;

#define MFMA16 __builtin_amdgcn_mfma_f32_16x16x32_bf16

#define RSQRT8    0.35355339059327373f
#define RSQRT128  0.08838834764831845f
#define RSQRT192  0.07216878364870323f
#define RSQRT64   0.125f
#define INV_SQRT3 0.57735026918962576f
#define SEG_NORM  0.25f       /* 1/sqrt(16) */
#define C_HALF    0.70710678118654752f
#define SQ23      0.81649658092772603f
#define SQ13      0.57735026918962576f

__device__ __forceinline__ float bf2f(u16 b) {
    return __uint_as_float(((u32)b) << 16);
}
// software RNE (cold paths only; bit-identical to HW cvt)
__device__ __forceinline__ u16 f2bf(float f) {
    u32 u = __float_as_uint(f);
    u += 0x7FFFu + ((u >> 16) & 1u);
    return (u16)(u >> 16);
}
// hardware RNE pack: lo -> bits[15:0], hi -> bits[31:16]; 1 VALU inst
__device__ __forceinline__ u32 cvtpk(float lo, float hi) {
    u32 r;
    asm("v_cvt_pk_bf16_f32 %0, %1, %2" : "=v"(r) : "v"(lo), "v"(hi));
    return r;
}
__device__ __forceinline__ u16 f2bf_hw(float f) { return (u16)cvtpk(f, f); }
__device__ __forceinline__ float silu_f(float x) {
    return x * __builtin_amdgcn_rcpf(1.0f + __expf(-x));
}

// ---------------------------------------------------------------------------
// gemm_rows: one wave owns ONE 16-col tile (weights pre-offset by caller) and
// sweeps NSTR row-strips of 16. B-fragments batched in chunks; AS is a
// compile-time LDS row stride. FP order: ks ascending, lo-then-hi.
// ---------------------------------------------------------------------------
template<int KS, int NSTR, int AS>
__device__ __forceinline__ void gemm_rows(
    const u16* A,
    const u16* __restrict__ Wh, const u16* __restrict__ Wl,
    int lane, f4_t* acc)
{
    const int r = lane & 15;
    const int q = lane >> 4;
    const u16* ab = A + r * AS + q * 8;
    constexpr int CH = (KS > 4) ? 3 : KS;
#pragma unroll
    for (int c0 = 0; c0 < KS; c0 += CH) {
        bf8_t bh[CH], bl[CH];
#pragma unroll
        for (int j = 0; j < CH; ++j) {
            bh[j] = *(const bf8_t*)(Wh + ((c0 + j) * 64 + lane) * 8);
            bl[j] = *(const bf8_t*)(Wl + ((c0 + j) * 64 + lane) * 8);
        }
#pragma unroll
        for (int j = 0; j < CH; ++j) {
#pragma unroll
            for (int s = 0; s < NSTR; ++s) {
                bf8_t a = *(const bf8_t*)(ab + s * 16 * AS + (c0 + j) * 32);
                acc[s] = MFMA16(a, bl[j], acc[s], 0, 0, 0);
                acc[s] = MFMA16(a, bh[j], acc[s], 0, 0, 0);
            }
        }
    }
}

// ---------------------------------------------------------------------------
// Weight prep (+ fused edge histogram): fp32 [K][N] -> bf16 hi/lo in
// FRAGMENT-LINEAR layout: element ((tile*KS + ks)*64 + lane)*8 + j  holds
// W^T[col = tile*16 + (lane&15)][k = ks*32 + (lane>>4)*8 + j].
// ---------------------------------------------------------------------------
struct PD { const float* src; u16* hi; u16* lo; int K, N, Kp, perm, off, cnt; };
struct PDs { PD d[10]; };

__global__ __launch_bounds__(256) void prep_all(PDs P, int total,
                                                const int* __restrict__ eidx,
                                                int* __restrict__ cnt, int E)
{
    int i = blockIdx.x * 256 + threadIdx.x;
    if (i < E) atomicAdd(&cnt[eidx[i]], 1);
    if (i >= total) return;
#pragma unroll
    for (int rg = 0; rg < 10; ++rg) {
        if (i >= P.d[rg].off && i < P.d[rg].off + P.d[rg].cnt) {
            int li = i - P.d[rg].off;
            int KS = P.d[rg].Kp >> 5;
            int tile = li / (KS * 512);
            int rem  = li - tile * KS * 512;
            int ks   = rem >> 9;
            int lane = (rem >> 3) & 63;
            int j    = rem & 7;
            int n = tile * 16 + (lane & 15);
            int k = ks * 32 + (lane >> 4) * 8 + j;
            int ksrc = k;
            if (P.d[rg].perm && k >= 128)
                ksrc = (k < 160) ? (128 + 2 * (k - 128)) : (129 + 2 * (k - 160));
            float wv = (ksrc < P.d[rg].K) ? P.d[rg].src[(size_t)ksrc * P.d[rg].N + n] : 0.f;
            u16 h = f2bf(wv);
            P.d[rg].hi[li] = h;
            P.d[rg].lo[li] = f2bf(wv - bf2f(h));
        }
    }
}

// ---------------------------------------------------------------------------
// Exclusive scan over node counts. LDS-staged: coalesced global loads,
// in-LDS chunk scans (the old version's stride-13 global walk was a fully
// latency-serialized single-CU bottleneck), coalesced stores.
// ---------------------------------------------------------------------------
__global__ __launch_bounds__(1024) void scan_k(const int* __restrict__ cnt,
                                               int* __restrict__ base,
                                               int* __restrict__ cursor, int NN)
{
    __shared__ int vals[12500];
    __shared__ int part[1024];
    const int t = threadIdx.x;
    for (int i = t; i < NN; i += 1024) vals[i] = cnt[i];
    __syncthreads();
    const int CHK = (NN + 1023) >> 10;
    const int lo = t * CHK, hi = min(lo + CHK, NN);
    int s = 0;
    for (int i = lo; i < hi; ++i) s += vals[i];
    part[t] = s;
    __syncthreads();
    for (int off = 1; off < 1024; off <<= 1) {
        int v = (t >= off) ? part[t - off] : 0;
        __syncthreads();
        part[t] += v;
        __syncthreads();
    }
    if (t == 0) base[NN] = part[1023];
    int run = (t == 0) ? 0 : part[t - 1];
    for (int i = lo; i < hi; ++i) { int c = vals[i]; vals[i] = run; run += c; }
    __syncthreads();
    for (int i = t; i < NN; i += 1024) { int v = vals[i]; base[i] = v; cursor[i] = v; }
}

__global__ __launch_bounds__(256) void scatter_k(const int* __restrict__ eidx,
                                                 int* __restrict__ cursor,
                                                 int* __restrict__ sorted, int E)
{
    int i = blockIdx.x * 256 + threadIdx.x;
    if (i < E) {
        int p = atomicAdd(&cursor[eidx[i]], 1);
        sorted[p] = i;
    }
}

// ---------------------------------------------------------------------------
// Segment reduction from WEIGHT-SPACE rows: env[node][c] =
//   SEG_NORM * sum_e  w[e][2m+(idx>0)] * attr[e][idx]   (c = 4m+idx).
// ---------------------------------------------------------------------------
__global__ __launch_bounds__(256) void reduce_env(
    const int* __restrict__ base, const int* __restrict__ sorted,
    const u16* __restrict__ envw, const float* __restrict__ attr,
    u16* __restrict__ env, int NN)
{
    const int node = blockIdx.x * 4 + (threadIdx.x >> 6);
    const int ch = threadIdx.x & 63;          // channel pair: 2ch, 2ch+1
    if (node >= NN) return;
    const int b = base[node], en = base[node + 1];
    const int wo = ch & ~1;                   // aligned u16 col of the u32 w-load
    const int ao = (ch & 1) * 2;              // attr index base
    const bool odd = (ch & 1) != 0;
    float a0 = 0.f, a1 = 0.f;
    int i = b;
    for (; i + 3 < en; i += 4) {
        int s0 = sorted[i], s1 = sorted[i + 1], s2 = sorted[i + 2], s3 = sorted[i + 3];
        u32 w0 = *(const u32*)(envw + (size_t)s0 * 64 + wo);
        u32 w1 = *(const u32*)(envw + (size_t)s1 * 64 + wo);
        u32 w2 = *(const u32*)(envw + (size_t)s2 * 64 + wo);
        u32 w3 = *(const u32*)(envw + (size_t)s3 * 64 + wo);
        float2 v0 = *(const float2*)(attr + (size_t)s0 * 4 + ao);
        float2 v1 = *(const float2*)(attr + (size_t)s1 * 4 + ao);
        float2 v2 = *(const float2*)(attr + (size_t)s2 * 4 + ao);
        float2 v3 = *(const float2*)(attr + (size_t)s3 * 4 + ao);
        float l0 = bf2f((u16)(odd ? (w0 >> 16) : w0)), h0 = bf2f((u16)(w0 >> 16));
        float l1 = bf2f((u16)(odd ? (w1 >> 16) : w1)), h1 = bf2f((u16)(w1 >> 16));
        float l2 = bf2f((u16)(odd ? (w2 >> 16) : w2)), h2 = bf2f((u16)(w2 >> 16));
        float l3 = bf2f((u16)(odd ? (w3 >> 16) : w3)), h3 = bf2f((u16)(w3 >> 16));
        a0 += (l0 * v0.x + l1 * v1.x) + (l2 * v2.x + l3 * v3.x);
        a1 += (h0 * v0.y + h1 * v1.y) + (h2 * v2.y + h3 * v3.y);
    }
    for (; i < en; ++i) {
        int s0 = sorted[i];
        u32 w0 = *(const u32*)(envw + (size_t)s0 * 64 + wo);
        float2 v0 = *(const float2*)(attr + (size_t)s0 * 4 + ao);
        a0 += bf2f((u16)(odd ? (w0 >> 16) : w0)) * v0.x;
        a1 += bf2f((u16)(w0 >> 16)) * v0.y;
    }
    *(u32*)(env + (size_t)node * 128 + 2 * ch) = cvtpk(a0 * SEG_NORM, a1 * SEG_NORM);
}

// ---------------------------------------------------------------------------
// Phase A. 8 waves; wave w owns col tile w (16 cols), sweeps all 64 rows.
// All global stores are LDS-staged coalesced 16B/lane copies.
// ---------------------------------------------------------------------------
__global__ __launch_bounds__(512, 6) void phaseA(
    const float* __restrict__ inv,
    const u16* __restrict__ Wh2b0, const u16* __restrict__ Wl2b0,
    const u16* __restrict__ Wh2b1, const u16* __restrict__ Wl2b1,
    const u16* __restrict__ Whenv0, const u16* __restrict__ Wlenv0,
    u16* __restrict__ latbuf, u16* __restrict__ featw,
    u16* __restrict__ envw, int E)
{
    __shared__ __align__(16) char sm[38912];
    u16 (*Xi)[32]  = (u16 (*)[32])sm;                     // 4096
    u16 (*Hs)[136] = (u16 (*)[136])(sm + 4096);           // 17408
    u16 (*Ls)[136] = (u16 (*)[136])(sm + 21504);          // 17408

    const int tid = threadIdx.x;
    const int lane = tid & 63;
    const int w = tid >> 6;
    const int e0 = blockIdx.x * 64;
    const int E1 = E - 1;
    const int r = lane & 15, q = lane >> 4;
    const bool full = (e0 + 64 <= E);

    // coalesced inv load: 64 rows x 8 floats contiguous (2KB)
    {
        int t = tid >> 3, c = tid & 7;
        Xi[t][c] = f2bf_hw(inv[(size_t)min(e0 + t, E1) * 8 + c]);
    }
    if (tid < 256) {                     // zero cols 8..31 (disjoint from loads)
        int t = tid >> 2, c = tid & 3;
        if (c) *(bf8_t*)&Xi[t][c * 8] = (bf8_t)(short)0;
    }
    __syncthreads();

    const f4_t z = {0.f, 0.f, 0.f, 0.f};
    f4_t acc[4];

    // GEMM1: inv(8->32) @ W2b0 -> silu -> Hs
#pragma unroll
    for (int s = 0; s < 4; ++s) acc[s] = z;
    gemm_rows<1, 4, 32>(&Xi[0][0], Wh2b0 + w * 512, Wl2b0 + w * 512, lane, acc);
#pragma unroll
    for (int s = 0; s < 4; ++s)
#pragma unroll
        for (int jj = 0; jj < 4; jj += 2) {
            u32 pk = cvtpk(silu_f(acc[s][jj] * RSQRT8), silu_f(acc[s][jj + 1] * RSQRT8));
            Hs[s * 16 + q * 4 + jj][w * 16 + r]     = (u16)pk;
            Hs[s * 16 + q * 4 + jj + 1][w * 16 + r] = (u16)(pk >> 16);
        }
    __syncthreads();

    // GEMM2: h(128) @ W2b1 -> lat -> Ls (latbuf written by bulk copy below)
#pragma unroll
    for (int s = 0; s < 4; ++s) acc[s] = z;
    gemm_rows<4, 4, 136>(&Hs[0][0], Wh2b1 + w * 4 * 512, Wl2b1 + w * 4 * 512, lane, acc);
#pragma unroll
    for (int s = 0; s < 4; ++s)
#pragma unroll
        for (int jj = 0; jj < 4; jj += 2) {
            int row0 = s * 16 + q * 4 + jj, cc = w * 16 + r;
            u32 pk = cvtpk(acc[s][jj] * RSQRT128, acc[s][jj + 1] * RSQRT128);
            Ls[row0][cc]     = (u16)pk;
            Ls[row0 + 1][cc] = (u16)(pk >> 16);
        }
    __syncthreads();

    // coalesced Ls -> latbuf (overlaps with GEMM3's MFMA work)
    for (int i = tid; i < 1024; i += 512) {
        int t = i >> 4, c = i & 15;
        int e = e0 + t;
        if (full || e < E)
            *(bf8_t*)(latbuf + (size_t)e * 128 + c * 8) = *(const bf8_t*)&Ls[t][c * 8];
    }

    // GEMM3: lat(128) @ Wenv0 -> w0; stage into Hs (dead), bulk-copy out.
#pragma unroll
    for (int s = 0; s < 4; ++s) acc[s] = z;
    gemm_rows<4, 4, 136>(&Ls[0][0], Whenv0 + w * 4 * 512, Wlenv0 + w * 4 * 512, lane, acc);
    {
        const int col = w * 16 + r;
#pragma unroll
        for (int s = 0; s < 4; ++s)
#pragma unroll
            for (int jj = 0; jj < 4; jj += 2) {
                int row0 = s * 16 + q * 4 + jj;
                u32 pk = cvtpk(acc[s][jj] * RSQRT128, acc[s][jj + 1] * RSQRT128);
                Hs[row0][col]     = (u16)pk;
                Hs[row0 + 1][col] = (u16)(pk >> 16);
            }
    }
    __syncthreads();
    for (int i = tid; i < 1024; i += 512) {
        int t = i >> 4, c = i & 15;
        int e = e0 + t;
        if (full || e < E) {
            u16* dst = (c < 8) ? (featw + (size_t)e * 64 + c * 8)
                               : (envw + (size_t)e * 64 + (c - 8) * 8);
            *(bf8_t*)dst = *(const bf8_t*)&Hs[t][c * 8];
        }
    }
}

// ---------------------------------------------------------------------------
// Phase B: tensor products (w0 x attr x env0 reconstructed in registers) +
// mix; new_lat MLP; lat2; w1 staged in X4 cols 128..191 -> coalesced envw.
// ---------------------------------------------------------------------------
__global__ __launch_bounds__(512, 6) void phaseB(
    const int* __restrict__ eidx, const float* __restrict__ attr,
    const u16* __restrict__ env0b,
    const u16* __restrict__ featw, u16* __restrict__ envw,
    const u16* __restrict__ Whs0, const u16* __restrict__ Wls0,
    const u16* __restrict__ Whv0, const u16* __restrict__ Wlv0,
    const u16* __restrict__ Whl10, const u16* __restrict__ Wll10,
    const u16* __restrict__ Whl11, const u16* __restrict__ Wll11,
    const u16* __restrict__ Whe1, const u16* __restrict__ Wle1,
    u16* __restrict__ latbuf, u16* __restrict__ featbuf, int E)
{
    __shared__ __align__(16) char sm[51200];
    u16 (*X4)[200] = (u16 (*)[200])sm;                    // 25600: lat|ss|vv -> lat2
    u16 (*P)[200]  = (u16 (*)[200])(sm + 25600);          // 25600: sv|vs per dim (192 used)
    u16 (*Hs)[136] = (u16 (*)[136])(sm + 25600);          // overlay P (dead post-mix)

    const int tid = threadIdx.x;
    const int lane = tid & 63;
    const int w = tid >> 6;
    const int e0 = blockIdx.x * 64;
    const int E1 = E - 1;
    const int r = lane & 15, q = lane >> 4;
    const bool full = (e0 + 64 <= E);

    // lat -> X4[:, 0:128]
    for (int i = tid; i < 64 * 16; i += 512) {
        int t = i >> 4, dc = i & 15;
        *(bf8_t*)&X4[t][dc * 8] = ((const bf8_t*)(latbuf + (size_t)min(e0 + t, E1) * 128))[dc];
    }

    // tensor-product pass: f-channels reconstructed from w0 row x attr.
    {
        const int t = tid >> 3, cg = tid & 7;
        const int e = min(e0 + t, E1);
        const int nd = eidx[e];
        bf8_t wv = *(const bf8_t*)(featw + (size_t)e * 64 + cg * 8);
        const u16* gp = env0b + (size_t)nd * 128 + cg * 16;
        bf8_t gA = *(const bf8_t*)gp;
        bf8_t gB = *(const bf8_t*)(gp + 8);
        float4 av = *(const float4*)(attr + (size_t)e * 4);
        float ssf[4], vvf[4], svf[3][4], vsf[3][4];
#pragma unroll
        for (int c = 0; c < 4; ++c) {
            float wf0 = bf2f((u16)wv[2 * c]);
            float wf1 = bf2f((u16)wv[2 * c + 1]);
            float f0 = wf0 * av.x, f1 = wf1 * av.y, f2 = wf1 * av.z, f3 = wf1 * av.w;
            float g0, g1, g2, g3;
            if (c < 2) {
                g0 = bf2f((u16)gA[4 * c]);     g1 = bf2f((u16)gA[4 * c + 1]);
                g2 = bf2f((u16)gA[4 * c + 2]); g3 = bf2f((u16)gA[4 * c + 3]);
            } else {
                int cc = c - 2;
                g0 = bf2f((u16)gB[4 * cc]);     g1 = bf2f((u16)gB[4 * cc + 1]);
                g2 = bf2f((u16)gB[4 * cc + 2]); g3 = bf2f((u16)gB[4 * cc + 3]);
            }
            ssf[c] = f0 * g0;
            vvf[c] = (f1 * g1 + f2 * g2 + f3 * g3) * INV_SQRT3;
            svf[0][c] = f0 * g1;  svf[1][c] = f0 * g2;  svf[2][c] = f0 * g3;
            vsf[0][c] = f1 * g0;  vsf[1][c] = f2 * g0;  vsf[2][c] = f3 * g0;
        }
        *(uint2*)&X4[t][128 + 4 * cg] = make_uint2(cvtpk(ssf[0], ssf[1]), cvtpk(ssf[2], ssf[3]));
        *(uint2*)&X4[t][160 + 4 * cg] = make_uint2(cvtpk(vvf[0], vvf[1]), cvtpk(vvf[2], vvf[3]));
#pragma unroll
        for (int d = 0; d < 3; ++d) {
            *(uint2*)&P[t][d * 64 + 4 * cg]      = make_uint2(cvtpk(svf[d][0], svf[d][1]), cvtpk(svf[d][2], svf[d][3]));
            *(uint2*)&P[t][d * 64 + 32 + 4 * cg] = make_uint2(cvtpk(vsf[d][0], vsf[d][1]), cvtpk(vsf[d][2], vsf[d][3]));
        }
    }
    __syncthreads();

    const f4_t z = {0.f, 0.f, 0.f, 0.f};

    // ---- mix: wave = (strip sw, col-half cw); B-frags loaded once, shared
    // across S and all 3 V dims.
    {
        const int sw = w >> 1, cw = w & 1;
        f4_t aS = z, aV[3] = {z, z, z};
        const u16* bsh = Whs0 + cw * 2 * 512;
        const u16* bsl = Wls0 + cw * 2 * 512;
        const u16* bvh = Whv0 + cw * 2 * 512;
        const u16* bvl = Wlv0 + cw * 2 * 512;
        bf8_t s0h = *(const bf8_t*)(bsh + lane * 8);
        bf8_t s0l = *(const bf8_t*)(bsl + lane * 8);
        bf8_t s1h = *(const bf8_t*)(bsh + 512 + lane * 8);
        bf8_t s1l = *(const bf8_t*)(bsl + 512 + lane * 8);
        bf8_t v0h = *(const bf8_t*)(bvh + lane * 8);
        bf8_t v0l = *(const bf8_t*)(bvl + lane * 8);
        bf8_t v1h = *(const bf8_t*)(bvh + 512 + lane * 8);
        bf8_t v1l = *(const bf8_t*)(bvl + 512 + lane * 8);
        const u16* arow = &X4[sw * 16 + r][0];
        bf8_t a0 = *(const bf8_t*)(arow + 128 + q * 8);
        bf8_t a1 = *(const bf8_t*)(arow + 160 + q * 8);
        aS = MFMA16(a0, s0l, aS, 0, 0, 0);
        aS = MFMA16(a0, s0h, aS, 0, 0, 0);
        aS = MFMA16(a1, s1l, aS, 0, 0, 0);
        aS = MFMA16(a1, s1h, aS, 0, 0, 0);
        const u16* prow = &P[sw * 16 + r][0];
#pragma unroll
        for (int d = 0; d < 3; ++d) {
            bf8_t p0 = *(const bf8_t*)(prow + d * 64 + q * 8);
            bf8_t p1 = *(const bf8_t*)(prow + d * 64 + 32 + q * 8);
            aV[d] = MFMA16(p0, v0l, aV[d], 0, 0, 0);
            aV[d] = MFMA16(p0, v0h, aV[d], 0, 0, 0);
            aV[d] = MFMA16(p1, v1l, aV[d], 0, 0, 0);
            aV[d] = MFMA16(p1, v1h, aV[d], 0, 0, 0);
        }
        // feat2 direct to global: one 8B store per reg (128B/16-lane group)
        const int m = cw * 16 + r;
#pragma unroll
        for (int reg = 0; reg < 4; ++reg) {
            int e = e0 + sw * 16 + q * 4 + reg;
            if (full || e < E) {
                uint2 pv;
                pv.x = cvtpk(aS[reg] * RSQRT64,
                             aV[0][reg] * (RSQRT64 * INV_SQRT3));
                pv.y = cvtpk(aV[1][reg] * (RSQRT64 * INV_SQRT3),
                             aV[2][reg] * (RSQRT64 * INV_SQRT3));
                *(uint2*)(featbuf + (size_t)e * 128 + 4 * m) = pv;
            }
        }
    }

    // GEMM4: [lat|sscal](192) @ Wlat1_0
    f4_t acc[4];
#pragma unroll
    for (int s = 0; s < 4; ++s) acc[s] = z;
    gemm_rows<6, 4, 200>(&X4[0][0], Whl10 + w * 6 * 512, Wll10 + w * 6 * 512, lane, acc);
    __syncthreads();   // all P reads (mix) done -> Hs may overwrite P
#pragma unroll
    for (int s = 0; s < 4; ++s)
#pragma unroll
        for (int jj = 0; jj < 4; jj += 2) {
            u32 pk = cvtpk(silu_f(acc[s][jj] * RSQRT192), silu_f(acc[s][jj + 1] * RSQRT192));
            Hs[s * 16 + q * 4 + jj][w * 16 + r]     = (u16)pk;
            Hs[s * 16 + q * 4 + jj + 1][w * 16 + r] = (u16)(pk >> 16);
        }
    __syncthreads();

    // GEMM5: h @ Wlat1_1 -> new_lat; lat2 = C*(lat+new_lat) in place in X4
#pragma unroll
    for (int s = 0; s < 4; ++s) acc[s] = z;
    gemm_rows<4, 4, 136>(&Hs[0][0], Whl11 + w * 4 * 512, Wll11 + w * 4 * 512, lane, acc);
#pragma unroll
    for (int s = 0; s < 4; ++s)
#pragma unroll
        for (int jj = 0; jj < 4; jj += 2) {
            int row0 = s * 16 + q * 4 + jj, cc = w * 16 + r;
            float l2a = C_HALF * (bf2f(X4[row0][cc]) + acc[s][jj] * RSQRT128);
            float l2b = C_HALF * (bf2f(X4[row0 + 1][cc]) + acc[s][jj + 1] * RSQRT128);
            u32 pk = cvtpk(l2a, l2b);
            X4[row0][cc]     = (u16)pk;       // cells owned by this lane-reg only
            X4[row0 + 1][cc] = (u16)(pk >> 16);
        }
    __syncthreads();

    // lat2 -> latbuf (coalesced) ; GEMM6: lat2 @ Wenv1 -> w1 staged in X4
    for (int i = tid; i < 64 * 16; i += 512) {
        int t = i >> 4, dc = i & 15;
        int e = e0 + t;
        if (full || e < E)
            ((bf8_t*)(latbuf + (size_t)e * 128))[dc] = *(const bf8_t*)&X4[t][dc * 8];
    }
    {
        const int ct = w & 3, rh = w >> 2;   // col tile 0..3, row half 0..1
        f4_t a6[2] = {z, z};
        gemm_rows<4, 2, 200>(&X4[rh * 32][0], Whe1 + ct * 4 * 512, Wle1 + ct * 4 * 512, lane, a6);
        const int col = ct * 16 + r;         // 0..63
#pragma unroll
        for (int s = 0; s < 2; ++s)
#pragma unroll
            for (int jj = 0; jj < 4; jj += 2) {
                int row0 = rh * 32 + s * 16 + q * 4 + jj;
                u32 pk = cvtpk(a6[s][jj] * RSQRT128, a6[s][jj + 1] * RSQRT128);
                X4[row0][128 + col]     = (u16)pk;     // stage (cols 128.. dead)
                X4[row0 + 1][128 + col] = (u16)(pk >> 16);
            }
    }
    __syncthreads();
    // coalesced w1 copy: 64 rows x 64 u16 = 512 chunks of 16B
    {
        int t = tid >> 3, c = tid & 7;
        int e = e0 + t;
        if (full || e < E)
            *(bf8_t*)(envw + (size_t)e * 64 + c * 8) = *(const bf8_t*)&X4[t][128 + c * 8];
    }
}

// ---------------------------------------------------------------------------
// Phase C: scalars1 streamed from global, final MLP, out mix.
// ---------------------------------------------------------------------------
__global__ __launch_bounds__(512, 6) void phaseC(
    const int* __restrict__ eidx, const u16* __restrict__ env1b,
    const u16* __restrict__ Whf0, const u16* __restrict__ Wlf0,
    const u16* __restrict__ Whf1, const u16* __restrict__ Wlf1,
    const u16* __restrict__ latbuf, const u16* __restrict__ featbuf,
    float* __restrict__ outp, int E)
{
    __shared__ __align__(16) char sm[43008];
    u16 (*X7)[200] = (u16 (*)[200])sm;                    // 25600: lat2|scal1
    u16 (*Hs)[136] = (u16 (*)[136])(sm + 25600);          // 17408

    const int tid = threadIdx.x;
    const int lane = tid & 63;
    const int w = tid >> 6;
    const int e0 = blockIdx.x * 64;
    const int E1 = E - 1;
    const int r = lane & 15, q = lane >> 4;
    const bool full = (e0 + 64 <= E);

    // lat2 -> X7[:, 0:128]
    for (int i = tid; i < 64 * 16; i += 512) {
        int t = i >> 4, dc = i & 15;
        *(bf8_t*)&X7[t][dc * 8] = ((const bf8_t*)(latbuf + (size_t)min(e0 + t, E1) * 128))[dc];
    }

    // scalars1 pass: ss/vv from feat2 x env1, streamed from global
    {
        const int t = tid >> 3, cg = tid & 7;
        const int e = min(e0 + t, E1);
        const int nd = eidx[e];
        const u16* fp = featbuf + (size_t)e * 128 + cg * 16;
        const u16* gp = env1b + (size_t)nd * 128 + cg * 16;
        bf8_t fA = *(const bf8_t*)fp;
        bf8_t fB = *(const bf8_t*)(fp + 8);
        bf8_t gA = *(const bf8_t*)gp;
        bf8_t gB = *(const bf8_t*)(gp + 8);
        float ssf[4], vvf[4];
#pragma unroll
        for (int c = 0; c < 4; ++c) {
            float f0, f1, f2, f3, g0, g1, g2, g3;
            if (c < 2) {
                f0 = bf2f((u16)fA[4 * c]);     g0 = bf2f((u16)gA[4 * c]);
                f1 = bf2f((u16)fA[4 * c + 1]); g1 = bf2f((u16)gA[4 * c + 1]);
                f2 = bf2f((u16)fA[4 * c + 2]); g2 = bf2f((u16)gA[4 * c + 2]);
                f3 = bf2f((u16)fA[4 * c + 3]); g3 = bf2f((u16)gA[4 * c + 3]);
            } else {
                int cc = c - 2;
                f0 = bf2f((u16)fB[4 * cc]);     g0 = bf2f((u16)gB[4 * cc]);
                f1 = bf2f((u16)fB[4 * cc + 1]); g1 = bf2f((u16)gB[4 * cc + 1]);
                f2 = bf2f((u16)fB[4 * cc + 2]); g2 = bf2f((u16)gB[4 * cc + 2]);
                f3 = bf2f((u16)fB[4 * cc + 3]); g3 = bf2f((u16)gB[4 * cc + 3]);
            }
            ssf[c] = f0 * g0;
            vvf[c] = (f1 * g1 + f2 * g2 + f3 * g3) * INV_SQRT3;
        }
        *(uint2*)&X7[t][128 + 4 * cg] = make_uint2(cvtpk(ssf[0], ssf[1]), cvtpk(ssf[2], ssf[3]));
        *(uint2*)&X7[t][160 + 4 * cg] = make_uint2(cvtpk(vvf[0], vvf[1]), cvtpk(vvf[2], vvf[3]));
    }
    __syncthreads();

    const f4_t z = {0.f, 0.f, 0.f, 0.f};
    f4_t acc[4];
#pragma unroll
    for (int s = 0; s < 4; ++s) acc[s] = z;
    gemm_rows<6, 4, 200>(&X7[0][0], Whf0 + w * 6 * 512, Wlf0 + w * 6 * 512, lane, acc);
    // Hs is a fresh region (disjoint from X7) -> no barrier needed before writes
#pragma unroll
    for (int s = 0; s < 4; ++s)
#pragma unroll
        for (int jj = 0; jj < 4; jj += 2) {
            u32 pk = cvtpk(silu_f(acc[s][jj] * RSQRT192), silu_f(acc[s][jj + 1] * RSQRT192));
            Hs[s * 16 + q * 4 + jj][w * 16 + r]     = (u16)pk;
            Hs[s * 16 + q * 4 + jj + 1][w * 16 + r] = (u16)(pk >> 16);
        }
    __syncthreads();

#pragma unroll
    for (int s = 0; s < 4; ++s) acc[s] = z;
    gemm_rows<4, 4, 136>(&Hs[0][0], Whf1 + w * 4 * 512, Wlf1 + w * 4 * 512, lane, acc);
    if (full) {
#pragma unroll
        for (int s = 0; s < 4; ++s)
#pragma unroll
            for (int jj = 0; jj < 4; ++jj) {
                int row = s * 16 + q * 4 + jj, cc = w * 16 + r;
                outp[(size_t)(e0 + row) * 128 + cc] =
                    SQ23 * bf2f(X7[row][cc]) + SQ13 * (acc[s][jj] * RSQRT128);
            }
    } else {
#pragma unroll
        for (int s = 0; s < 4; ++s)
#pragma unroll
            for (int jj = 0; jj < 4; ++jj) {
                int row = s * 16 + q * 4 + jj, cc = w * 16 + r;
                int e = e0 + row;
                if (e < E)
                    outp[(size_t)e * 128 + cc] =
                        SQ23 * bf2f(X7[row][cc]) + SQ13 * (acc[s][jj] * RSQRT128);
            }
    }
}

extern "C" void kernel_launch(void* const* d_in, const int* in_sizes, int n_in,
                              void* d_out, int out_size, void* d_ws, size_t ws_size,
                              hipStream_t stream)
{
    const int E  = in_sizes[0] / 2;
    const int NN = 12500;

    const int*   eidx    = (const int*)d_in[0];
    const float* attr    = (const float*)d_in[1];
    const float* inv     = (const float*)d_in[2];
    float* outp = (float*)d_out;

    // ws: lat bf16 | feat2 bf16 | env0b, env1b bf16 | weights | sort ints
    u16* latbuf  = (u16*)d_ws;
    u16* featbuf = latbuf + (size_t)E * 128;
    u16* env0b   = featbuf + (size_t)E * 128;
    u16* env1b   = env0b + (size_t)NN * 128;
    u16* p = env1b + (size_t)NN * 128;
    auto carve = [&](int elems) { u16* q0 = p; p += elems; return q0; };
    u16 *Wh2b0 = carve(128 * 32),  *Wl2b0 = carve(128 * 32);
    u16 *Wh2b1 = carve(128 * 128), *Wl2b1 = carve(128 * 128);
    u16 *Whe0  = carve(128 * 128), *Wle0  = carve(128 * 128);
    u16 *Whl10 = carve(128 * 192), *Wll10 = carve(128 * 192);
    u16 *Whl11 = carve(128 * 128), *Wll11 = carve(128 * 128);
    u16 *Whe1  = carve(64 * 128),  *Wle1  = carve(64 * 128);
    u16 *Whs0  = carve(32 * 64),   *Wls0  = carve(32 * 64);
    u16 *Whv0  = carve(32 * 64),   *Wlv0  = carve(32 * 64);
    u16 *Whf0  = carve(128 * 192), *Wlf0  = carve(128 * 192);
    u16 *Whf1  = carve(128 * 128), *Wlf1  = carve(128 * 128);
    int* cnt;
    {
        size_t off_bytes = (size_t)((char*)p - (char*)d_ws);
        off_bytes = (off_bytes + 3) & ~(size_t)3;
        cnt = (int*)((char*)d_ws + off_bytes);
    }
    int* base   = cnt + NN;          // NN+1 entries
    int* cursor = base + NN + 1;
    int* sorted = cursor + NN;

    // w-space scratch lives in d_out (fully overwritten by phaseC afterwards):
    // featw = w0[:, :64] rows, envw = w0[:,64:] rows then w1 rows.
    u16* featw = (u16*)d_out;
    u16* envw  = featw + (size_t)E * 64;

    hipMemsetAsync(cnt, 0, NN * sizeof(int), stream);

    // ---- weight prep + edge histogram (one kernel) ----
    PDs P;
    auto setpd = [&](int i, const float* s, u16* h, u16* l, int K, int N, int Kp, int pm, int off) {
        P.d[i] = {s, h, l, K, N, Kp, pm, off, N * Kp};
    };
    setpd(0, (const float*)d_in[3],  Wh2b0, Wl2b0,   8, 128,  32, 0, 0);
    setpd(1, (const float*)d_in[4],  Wh2b1, Wl2b1, 128, 128, 128, 0, 4096);
    setpd(2, (const float*)d_in[5],  Whe0,  Wle0,  128, 128, 128, 0, 20480);
    setpd(3, (const float*)d_in[6],  Whl10, Wll10, 192, 128, 192, 1, 36864);
    setpd(4, (const float*)d_in[7],  Whl11, Wll11, 128, 128, 128, 0, 61440);
    setpd(5, (const float*)d_in[8],  Whe1,  Wle1,  128,  64, 128, 0, 77824);
    setpd(6, (const float*)d_in[9],  Whs0,  Wls0,   64,  32,  64, 0, 86016);
    setpd(7, (const float*)d_in[10], Whv0,  Wlv0,   64,  32,  64, 0, 88064);
    setpd(8, (const float*)d_in[11], Whf0,  Wlf0,  192, 128, 192, 1, 90112);
    setpd(9, (const float*)d_in[12], Whf1,  Wlf1,  128, 128, 128, 0, 114688);
    const int total = 131072;
    const int span = (E > total) ? E : total;
    prep_all<<<(span + 255) / 256, 256, 0, stream>>>(P, total, eidx, cnt, E);

    // ---- counting sort of edges by center node ----
    scan_k<<<1, 1024, 0, stream>>>(cnt, base, cursor, NN);
    scatter_k<<<(E + 255) / 256, 256, 0, stream>>>(eidx, cursor, sorted, E);

    const int nb = (E + 63) / 64;
    phaseA<<<nb, 512, 0, stream>>>(inv, Wh2b0, Wl2b0, Wh2b1, Wl2b1,
                                   Whe0, Wle0, latbuf, featw, envw, E);
    reduce_env<<<(NN + 3) / 4, 256, 0, stream>>>(base, sorted, envw, attr, env0b, NN);
    phaseB<<<nb, 512, 0, stream>>>(eidx, attr, env0b, featw, envw,
                                   Whs0, Wls0, Whv0, Wlv0,
                                   Whl10, Wll10, Whl11, Wll11, Whe1, Wle1,
                                   latbuf, featbuf, E);
    reduce_env<<<(NN + 3) / 4, 256, 0, stream>>>(base, sorted, envw, attr, env1b, NN);
    phaseC<<<nb, 512, 0, stream>>>(eidx, env1b, Whf0, Wlf0, Whf1, Wlf1,
                                   latbuf, featbuf, outp, E);
}